// Round 2
// baseline (48758.478 us; speedup 1.0000x reference)
//
#include <hip/hip_runtime.h>
#include <math.h>

namespace {

constexpr int cB = 32, cL = 1024, cCIN = 32, cDM = 512, cDFF = 2048;
constexpr int cH = 8, cE = 64, cM = 64, cPRED = 256;
constexpr int M2 = 2 * cM; // 128 (re/im interleaved modes)

// ================= basis init (DFT / iDFT as GEMM operands) =================
__global__ void basis_kernel(float* __restrict__ basisd, float* __restrict__ basisi) {
  int idx = blockIdx.x * 256 + threadIdx.x;
  if (idx >= M2 * cL) return;
  int t = idx & (cL - 1);
  int m2 = idx >> 10;
  int m = m2 >> 1;
  float ang = 6.2831853071795864f * (float)((m * t) & (cL - 1)) / (float)cL;
  float cv = cosf(ang), sv = sinf(ang);
  float vd = (m2 & 1) ? -sv : cv;
  basisd[idx] = vd;
  float s = (m == 0) ? ((m2 & 1) ? 0.f : (1.f / (float)cL)) : (2.f / (float)cL);
  basisi[t * M2 + m2] = vd * s;
}

// ================= moving-average decomposition =================
__global__ void decomp_kernel(const float* __restrict__ x, float* __restrict__ seasonal,
                              float* __restrict__ ma_out, int total, int C) {
  int idx = blockIdx.x * 256 + threadIdx.x;
  if (idx >= total) return;
  int c = idx % C;
  int t = (idx / C) & (cL - 1);
  long base = (long)(idx / (C * cL)) * cL * C + c;
  float s = 0.f;
#pragma unroll
  for (int j = -12; j <= 12; j++) {
    int tt = t + j;
    tt = tt < 0 ? 0 : (tt >= cL ? cL - 1 : tt);
    s += x[base + (long)tt * C];
  }
  float ma = s * (1.0f / 25.0f);
  if (seasonal) seasonal[idx] = x[idx] - ma;
  if (ma_out) ma_out[idx] = ma;
}

// ================= token embedding: circular conv3 CIN->DM + pos emb =================
// x is pre-offset to the group's first batch
__global__ void emb_kernel(const float* __restrict__ x, const float* __restrict__ W,
                           float* __restrict__ out) {
  int idx = blockIdx.x * 256 + threadIdx.x; // (bl*L + t)*DM + o
  int o = idx & (cDM - 1);
  int t = (idx >> 9) & (cL - 1);
  int b = idx >> 19;
  const float* xb = x + (long)b * cL * cCIN;
  int tm = (t + cL - 1) & (cL - 1), tp = (t + 1) & (cL - 1);
  const float* r0 = xb + tm * cCIN;
  const float* r1 = xb + t * cCIN;
  const float* r2 = xb + tp * cCIN;
  const float* w = W + o * (cCIN * 3);
  float s = 0.f;
#pragma unroll
  for (int c = 0; c < cCIN; c++) {
    s += r0[c] * w[c * 3] + r1[c] * w[c * 3 + 1] + r2[c] * w[c * 3 + 2];
  }
  int i = o >> 1;
  float freq = __expf((float)(2 * i) * (-9.210340371976184f / (float)cDM));
  float angf = freq * (float)t;
  s += (o & 1) ? cosf(angf) : sinf(angf);
  out[idx] = s;
}

// ================= trend projection: circular conv3 DM->CIN, accumulating =================
__global__ void trendconv_kernel(const float* __restrict__ ma, const float* __restrict__ W,
                                 float* __restrict__ trend) {
  int idx = blockIdx.x * 256 + threadIdx.x; // (bl*L + t)*CIN + o
  int o = idx & (cCIN - 1);
  int t = (idx >> 5) & (cL - 1);
  int b = idx >> 15;
  const float* xb = ma + (long)b * cL * cDM;
  int tm = (t + cL - 1) & (cL - 1), tp = (t + 1) & (cL - 1);
  const float* r0 = xb + (long)tm * cDM;
  const float* r1 = xb + (long)t * cDM;
  const float* r2 = xb + (long)tp * cDM;
  const float* w = W + (long)o * (cDM * 3);
  float s = 0.f;
  for (int c = 0; c < cDM; c++) {
    s += r0[c] * w[c * 3] + r1[c] * w[c * 3 + 1] + r2[c] * w[c * 3 + 2];
  }
  trend[idx] += s;
}

// ================= final time projection (out pre-offset to group) =================
__global__ void p2_kernel(const float* __restrict__ x, const float* __restrict__ W,
                          const float* __restrict__ bias, float* __restrict__ out) {
  int idx = blockIdx.x * 256 + threadIdx.x; // (bl*PRED + p)*CIN + c
  int c = idx & 31;
  int p = (idx >> 5) & 255;
  int b = idx >> 13;
  const float* xb = x + (long)b * cL * cCIN + c;
  const float* w = W + (long)p * cL;
  float s = bias[p];
  for (int l = 0; l < cL; l++) s += xb[(long)l * cCIN] * w[l];
  out[idx] = s;
}

// ================= per-(h,mode) complex mode mix (in-place safe) =================
__global__ __launch_bounds__(256) void modemix_kernel(const float* __restrict__ F,
                                                      const float* __restrict__ W,
                                                      float* __restrict__ out, float scale) {
  int b = blockIdx.x, h = blockIdx.y;
  __shared__ float2 Fs[cE][cM]; // [e][x]
  const float* Fb = F + ((long)b * cDM + h * cE) * M2;
  for (int i = threadIdx.x; i < cE * cM; i += 256) {
    int e = i >> 6, x = i & 63;
    Fs[e][x] = ((const float2*)(Fb + (long)e * M2))[x];
  }
  __syncthreads();
  int x = threadIdx.x & 63, og = threadIdx.x >> 6;
  float2 acc[16];
#pragma unroll
  for (int i = 0; i < 16; i++) acc[i] = make_float2(0.f, 0.f);
  for (int e = 0; e < cE; e++) {
    float2 f = Fs[e][x];
#pragma unroll
    for (int i = 0; i < 16; i++) {
      int o = og * 16 + i;
      const float2 w = *(const float2*)(W + ((((long)h * cE + e) * cE + o) * cM + x) * 2);
      acc[i].x += f.x * w.x - f.y * w.y;
      acc[i].y += f.x * w.y + f.y * w.x;
    }
  }
  float* ob = out + ((long)b * cDM + h * cE) * M2;
#pragma unroll
  for (int i = 0; i < 16; i++) {
    int o = og * 16 + i;
    ((float2*)(ob + (long)o * M2))[x] = make_float2(acc[i].x * scale, acc[i].y * scale);
  }
}

// ================= fourier_cross: qk = tanh(sum_e xq[e,x]*xk[e,y]) =================
__global__ __launch_bounds__(256) void crossqk_kernel(const float* __restrict__ Fq,
                                                      const float* __restrict__ Fk,
                                                      float* __restrict__ QKb) {
  int b = blockIdx.x, h = blockIdx.y;
  __shared__ float2 Ks[cE][cM]; // [e][y]
  const float* kb = Fk + ((long)b * cDM + h * cE) * M2;
  for (int i = threadIdx.x; i < cE * cM; i += 256) {
    int e = i >> 6, y = i & 63;
    Ks[e][y] = ((const float2*)(kb + (long)e * M2))[y];
  }
  __syncthreads();
  int x = threadIdx.x & 63, yg = threadIdx.x >> 6;
  const float* qb = Fq + ((long)b * cDM + h * cE) * M2;
  float2 acc[16];
#pragma unroll
  for (int i = 0; i < 16; i++) acc[i] = make_float2(0.f, 0.f);
  for (int e = 0; e < cE; e++) {
    float2 q = ((const float2*)(qb + (long)e * M2))[x];
#pragma unroll
    for (int i = 0; i < 16; i++) {
      float2 k = Ks[e][yg * 16 + i];
      acc[i].x += q.x * k.x - q.y * k.y;
      acc[i].y += q.x * k.y + q.y * k.x;
    }
  }
  float2* qkb = (float2*)(QKb) + (((long)b * cH + h) * cM * cM);
#pragma unroll
  for (int i = 0; i < 16; i++) {
    int y = yg * 16 + i;
    float a = acc[i].x, bi = acc[i].y;
    float re, im;
    float t2a = 2.f * a;
    if (fabsf(t2a) > 60.f) {
      re = t2a > 0.f ? 1.f : -1.f;
      im = 0.f;
    } else {
      float denom = coshf(t2a) + cosf(2.f * bi);
      re = sinhf(t2a) / denom;
      im = sinf(2.f * bi) / denom;
    }
    qkb[x * cM + y] = make_float2(re, im);
  }
}

// qkv[e,x] = sum_y qk[x,y] * xk[e,y]   (writes over Fq)
__global__ __launch_bounds__(256) void crossqkv_kernel(const float* __restrict__ QKb,
                                                       const float* __restrict__ Fk,
                                                       float* __restrict__ Fq) {
  int b = blockIdx.x, h = blockIdx.y;
  __shared__ float2 qks[cM][cM]; // [x][y]
  const float2* qkb = (const float2*)(QKb) + (((long)b * cH + h) * cM * cM);
  for (int i = threadIdx.x; i < cM * cM; i += 256) qks[i >> 6][i & 63] = qkb[i];
  __syncthreads();
  int e = threadIdx.x & 63, xg = threadIdx.x >> 6;
  const float* kb = Fk + ((long)b * cDM + h * cE) * M2;
  float2 acc[16];
#pragma unroll
  for (int i = 0; i < 16; i++) acc[i] = make_float2(0.f, 0.f);
  for (int y = 0; y < cM; y++) {
    float2 k = ((const float2*)(kb + (long)e * M2))[y];
#pragma unroll
    for (int i = 0; i < 16; i++) {
      float2 qk = qks[xg * 16 + i][y];
      acc[i].x += qk.x * k.x - qk.y * k.y;
      acc[i].y += qk.x * k.y + qk.y * k.x;
    }
  }
  float* ob = Fq + ((long)b * cDM + h * cE) * M2;
#pragma unroll
  for (int i = 0; i < 16; i++) {
    int x = xg * 16 + i;
    ((float2*)(ob + (long)e * M2))[x] = acc[i];
  }
}

// ================= generic tiled f32 GEMM =================
constexpr int GBM = 128, GBN = 128, GBK = 16, LPAD = 132;

template <bool TRANSA>
__global__ __launch_bounds__(256) void gemm_kernel(const float* __restrict__ A,
                                                   const float* __restrict__ B,
                                                   const float* __restrict__ bias,
                                                   const float* __restrict__ addend,
                                                   float* __restrict__ C, int M, int N, int K,
                                                   long sA, long sB, long sC, int relu) {
  __shared__ float As[GBK][LPAD];
  __shared__ float Bs[GBK][LPAD];
  int z = blockIdx.z;
  A += (long)z * sA;
  B += (long)z * sB;
  C += (long)z * sC;
  const float* Ad = addend ? addend + (long)z * sC : nullptr;
  int n0 = blockIdx.x * GBN, m0 = blockIdx.y * GBM;
  int tid = threadIdx.x;
  int tx = tid & 15, ty = tid >> 4;
  float acc[8][8];
#pragma unroll
  for (int i = 0; i < 8; i++)
#pragma unroll
    for (int j = 0; j < 8; j++) acc[i][j] = 0.f;

  for (int k0 = 0; k0 < K; k0 += GBK) {
    if (TRANSA) {
#pragma unroll
      for (int p = 0; p < 8; p++) {
        int i = p * 256 + tid;
        int kk = i >> 7, mm = i & 127;
        int gm = m0 + mm;
        As[kk][mm] = (gm < M) ? A[(long)(k0 + kk) * M + gm] : 0.f;
      }
    } else {
#pragma unroll
      for (int p = 0; p < 8; p++) {
        int i = p * 256 + tid;
        int mm = i >> 4, kk = i & 15;
        int gm = m0 + mm;
        As[kk][mm] = (gm < M) ? A[(long)gm * K + k0 + kk] : 0.f;
      }
    }
#pragma unroll
    for (int p = 0; p < 8; p++) {
      int i = p * 256 + tid;
      int nn = i >> 4, kk = i & 15;
      int gn = n0 + nn;
      Bs[kk][nn] = (gn < N) ? B[(long)gn * K + k0 + kk] : 0.f;
    }
    __syncthreads();
#pragma unroll
    for (int kk = 0; kk < GBK; kk++) {
      float a[8], bb[8];
      *(float4*)&a[0] = *(const float4*)&As[kk][ty * 8];
      *(float4*)&a[4] = *(const float4*)&As[kk][ty * 8 + 4];
      *(float4*)&bb[0] = *(const float4*)&Bs[kk][tx * 8];
      *(float4*)&bb[4] = *(const float4*)&Bs[kk][tx * 8 + 4];
#pragma unroll
      for (int i = 0; i < 8; i++)
#pragma unroll
        for (int j = 0; j < 8; j++) acc[i][j] += a[i] * bb[j];
    }
    __syncthreads();
  }

  for (int i = 0; i < 8; i++) {
    int gm = m0 + ty * 8 + i;
    if (gm >= M) break;
    long rowoff = (long)gm * N;
    for (int j = 0; j < 8; j++) {
      int gn = n0 + tx * 8 + j;
      if (gn < N) {
        float v = acc[i][j];
        if (bias) v += bias[gn];
        if (Ad) v += Ad[rowoff + gn];
        if (relu) v = fmaxf(v, 0.f);
        C[rowoff + gn] = v;
      }
    }
  }
}

} // namespace

extern "C" void kernel_launch(void* const* d_in, const int* in_sizes, int n_in, void* d_out,
                              int out_size, void* d_ws, size_t ws_size, hipStream_t stream) {
  const float* x_enc = (const float*)d_in[0];
  const float* tok_W = (const float*)d_in[1];
  const float* enc_Wq = (const float*)d_in[2];
  const float* enc_Wo = (const float*)d_in[5];
  const float* enc_bq = (const float*)d_in[6];
  const float* enc_bo = (const float*)d_in[9];
  const float* dsWq = (const float*)d_in[10];
  const float* dsWo = (const float*)d_in[13];
  const float* dsbq = (const float*)d_in[14];
  const float* dsbo = (const float*)d_in[17];
  const float* dcWq = (const float*)d_in[18];
  const float* dcWk = (const float*)d_in[19];
  const float* dcWo = (const float*)d_in[21];
  const float* dcbq = (const float*)d_in[22];
  const float* dcbk = (const float*)d_in[23];
  const float* dcbo = (const float*)d_in[25];
  const float* enc_c1W = (const float*)d_in[26];
  const float* enc_c1b = (const float*)d_in[27];
  const float* enc_c2W = (const float*)d_in[28];
  const float* enc_c2b = (const float*)d_in[29];
  const float* dec_c1W = (const float*)d_in[30];
  const float* dec_c1b = (const float*)d_in[31];
  const float* dec_c2W = (const float*)d_in[32];
  const float* dec_c2b = (const float*)d_in[33];
  const float* dec_trW = (const float*)d_in[34];
  const float* fb_enc = (const float*)d_in[35];
  const float* fb_dec = (const float*)d_in[36];
  const float* fc_w = (const float*)d_in[37];
  const float* p1W = (const float*)d_in[38];
  const float* p1b = (const float*)d_in[39];
  const float* p2W = (const float*)d_in[40];
  const float* p2b = (const float*)d_in[41];
  const float* p3W = (const float*)d_in[42];
  const float* p3b = (const float*)d_in[43];

  // ---- adaptive batch-grouping so the layout fits ws_size ----
  auto need_bytes = [&](int BG, long RH) -> size_t {
    long G = (long)BG * cL * cDM;
    long tot = 2L * M2 * cL          // basisd + basisi
               + 4 * G               // ENC, X, A, S
               + RH * cDFF           // FFN hidden chunk
               + 2L * BG * cDM * M2  // Fq, Fk
               + (long)BG * cH * cM * cM * 2  // QKb
               + 3L * BG * cL * cCIN;         // TRD, O1, O2
    return (size_t)tot * 4;
  };
  int BG = cB;
  long RH = 2048;
  while (BG > 1 && need_bytes(BG, RH) > ws_size) BG >>= 1;
  while (RH > 256 && need_bytes(BG, RH) > ws_size) RH >>= 1;
  if (RH > (long)BG * cL) RH = (long)BG * cL;

  long G = (long)BG * cL * cDM;
  float* ws = (float*)d_ws;
  long off = 0;
  float* basisd = ws + off; off += (long)M2 * cL;
  float* basisi = ws + off; off += (long)cL * M2;
  float* ENC = ws + off; off += G;
  float* X = ws + off; off += G;
  float* A = ws + off; off += G;
  float* S = ws + off; off += G;   // ma / k scratch
  float* HD = ws + off; off += RH * cDFF;
  float* Fq = ws + off; off += (long)BG * cDM * M2;
  float* Fk = ws + off; off += (long)BG * cDM * M2;
  float* QKb = ws + off; off += (long)BG * cH * cM * cM * 2;
  float* TRD = ws + off; off += (long)BG * cL * cCIN;
  float* O1 = ws + off; off += (long)BG * cL * cCIN;
  float* O2 = ws + off; off += (long)BG * cL * cCIN;

  auto gemmNT = [&](const float* Am, const float* Bm, const float* bias, const float* add,
                    float* C, int Mm, int Nn, int Kk, long sA, long sB, long sC, int batch,
                    int relu) {
    dim3 g((Nn + GBN - 1) / GBN, (Mm + GBM - 1) / GBM, batch);
    gemm_kernel<false><<<g, 256, 0, stream>>>(Am, Bm, bias, add, C, Mm, Nn, Kk, sA, sB, sC, relu);
  };
  auto gemmTN = [&](const float* Am, const float* Bm, float* C, int Mm, int Nn, int Kk, long sA,
                    long sB, long sC, int batch) {
    dim3 g((Nn + GBN - 1) / GBN, (Mm + GBM - 1) / GBM, batch);
    gemm_kernel<true><<<g, 256, 0, stream>>>(Am, Bm, nullptr, nullptr, C, Mm, Nn, Kk, sA, sB, sC, 0);
  };
  auto dft = [&](const float* q, float* F) {
    gemmTN(q, basisd, F, cDM, M2, cL, (long)cL * cDM, 0, (long)cDM * M2, BG);
  };
  auto idft = [&](const float* F, float* o) {
    gemmNT(basisi, F, nullptr, nullptr, o, cL, cDM, M2, 0, (long)cDM * M2, (long)cL * cDM, BG, 0);
  };
  auto decomp = [&](const float* x, float* seasonal, float* ma, long total, int C_) {
    decomp_kernel<<<(total + 255) / 256, 256, 0, stream>>>(x, seasonal, ma, (int)total, C_);
  };
  auto ffn = [&](const float* in, float* out, const float* c1W, const float* c1b,
                 const float* c2W, const float* c2b) {
    long R = (long)BG * cL;
    for (long r = 0; r < R; r += RH) {
      long o2 = r * cDM;
      gemmNT(in + o2, c1W, c1b, nullptr, HD, (int)RH, cDFF, cDM, 0, 0, 0, 1, 1);
      gemmNT(HD, c2W, c2b, in + o2, out + o2, (int)RH, cDM, cDFF, 0, 0, 0, 1, 0);
    }
  };
  auto trendconv = [&](const float* ma, const float* W) {
    trendconv_kernel<<<((long)BG * cL * cCIN) / 256, 256, 0, stream>>>(ma, W, TRD);
  };
  auto mix = [&](float* F, const float* W, float scale) {
    modemix_kernel<<<dim3(BG, cH), 256, 0, stream>>>(F, W, F, scale);
  };

  basis_kernel<<<(M2 * cL) / 256, 256, 0, stream>>>(basisd, basisi);

  for (int b0 = 0; b0 < cB; b0 += BG) {
    const float* xg = x_enc + (long)b0 * cL * cCIN;
    long GBL = (long)BG * cL;

    // trend_init (writes TRD fresh) + embedding
    decomp(xg, nullptr, TRD, GBL * cCIN, cCIN);
    emb_kernel<<<G / 256, 256, 0, stream>>>(xg, tok_W, ENC);

    // ---- encoder ----
    for (int l = 0; l < 2; l++) {
      const float* Wq = enc_Wq + (long)l * cDM * cDM;
      const float* Wo = enc_Wo + (long)l * cDM * cDM;
      gemmNT(ENC, Wq, enc_bq + l * cDM, nullptr, X, (int)GBL, cDM, cDM, 0, 0, 0, 1, 0);
      dft(X, Fq);
      mix(Fq, fb_enc, 1.0f);
      idft(Fq, X);
      gemmNT(X, Wo, enc_bo + l * cDM, ENC, A, (int)GBL, cDM, cDM, 0, 0, 0, 1, 0);
      decomp(A, X, nullptr, GBL * cDM, cDM);
      ffn(X, A, enc_c1W + (long)l * cDFF * cDM, enc_c1b + l * cDFF,
          enc_c2W + (long)l * cDM * cDFF, enc_c2b + l * cDM);
      decomp(A, ENC, nullptr, GBL * cDM, cDM);
    }

    // ---- decoder ----
    gemmNT(ENC, dsWq, dsbq, nullptr, X, (int)GBL, cDM, cDM, 0, 0, 0, 1, 0);
    dft(X, Fq);
    mix(Fq, fb_dec, 1.0f);
    idft(Fq, X);
    gemmNT(X, dsWo, dsbo, ENC, A, (int)GBL, cDM, cDM, 0, 0, 0, 1, 0);  // x1
    decomp(A, X, S, GBL * cDM, cDM);                                    // x2 -> X, ma -> S
    trendconv(S, dec_trW);                                              // t1

    gemmNT(X, dcWq, dcbq, nullptr, A, (int)GBL, cDM, cDM, 0, 0, 0, 1, 0); // q2 -> A
    gemmNT(ENC, dcWk, dcbk, nullptr, S, (int)GBL, cDM, cDM, 0, 0, 0, 1, 0); // k -> S (ENC dead)
    dft(A, Fq);
    dft(S, Fk);
    crossqk_kernel<<<dim3(BG, cH), 256, 0, stream>>>(Fq, Fk, QKb);
    crossqkv_kernel<<<dim3(BG, cH), 256, 0, stream>>>(QKb, Fk, Fq);
    mix(Fq, fc_w, 1.0f / (float)(cDM * cDM));
    idft(Fq, A);
    gemmNT(A, dcWo, dcbo, X, ENC, (int)GBL, cDM, cDM, 0, 0, 0, 1, 0); // x3 -> ENC
    decomp(ENC, A, X, GBL * cDM, cDM);                                 // x4 -> A, ma -> X
    trendconv(X, dec_trW);                                             // t2

    ffn(A, ENC, dec_c1W, dec_c1b, dec_c2W, dec_c2b);                   // x4 + y -> ENC
    decomp(ENC, X, A, GBL * cDM, cDM);                                 // x5 -> X, ma -> A
    trendconv(A, dec_trW);                                             // t3

    // ---- final projections ----
    gemmNT(X, p3W, p3b, TRD, O1, (int)GBL, cCIN, cDM, 0, 0, 0, 1, 0);
    gemmNT(O1, p1W, p1b, nullptr, O2, (int)GBL, cCIN, cCIN, 0, 0, 0, 1, 0);
    p2_kernel<<<((long)BG * cPRED * cCIN) / 256, 256, 0, stream>>>(
        O2, p2W, p2b, (float*)d_out + (long)b0 * cPRED * cCIN);
  }
}

// Round 3
// 23397.263 us; speedup vs baseline: 2.0839x; 2.0839x over previous
//
#include <hip/hip_runtime.h>
#include <math.h>

namespace {

constexpr int cB = 32, cL = 1024, cCIN = 32, cDM = 512, cDFF = 2048;
constexpr int cH = 8, cE = 64, cM = 64, cPRED = 256;
constexpr int M2 = 2 * cM; // 128 (re/im interleaved modes)

typedef __attribute__((ext_vector_type(8))) short short8v;
typedef __attribute__((ext_vector_type(4))) float float4v;

__device__ inline unsigned short f2bf(float f) {
  unsigned int u = __builtin_bit_cast(unsigned int, f);
  u += 0x7FFFu + ((u >> 16) & 1u); // RNE
  return (unsigned short)(u >> 16);
}

// ================= basis init =================
__global__ void basis_kernel(float* __restrict__ basisd, float* __restrict__ basisi) {
  int idx = blockIdx.x * 256 + threadIdx.x;
  if (idx >= M2 * cL) return;
  int t = idx & (cL - 1);
  int m2 = idx >> 10;
  int m = m2 >> 1;
  float ang = 6.2831853071795864f * (float)((m * t) & (cL - 1)) / (float)cL;
  float cv = cosf(ang), sv = sinf(ang);
  float vd = (m2 & 1) ? -sv : cv;
  basisd[idx] = vd;
  float s = (m == 0) ? ((m2 & 1) ? 0.f : (1.f / (float)cL)) : (2.f / (float)cL);
  basisi[t * M2 + m2] = vd * s;
}

// ================= moving-average decomposition =================
__global__ void decomp_kernel(const float* __restrict__ x, float* __restrict__ seasonal,
                              float* __restrict__ ma_out, int total, int C) {
  int idx = blockIdx.x * 256 + threadIdx.x;
  if (idx >= total) return;
  int c = idx % C;
  int t = (idx / C) & (cL - 1);
  long base = (long)(idx / (C * cL)) * cL * C + c;
  float s = 0.f;
#pragma unroll
  for (int j = -12; j <= 12; j++) {
    int tt = t + j;
    tt = tt < 0 ? 0 : (tt >= cL ? cL - 1 : tt);
    s += x[base + (long)tt * C];
  }
  float ma = s * (1.0f / 25.0f);
  if (seasonal) seasonal[idx] = x[idx] - ma;
  if (ma_out) ma_out[idx] = ma;
}

// ================= token embedding =================
__global__ void emb_kernel(const float* __restrict__ x, const float* __restrict__ W,
                           float* __restrict__ out) {
  int idx = blockIdx.x * 256 + threadIdx.x;
  int o = idx & (cDM - 1);
  int t = (idx >> 9) & (cL - 1);
  int b = idx >> 19;
  const float* xb = x + (long)b * cL * cCIN;
  int tm = (t + cL - 1) & (cL - 1), tp = (t + 1) & (cL - 1);
  const float* r0 = xb + tm * cCIN;
  const float* r1 = xb + t * cCIN;
  const float* r2 = xb + tp * cCIN;
  const float* w = W + o * (cCIN * 3);
  float s = 0.f;
#pragma unroll
  for (int c = 0; c < cCIN; c++) {
    s += r0[c] * w[c * 3] + r1[c] * w[c * 3 + 1] + r2[c] * w[c * 3 + 2];
  }
  int i = o >> 1;
  float freq = __expf((float)(2 * i) * (-9.210340371976184f / (float)cDM));
  float angf = freq * (float)t;
  s += (o & 1) ? cosf(angf) : sinf(angf);
  out[idx] = s;
}

// ================= trend projection =================
__global__ void trendconv_kernel(const float* __restrict__ ma, const float* __restrict__ W,
                                 float* __restrict__ trend) {
  int idx = blockIdx.x * 256 + threadIdx.x;
  int o = idx & (cCIN - 1);
  int t = (idx >> 5) & (cL - 1);
  int b = idx >> 15;
  const float* xb = ma + (long)b * cL * cDM;
  int tm = (t + cL - 1) & (cL - 1), tp = (t + 1) & (cL - 1);
  const float* r0 = xb + (long)tm * cDM;
  const float* r1 = xb + (long)t * cDM;
  const float* r2 = xb + (long)tp * cDM;
  const float* w = W + (long)o * (cDM * 3);
  float s = 0.f;
  for (int c = 0; c < cDM; c++) {
    s += r0[c] * w[c * 3] + r1[c] * w[c * 3 + 1] + r2[c] * w[c * 3 + 2];
  }
  trend[idx] += s;
}

// ================= final time projection =================
__global__ void p2_kernel(const float* __restrict__ x, const float* __restrict__ W,
                          const float* __restrict__ bias, float* __restrict__ out) {
  int idx = blockIdx.x * 256 + threadIdx.x;
  int c = idx & 31;
  int p = (idx >> 5) & 255;
  int b = idx >> 13;
  const float* xb = x + (long)b * cL * cCIN + c;
  const float* w = W + (long)p * cL;
  float s = bias[p];
  for (int l = 0; l < cL; l++) s += xb[(long)l * cCIN] * w[l];
  out[idx] = s;
}

// ================= per-(h,mode) complex mode mix =================
__global__ __launch_bounds__(256) void modemix_kernel(const float* __restrict__ F,
                                                      const float* __restrict__ W,
                                                      float* __restrict__ out, float scale) {
  int b = blockIdx.x, h = blockIdx.y;
  __shared__ float2 Fs[cE][cM];
  const float* Fb = F + ((long)b * cDM + h * cE) * M2;
  for (int i = threadIdx.x; i < cE * cM; i += 256) {
    int e = i >> 6, x = i & 63;
    Fs[e][x] = ((const float2*)(Fb + (long)e * M2))[x];
  }
  __syncthreads();
  int x = threadIdx.x & 63, og = threadIdx.x >> 6;
  float2 acc[16];
#pragma unroll
  for (int i = 0; i < 16; i++) acc[i] = make_float2(0.f, 0.f);
  for (int e = 0; e < cE; e++) {
    float2 f = Fs[e][x];
#pragma unroll
    for (int i = 0; i < 16; i++) {
      int o = og * 16 + i;
      const float2 w = *(const float2*)(W + ((((long)h * cE + e) * cE + o) * cM + x) * 2);
      acc[i].x += f.x * w.x - f.y * w.y;
      acc[i].y += f.x * w.y + f.y * w.x;
    }
  }
  float* ob = out + ((long)b * cDM + h * cE) * M2;
#pragma unroll
  for (int i = 0; i < 16; i++) {
    int o = og * 16 + i;
    ((float2*)(ob + (long)o * M2))[x] = make_float2(acc[i].x * scale, acc[i].y * scale);
  }
}

// ================= fourier_cross =================
__global__ __launch_bounds__(256) void crossqk_kernel(const float* __restrict__ Fq,
                                                      const float* __restrict__ Fk,
                                                      float* __restrict__ QKb) {
  int b = blockIdx.x, h = blockIdx.y;
  __shared__ float2 Ks[cE][cM];
  const float* kb = Fk + ((long)b * cDM + h * cE) * M2;
  for (int i = threadIdx.x; i < cE * cM; i += 256) {
    int e = i >> 6, y = i & 63;
    Ks[e][y] = ((const float2*)(kb + (long)e * M2))[y];
  }
  __syncthreads();
  int x = threadIdx.x & 63, yg = threadIdx.x >> 6;
  const float* qb = Fq + ((long)b * cDM + h * cE) * M2;
  float2 acc[16];
#pragma unroll
  for (int i = 0; i < 16; i++) acc[i] = make_float2(0.f, 0.f);
  for (int e = 0; e < cE; e++) {
    float2 q = ((const float2*)(qb + (long)e * M2))[x];
#pragma unroll
    for (int i = 0; i < 16; i++) {
      float2 k = Ks[e][yg * 16 + i];
      acc[i].x += q.x * k.x - q.y * k.y;
      acc[i].y += q.x * k.y + q.y * k.x;
    }
  }
  float2* qkb = (float2*)(QKb) + (((long)b * cH + h) * cM * cM);
#pragma unroll
  for (int i = 0; i < 16; i++) {
    int y = yg * 16 + i;
    float a = acc[i].x, bi = acc[i].y;
    float re, im;
    float t2a = 2.f * a;
    if (fabsf(t2a) > 60.f) {
      re = t2a > 0.f ? 1.f : -1.f;
      im = 0.f;
    } else {
      float denom = coshf(t2a) + cosf(2.f * bi);
      re = sinhf(t2a) / denom;
      im = sinf(2.f * bi) / denom;
    }
    qkb[x * cM + y] = make_float2(re, im);
  }
}

__global__ __launch_bounds__(256) void crossqkv_kernel(const float* __restrict__ QKb,
                                                       const float* __restrict__ Fk,
                                                       float* __restrict__ Fq) {
  int b = blockIdx.x, h = blockIdx.y;
  __shared__ float2 qks[cM][cM];
  const float2* qkb = (const float2*)(QKb) + (((long)b * cH + h) * cM * cM);
  for (int i = threadIdx.x; i < cM * cM; i += 256) qks[i >> 6][i & 63] = qkb[i];
  __syncthreads();
  int e = threadIdx.x & 63, xg = threadIdx.x >> 6;
  const float* kb = Fk + ((long)b * cDM + h * cE) * M2;
  float2 acc[16];
#pragma unroll
  for (int i = 0; i < 16; i++) acc[i] = make_float2(0.f, 0.f);
  for (int y = 0; y < cM; y++) {
    float2 k = ((const float2*)(kb + (long)e * M2))[y];
#pragma unroll
    for (int i = 0; i < 16; i++) {
      float2 qk = qks[xg * 16 + i][y];
      acc[i].x += qk.x * k.x - qk.y * k.y;
      acc[i].y += qk.x * k.y + qk.y * k.x;
    }
  }
  float* ob = Fq + ((long)b * cDM + h * cE) * M2;
#pragma unroll
  for (int i = 0; i < 16; i++) {
    int x = xg * 16 + i;
    ((float2*)(ob + (long)e * M2))[x] = acc[i];
  }
}

// ================= f32 shader GEMM (dft TRANSA + small finals) =================
constexpr int GBM = 128, GBN = 128, GBK = 16, LPAD = 132;

template <bool TRANSA>
__global__ __launch_bounds__(256) void gemm_kernel(const float* __restrict__ A,
                                                   const float* __restrict__ B,
                                                   const float* __restrict__ bias,
                                                   const float* __restrict__ addend,
                                                   float* __restrict__ C, int M, int N, int K,
                                                   long sA, long sB, long sC, int relu) {
  __shared__ float As[GBK][LPAD];
  __shared__ float Bs[GBK][LPAD];
  int z = blockIdx.z;
  A += (long)z * sA;
  B += (long)z * sB;
  C += (long)z * sC;
  const float* Ad = addend ? addend + (long)z * sC : nullptr;
  int n0 = blockIdx.x * GBN, m0 = blockIdx.y * GBM;
  int tid = threadIdx.x;
  int tx = tid & 15, ty = tid >> 4;
  float acc[8][8];
#pragma unroll
  for (int i = 0; i < 8; i++)
#pragma unroll
    for (int j = 0; j < 8; j++) acc[i][j] = 0.f;

  for (int k0 = 0; k0 < K; k0 += GBK) {
    if (TRANSA) {
#pragma unroll
      for (int p = 0; p < 8; p++) {
        int i = p * 256 + tid;
        int kk = i >> 7, mm = i & 127;
        int gm = m0 + mm;
        As[kk][mm] = (gm < M) ? A[(long)(k0 + kk) * M + gm] : 0.f;
      }
    } else {
#pragma unroll
      for (int p = 0; p < 8; p++) {
        int i = p * 256 + tid;
        int mm = i >> 4, kk = i & 15;
        int gm = m0 + mm;
        As[kk][mm] = (gm < M) ? A[(long)gm * K + k0 + kk] : 0.f;
      }
    }
#pragma unroll
    for (int p = 0; p < 8; p++) {
      int i = p * 256 + tid;
      int nn = i >> 4, kk = i & 15;
      int gn = n0 + nn;
      Bs[kk][nn] = (gn < N) ? B[(long)gn * K + k0 + kk] : 0.f;
    }
    __syncthreads();
#pragma unroll
    for (int kk = 0; kk < GBK; kk++) {
      float a[8], bb[8];
      *(float4*)&a[0] = *(const float4*)&As[kk][ty * 8];
      *(float4*)&a[4] = *(const float4*)&As[kk][ty * 8 + 4];
      *(float4*)&bb[0] = *(const float4*)&Bs[kk][tx * 8];
      *(float4*)&bb[4] = *(const float4*)&Bs[kk][tx * 8 + 4];
#pragma unroll
      for (int i = 0; i < 8; i++)
#pragma unroll
        for (int j = 0; j < 8; j++) acc[i][j] += a[i] * bb[j];
    }
    __syncthreads();
  }

  for (int i = 0; i < 8; i++) {
    int gm = m0 + ty * 8 + i;
    if (gm >= M) break;
    long rowoff = (long)gm * N;
    for (int j = 0; j < 8; j++) {
      int gn = n0 + tx * 8 + j;
      if (gn < N) {
        float v = acc[i][j];
        if (bias) v += bias[gn];
        if (Ad) v += Ad[rowoff + gn];
        if (relu) v = fmaxf(v, 0.f);
        C[rowoff + gn] = v;
      }
    }
  }
}

// ================= bf16 MFMA GEMM: C = A @ B^T, f32 in/out, cvt in staging ==========
// Tile 128x128xK64, 4 waves, per-wave 64x64 via 4x4 frags of 16x16x32.
constexpr int TAPAD = 72; // shorts per LDS row (64 + 8) -> 144B stride, 2-way conflicts only

__global__ __launch_bounds__(256) void mfma_gemm(const float* __restrict__ A,
                                                 const float* __restrict__ B,
                                                 const float* __restrict__ bias,
                                                 const float* __restrict__ addend,
                                                 float* __restrict__ C, int M, int N, int K,
                                                 long sA, long sB, long sC, int relu) {
  __shared__ short As[128 * TAPAD];
  __shared__ short Bs[128 * TAPAD];
  int z = blockIdx.z;
  A += (long)z * sA;
  B += (long)z * sB;
  C += (long)z * sC;
  const float* Ad = addend ? addend + (long)z * sC : nullptr;
  int n0 = blockIdx.x * 128, m0 = blockIdx.y * 128;
  int tid = threadIdx.x;
  int lane = tid & 63;
  int w = tid >> 6;
  int wm = w & 1, wn = w >> 1;           // wave -> 64x64 quadrant
  int lr = lane & 15, lg = lane >> 4;    // frag row/col + k-group

  float4v acc[4][4];
#pragma unroll
  for (int i = 0; i < 4; i++)
#pragma unroll
    for (int j = 0; j < 4; j++) acc[i][j] = (float4v){0.f, 0.f, 0.f, 0.f};

  for (int k0 = 0; k0 < K; k0 += 64) {
    // stage A and B tiles: 128 rows x 64 k each, f32 -> bf16
#pragma unroll
    for (int p = 0; p < 8; p++) {
      int fi = p * 256 + tid;     // 2048 float4s
      int row = fi >> 4;          // 0..127
      int c4 = fi & 15;           // col = c4*4
      float4 v = *(const float4*)&A[(long)(m0 + row) * K + k0 + c4 * 4];
      unsigned int lo = (unsigned int)f2bf(v.x) | ((unsigned int)f2bf(v.y) << 16);
      unsigned int hi = (unsigned int)f2bf(v.z) | ((unsigned int)f2bf(v.w) << 16);
      *(uint2*)&As[row * TAPAD + c4 * 4] = make_uint2(lo, hi);
    }
#pragma unroll
    for (int p = 0; p < 8; p++) {
      int fi = p * 256 + tid;
      int row = fi >> 4;
      int c4 = fi & 15;
      float4 v = *(const float4*)&B[(long)(n0 + row) * K + k0 + c4 * 4];
      unsigned int lo = (unsigned int)f2bf(v.x) | ((unsigned int)f2bf(v.y) << 16);
      unsigned int hi = (unsigned int)f2bf(v.z) | ((unsigned int)f2bf(v.w) << 16);
      *(uint2*)&Bs[row * TAPAD + c4 * 4] = make_uint2(lo, hi);
    }
    __syncthreads();
#pragma unroll
    for (int ks = 0; ks < 2; ks++) {
      short8v af[4], bf[4];
#pragma unroll
      for (int mi = 0; mi < 4; mi++)
        af[mi] = *(const short8v*)&As[(wm * 64 + mi * 16 + lr) * TAPAD + ks * 32 + lg * 8];
#pragma unroll
      for (int ni = 0; ni < 4; ni++)
        bf[ni] = *(const short8v*)&Bs[(wn * 64 + ni * 16 + lr) * TAPAD + ks * 32 + lg * 8];
#pragma unroll
      for (int mi = 0; mi < 4; mi++)
#pragma unroll
        for (int ni = 0; ni < 4; ni++)
          acc[mi][ni] =
              __builtin_amdgcn_mfma_f32_16x16x32_bf16(af[mi], bf[ni], acc[mi][ni], 0, 0, 0);
    }
    __syncthreads();
  }

  // epilogue: D[row=(lg*4+i)+mi*16+wm*64][col=lr+ni*16+wn*64]
#pragma unroll
  for (int mi = 0; mi < 4; mi++) {
#pragma unroll
    for (int i = 0; i < 4; i++) {
      int gr = m0 + wm * 64 + mi * 16 + lg * 4 + i;
      long rowoff = (long)gr * N;
#pragma unroll
      for (int ni = 0; ni < 4; ni++) {
        int gc = n0 + wn * 64 + ni * 16 + lr;
        float v = acc[mi][ni][i];
        if (bias) v += bias[gc];
        if (Ad) v += Ad[rowoff + gc];
        if (relu) v = fmaxf(v, 0.f);
        C[rowoff + gc] = v;
      }
    }
  }
}

} // namespace

extern "C" void kernel_launch(void* const* d_in, const int* in_sizes, int n_in, void* d_out,
                              int out_size, void* d_ws, size_t ws_size, hipStream_t stream) {
  const float* x_enc = (const float*)d_in[0];
  const float* tok_W = (const float*)d_in[1];
  const float* enc_Wq = (const float*)d_in[2];
  const float* enc_Wo = (const float*)d_in[5];
  const float* enc_bq = (const float*)d_in[6];
  const float* enc_bo = (const float*)d_in[9];
  const float* dsWq = (const float*)d_in[10];
  const float* dsWo = (const float*)d_in[13];
  const float* dsbq = (const float*)d_in[14];
  const float* dsbo = (const float*)d_in[17];
  const float* dcWq = (const float*)d_in[18];
  const float* dcWk = (const float*)d_in[19];
  const float* dcWo = (const float*)d_in[21];
  const float* dcbq = (const float*)d_in[22];
  const float* dcbk = (const float*)d_in[23];
  const float* dcbo = (const float*)d_in[25];
  const float* enc_c1W = (const float*)d_in[26];
  const float* enc_c1b = (const float*)d_in[27];
  const float* enc_c2W = (const float*)d_in[28];
  const float* enc_c2b = (const float*)d_in[29];
  const float* dec_c1W = (const float*)d_in[30];
  const float* dec_c1b = (const float*)d_in[31];
  const float* dec_c2W = (const float*)d_in[32];
  const float* dec_c2b = (const float*)d_in[33];
  const float* dec_trW = (const float*)d_in[34];
  const float* fb_enc = (const float*)d_in[35];
  const float* fb_dec = (const float*)d_in[36];
  const float* fc_w = (const float*)d_in[37];
  const float* p1W = (const float*)d_in[38];
  const float* p1b = (const float*)d_in[39];
  const float* p2W = (const float*)d_in[40];
  const float* p2b = (const float*)d_in[41];
  const float* p3W = (const float*)d_in[42];
  const float* p3b = (const float*)d_in[43];

  auto need_bytes = [&](int BG, long RH) -> size_t {
    long G = (long)BG * cL * cDM;
    long tot = 2L * M2 * cL + 4 * G + RH * cDFF + 2L * BG * cDM * M2 +
               (long)BG * cH * cM * cM * 2 + 3L * BG * cL * cCIN;
    return (size_t)tot * 4;
  };
  int BG = cB;
  long RH = 2048;
  while (BG > 1 && need_bytes(BG, RH) > ws_size) BG >>= 1;
  while (RH > 256 && need_bytes(BG, RH) > ws_size) RH >>= 1;
  if (RH > (long)BG * cL) RH = (long)BG * cL;

  long G = (long)BG * cL * cDM;
  float* ws = (float*)d_ws;
  long off = 0;
  float* basisd = ws + off; off += (long)M2 * cL;
  float* basisi = ws + off; off += (long)cL * M2;
  float* ENC = ws + off; off += G;
  float* X = ws + off; off += G;
  float* A = ws + off; off += G;
  float* S = ws + off; off += G;
  float* HD = ws + off; off += RH * cDFF;
  float* Fq = ws + off; off += (long)BG * cDM * M2;
  float* Fk = ws + off; off += (long)BG * cDM * M2;
  float* QKb = ws + off; off += (long)BG * cH * cM * cM * 2;
  float* TRD = ws + off; off += (long)BG * cL * cCIN;
  float* O1 = ws + off; off += (long)BG * cL * cCIN;
  float* O2 = ws + off; off += (long)BG * cL * cCIN;

  // MFMA path (M%128==0, N%128==0, K%64==0 guaranteed by callers)
  auto mgemm = [&](const float* Am, const float* Bm, const float* bias, const float* add,
                   float* C, int Mm, int Nn, int Kk, long sA, long sB, long sC, int batch,
                   int relu) {
    dim3 g(Nn / 128, Mm / 128, batch);
    mfma_gemm<<<g, 256, 0, stream>>>(Am, Bm, bias, add, C, Mm, Nn, Kk, sA, sB, sC, relu);
  };
  auto gemmNT32 = [&](const float* Am, const float* Bm, const float* bias, const float* add,
                      float* C, int Mm, int Nn, int Kk, int relu) {
    dim3 g((Nn + GBN - 1) / GBN, (Mm + GBM - 1) / GBM, 1);
    gemm_kernel<false><<<g, 256, 0, stream>>>(Am, Bm, bias, add, C, Mm, Nn, Kk, 0, 0, 0, relu);
  };
  auto dft = [&](const float* q, float* F) { // f32 TRANSA: F[dm][m2] per batch
    dim3 g(1, cDM / GBM, BG);
    gemm_kernel<true><<<g, 256, 0, stream>>>(q, basisd, nullptr, nullptr, F, cDM, M2, cL,
                                             (long)cL * cDM, 0, (long)cDM * M2, 0);
  };
  auto idft = [&](const float* F, float* o) { // MFMA NT: o[t][dm] = basisi @ F^T
    mgemm(basisi, F, nullptr, nullptr, o, cL, cDM, M2, 0, (long)cDM * M2, (long)cL * cDM, BG, 0);
  };
  auto decomp = [&](const float* x, float* seasonal, float* ma, long total, int C_) {
    decomp_kernel<<<(total + 255) / 256, 256, 0, stream>>>(x, seasonal, ma, (int)total, C_);
  };
  auto ffn = [&](const float* in, float* out, const float* c1W, const float* c1b,
                 const float* c2W, const float* c2b) {
    long R = (long)BG * cL;
    for (long r = 0; r < R; r += RH) {
      long o2 = r * cDM;
      mgemm(in + o2, c1W, c1b, nullptr, HD, (int)RH, cDFF, cDM, 0, 0, 0, 1, 1);
      mgemm(HD, c2W, c2b, in + o2, out + o2, (int)RH, cDM, cDFF, 0, 0, 0, 1, 0);
    }
  };
  auto trendconv = [&](const float* ma, const float* W) {
    trendconv_kernel<<<((long)BG * cL * cCIN) / 256, 256, 0, stream>>>(ma, W, TRD);
  };
  auto mix = [&](float* F, const float* W, float scale) {
    modemix_kernel<<<dim3(BG, cH), 256, 0, stream>>>(F, W, F, scale);
  };

  basis_kernel<<<(M2 * cL) / 256, 256, 0, stream>>>(basisd, basisi);

  for (int b0 = 0; b0 < cB; b0 += BG) {
    const float* xg = x_enc + (long)b0 * cL * cCIN;
    long GBL = (long)BG * cL;

    decomp(xg, nullptr, TRD, GBL * cCIN, cCIN);
    emb_kernel<<<G / 256, 256, 0, stream>>>(xg, tok_W, ENC);

    // ---- encoder ----
    for (int l = 0; l < 2; l++) {
      const float* Wq = enc_Wq + (long)l * cDM * cDM;
      const float* Wo = enc_Wo + (long)l * cDM * cDM;
      mgemm(ENC, Wq, enc_bq + l * cDM, nullptr, X, (int)GBL, cDM, cDM, 0, 0, 0, 1, 0);
      dft(X, Fq);
      mix(Fq, fb_enc, 1.0f);
      idft(Fq, X);
      mgemm(X, Wo, enc_bo + l * cDM, ENC, A, (int)GBL, cDM, cDM, 0, 0, 0, 1, 0);
      decomp(A, X, nullptr, GBL * cDM, cDM);
      ffn(X, A, enc_c1W + (long)l * cDFF * cDM, enc_c1b + l * cDFF,
          enc_c2W + (long)l * cDM * cDFF, enc_c2b + l * cDM);
      decomp(A, ENC, nullptr, GBL * cDM, cDM);
    }

    // ---- decoder ----
    mgemm(ENC, dsWq, dsbq, nullptr, X, (int)GBL, cDM, cDM, 0, 0, 0, 1, 0);
    dft(X, Fq);
    mix(Fq, fb_dec, 1.0f);
    idft(Fq, X);
    mgemm(X, dsWo, dsbo, ENC, A, (int)GBL, cDM, cDM, 0, 0, 0, 1, 0);  // x1
    decomp(A, X, S, GBL * cDM, cDM);                                   // x2 -> X, ma -> S
    trendconv(S, dec_trW);                                             // t1

    mgemm(X, dcWq, dcbq, nullptr, A, (int)GBL, cDM, cDM, 0, 0, 0, 1, 0);   // q2 -> A
    mgemm(ENC, dcWk, dcbk, nullptr, S, (int)GBL, cDM, cDM, 0, 0, 0, 1, 0); // k -> S
    dft(A, Fq);
    dft(S, Fk);
    crossqk_kernel<<<dim3(BG, cH), 256, 0, stream>>>(Fq, Fk, QKb);
    crossqkv_kernel<<<dim3(BG, cH), 256, 0, stream>>>(QKb, Fk, Fq);
    mix(Fq, fc_w, 1.0f / (float)(cDM * cDM));
    idft(Fq, A);
    mgemm(A, dcWo, dcbo, X, ENC, (int)GBL, cDM, cDM, 0, 0, 0, 1, 0);  // x3 -> ENC
    decomp(ENC, A, X, GBL * cDM, cDM);                                 // x4 -> A, ma -> X
    trendconv(X, dec_trW);                                             // t2

    ffn(A, ENC, dec_c1W, dec_c1b, dec_c2W, dec_c2b);                   // x4 + y -> ENC
    decomp(ENC, X, A, GBL * cDM, cDM);                                 // x5 -> X, ma -> A
    trendconv(A, dec_trW);                                             // t3

    // ---- final projections (f32 for precision) ----
    gemmNT32(X, p3W, p3b, TRD, O1, (int)GBL, cCIN, cDM, 0);
    gemmNT32(O1, p1W, p1b, nullptr, O2, (int)GBL, cCIN, cCIN, 0);
    p2_kernel<<<((long)BG * cPRED * cCIN) / 256, 256, 0, stream>>>(
        O2, p2W, p2b, (float*)d_out + (long)b0 * cPRED * cCIN);
  }
}

// Round 4
// 20237.555 us; speedup vs baseline: 2.4093x; 1.1561x over previous
//
#include <hip/hip_runtime.h>
#include <math.h>

namespace {

constexpr int cB = 32, cL = 1024, cCIN = 32, cDM = 512, cDFF = 2048;
constexpr int cH = 8, cE = 64, cM = 64, cPRED = 256;
constexpr int M2 = 2 * cM; // 128 (re/im interleaved modes)

typedef __attribute__((ext_vector_type(8))) short short8v;
typedef __attribute__((ext_vector_type(4))) float float4v;

__device__ inline unsigned short f2bf(float f) {
  unsigned int u = __builtin_bit_cast(unsigned int, f);
  u += 0x7FFFu + ((u >> 16) & 1u); // RNE
  return (unsigned short)(u >> 16);
}

// ================= basis init =================
__global__ void basis_kernel(float* __restrict__ basisd, float* __restrict__ basisi) {
  int idx = blockIdx.x * 256 + threadIdx.x;
  if (idx >= M2 * cL) return;
  int t = idx & (cL - 1);
  int m2 = idx >> 10;
  int m = m2 >> 1;
  float ang = 6.2831853071795864f * (float)((m * t) & (cL - 1)) / (float)cL;
  float cv = cosf(ang), sv = sinf(ang);
  float vd = (m2 & 1) ? -sv : cv;
  basisd[idx] = vd;
  float s = (m == 0) ? ((m2 & 1) ? 0.f : (1.f / (float)cL)) : (2.f / (float)cL);
  basisi[t * M2 + m2] = vd * s;
}

// ================= positional embedding table [L][DM] =================
__global__ void pe_kernel(float* __restrict__ pe) {
  int idx = blockIdx.x * 256 + threadIdx.x;
  int o = idx & (cDM - 1), t = idx >> 9;
  int i = o >> 1;
  float freq = __expf((float)(2 * i) * (-9.210340371976184f / (float)cDM));
  float ang = freq * (float)t;
  pe[idx] = (o & 1) ? cosf(ang) : sinf(ang);
}

// ================= weight prep: Bpad (token conv), WJt (trend conv), p3pad ======
__global__ void prep_kernel(const float* __restrict__ tok_W, const float* __restrict__ trW,
                            const float* __restrict__ p3W, const float* __restrict__ p3b,
                            float* __restrict__ Bpad, float* __restrict__ WJt,
                            float* __restrict__ p3pad, float* __restrict__ p3bpad) {
  int idx = blockIdx.x * 256 + threadIdx.x;
  if (idx < 512 * 128) { // Bpad[o][j*32+c] = tok_W[o][c][j]
    int o = idx >> 7, s = idx & 127, j = s >> 5, c = s & 31;
    Bpad[idx] = (j < 3) ? tok_W[o * 96 + c * 3 + j] : 0.f;
  }
  if (idx < 3 * 32 * 512) { // WJt[j][o][c] = trW[o][c][j]
    int j = idx >> 14, r = idx & 16383, o = r >> 9, c = r & 511;
    WJt[idx] = trW[(long)o * 1536 + c * 3 + j];
  }
  if (idx < 128 * 512) { // p3pad[o][k], zero rows >= 32
    int o = idx >> 9, k = idx & 511;
    p3pad[idx] = (o < 32) ? p3W[o * 512 + k] : 0.f;
  }
  if (idx < 128) p3bpad[idx] = (idx < 32) ? p3b[idx] : 0.f;
}

// ================= win build: [BG*L][128] = [x[t-1,:], x[t,:], x[t+1,:], 0x32] (circular) ===
__global__ void winbuild_kernel(const float* __restrict__ x, float* __restrict__ win) {
  int idx = blockIdx.x * 256 + threadIdx.x; // float4 index
  int s4 = idx & 31;
  int row = idx >> 5;
  int t = row & (cL - 1), b = row >> 10;
  int j = s4 >> 3, c4 = s4 & 7;
  float4 v = make_float4(0.f, 0.f, 0.f, 0.f);
  if (j < 3) {
    int ts = (t + j + cL - 1) & (cL - 1);
    v = *(const float4*)&x[((long)b * cL + ts) * cCIN + c4 * 4];
  }
  ((float4*)win)[idx] = v;
}

// ================= batched transpose: in [B][1024][512] -> out [B][512][1024] =====
__global__ __launch_bounds__(256) void transpose_kernel(const float* __restrict__ in,
                                                        float* __restrict__ out) {
  __shared__ float tile[32][33];
  int b = blockIdx.z;
  int c0 = blockIdx.x * 32, t0 = blockIdx.y * 32;
  in += (long)b * cL * cDM;
  out += (long)b * cL * cDM;
  int tx = threadIdx.x & 31, ty = threadIdx.x >> 5;
#pragma unroll
  for (int r = 0; r < 32; r += 8) tile[ty + r][tx] = in[(long)(t0 + ty + r) * cDM + c0 + tx];
  __syncthreads();
#pragma unroll
  for (int r = 0; r < 32; r += 8)
    out[(long)(c0 + ty + r) * cL + t0 + tx] = tile[tx][ty + r];
}

// ================= moving-average decomposition =================
__global__ void decomp_kernel(const float* __restrict__ x, float* __restrict__ seasonal,
                              float* __restrict__ ma_out, int total, int C) {
  int idx = blockIdx.x * 256 + threadIdx.x;
  if (idx >= total) return;
  int c = idx % C;
  int t = (idx / C) & (cL - 1);
  long base = (long)(idx / (C * cL)) * cL * C + c;
  float s = 0.f;
#pragma unroll
  for (int j = -12; j <= 12; j++) {
    int tt = t + j;
    tt = tt < 0 ? 0 : (tt >= cL ? cL - 1 : tt);
    s += x[base + (long)tt * C];
  }
  float ma = s * (1.0f / 25.0f);
  if (seasonal) seasonal[idx] = x[idx] - ma;
  if (ma_out) ma_out[idx] = ma;
}

// ================= trend projection: circular conv3 DM->CIN via WJt, accumulating ===
__global__ void trendconv_kernel(const float* __restrict__ ma, const float* __restrict__ WJt,
                                 float* __restrict__ trend) {
  int idx = blockIdx.x * 256 + threadIdx.x;
  int o = idx & (cCIN - 1);
  int t = (idx >> 5) & (cL - 1);
  int b = idx >> 15;
  const float* xb = ma + (long)b * cL * cDM;
  int tm = (t + cL - 1) & (cL - 1), tp = (t + 1) & (cL - 1);
  const float4* r0 = (const float4*)(xb + (long)tm * cDM);
  const float4* r1 = (const float4*)(xb + (long)t * cDM);
  const float4* r2 = (const float4*)(xb + (long)tp * cDM);
  const float4* w0 = (const float4*)(WJt + (long)(0 * 32 + o) * cDM);
  const float4* w1 = (const float4*)(WJt + (long)(1 * 32 + o) * cDM);
  const float4* w2 = (const float4*)(WJt + (long)(2 * 32 + o) * cDM);
  float sx = 0.f, sy = 0.f, sz = 0.f, sw = 0.f;
  for (int c4 = 0; c4 < cDM / 4; c4++) {
    float4 a = r0[c4], b4 = r1[c4], d = r2[c4];
    float4 u = w0[c4], v = w1[c4], w = w2[c4];
    sx += a.x * u.x + b4.x * v.x + d.x * w.x;
    sy += a.y * u.y + b4.y * v.y + d.y * w.y;
    sz += a.z * u.z + b4.z * v.z + d.z * w.z;
    sw += a.w * u.w + b4.w * v.w + d.w * w.w;
  }
  trend[idx] += sx + sy + sz + sw;
}

// ================= final time projection, LDS-staged =================
__global__ __launch_bounds__(256) void p2_kernel(const float* __restrict__ x,
                                                 const float* __restrict__ W,
                                                 const float* __restrict__ bias,
                                                 float* __restrict__ out) {
  __shared__ float tile[256 * 32];
  int b = blockIdx.x;
  int p0 = blockIdx.y * 8;
  int c = threadIdx.x & 31, pl = threadIdx.x >> 5;
  const float* xb = x + (long)b * cL * cCIN;
  const float* w = W + (long)(p0 + pl) * cL;
  float s = 0.f;
  for (int l0 = 0; l0 < cL; l0 += 256) {
    __syncthreads();
    for (int i = threadIdx.x; i < 256 * 32; i += 256) tile[i] = xb[(long)l0 * 32 + i];
    __syncthreads();
#pragma unroll 8
    for (int l = 0; l < 256; l++) s += tile[l * 32 + c] * w[l0 + l];
  }
  out[((long)b * cPRED + p0 + pl) * cCIN + c] = s + bias[p0 + pl];
}

// ================= per-(h,mode) complex mode mix =================
__global__ __launch_bounds__(256) void modemix_kernel(const float* __restrict__ F,
                                                      const float* __restrict__ W,
                                                      float* __restrict__ out, float scale) {
  int b = blockIdx.x, h = blockIdx.y;
  __shared__ float2 Fs[cE][cM];
  const float* Fb = F + ((long)b * cDM + h * cE) * M2;
  for (int i = threadIdx.x; i < cE * cM; i += 256) {
    int e = i >> 6, x = i & 63;
    Fs[e][x] = ((const float2*)(Fb + (long)e * M2))[x];
  }
  __syncthreads();
  int x = threadIdx.x & 63, og = threadIdx.x >> 6;
  float2 acc[16];
#pragma unroll
  for (int i = 0; i < 16; i++) acc[i] = make_float2(0.f, 0.f);
  for (int e = 0; e < cE; e++) {
    float2 f = Fs[e][x];
#pragma unroll
    for (int i = 0; i < 16; i++) {
      int o = og * 16 + i;
      const float2 w = *(const float2*)(W + ((((long)h * cE + e) * cE + o) * cM + x) * 2);
      acc[i].x += f.x * w.x - f.y * w.y;
      acc[i].y += f.x * w.y + f.y * w.x;
    }
  }
  float* ob = out + ((long)b * cDM + h * cE) * M2;
#pragma unroll
  for (int i = 0; i < 16; i++) {
    int o = og * 16 + i;
    ((float2*)(ob + (long)o * M2))[x] = make_float2(acc[i].x * scale, acc[i].y * scale);
  }
}

// ================= fourier_cross =================
__global__ __launch_bounds__(256) void crossqk_kernel(const float* __restrict__ Fq,
                                                      const float* __restrict__ Fk,
                                                      float* __restrict__ QKb) {
  int b = blockIdx.x, h = blockIdx.y;
  __shared__ float2 Ks[cE][cM];
  const float* kb = Fk + ((long)b * cDM + h * cE) * M2;
  for (int i = threadIdx.x; i < cE * cM; i += 256) {
    int e = i >> 6, y = i & 63;
    Ks[e][y] = ((const float2*)(kb + (long)e * M2))[y];
  }
  __syncthreads();
  int x = threadIdx.x & 63, yg = threadIdx.x >> 6;
  const float* qb = Fq + ((long)b * cDM + h * cE) * M2;
  float2 acc[16];
#pragma unroll
  for (int i = 0; i < 16; i++) acc[i] = make_float2(0.f, 0.f);
  for (int e = 0; e < cE; e++) {
    float2 q = ((const float2*)(qb + (long)e * M2))[x];
#pragma unroll
    for (int i = 0; i < 16; i++) {
      float2 k = Ks[e][yg * 16 + i];
      acc[i].x += q.x * k.x - q.y * k.y;
      acc[i].y += q.x * k.y + q.y * k.x;
    }
  }
  float2* qkb = (float2*)(QKb) + (((long)b * cH + h) * cM * cM);
#pragma unroll
  for (int i = 0; i < 16; i++) {
    int y = yg * 16 + i;
    float a = acc[i].x, bi = acc[i].y;
    float re, im;
    float t2a = 2.f * a;
    if (fabsf(t2a) > 60.f) {
      re = t2a > 0.f ? 1.f : -1.f;
      im = 0.f;
    } else {
      float denom = coshf(t2a) + cosf(2.f * bi);
      re = sinhf(t2a) / denom;
      im = sinf(2.f * bi) / denom;
    }
    qkb[x * cM + y] = make_float2(re, im);
  }
}

__global__ __launch_bounds__(256) void crossqkv_kernel(const float* __restrict__ QKb,
                                                       const float* __restrict__ Fk,
                                                       float* __restrict__ Fq) {
  int b = blockIdx.x, h = blockIdx.y;
  __shared__ float2 qks[cM][cM];
  const float2* qkb = (const float2*)(QKb) + (((long)b * cH + h) * cM * cM);
  for (int i = threadIdx.x; i < cM * cM; i += 256) qks[i >> 6][i & 63] = qkb[i];
  __syncthreads();
  int e = threadIdx.x & 63, xg = threadIdx.x >> 6;
  const float* kb = Fk + ((long)b * cDM + h * cE) * M2;
  float2 acc[16];
#pragma unroll
  for (int i = 0; i < 16; i++) acc[i] = make_float2(0.f, 0.f);
  for (int y = 0; y < cM; y++) {
    float2 k = ((const float2*)(kb + (long)e * M2))[y];
#pragma unroll
    for (int i = 0; i < 16; i++) {
      float2 qk = qks[xg * 16 + i][y];
      acc[i].x += qk.x * k.x - qk.y * k.y;
      acc[i].y += qk.x * k.y + qk.y * k.x;
    }
  }
  float* ob = Fq + ((long)b * cDM + h * cE) * M2;
#pragma unroll
  for (int i = 0; i < 16; i++) {
    int x = xg * 16 + i;
    ((float2*)(ob + (long)e * M2))[x] = acc[i];
  }
}

// ================= f32 shader GEMM (small finals: p1) =================
constexpr int GBM = 128, GBN = 128, GBK = 16, LPAD = 132;

__global__ __launch_bounds__(256) void gemm_kernel(const float* __restrict__ A,
                                                   const float* __restrict__ B,
                                                   const float* __restrict__ bias,
                                                   const float* __restrict__ addend,
                                                   float* __restrict__ C, int M, int N, int K,
                                                   int relu) {
  __shared__ float As[GBK][LPAD];
  __shared__ float Bs[GBK][LPAD];
  int n0 = blockIdx.x * GBN, m0 = blockIdx.y * GBM;
  int tid = threadIdx.x;
  int tx = tid & 15, ty = tid >> 4;
  float acc[8][8];
#pragma unroll
  for (int i = 0; i < 8; i++)
#pragma unroll
    for (int j = 0; j < 8; j++) acc[i][j] = 0.f;

  for (int k0 = 0; k0 < K; k0 += GBK) {
#pragma unroll
    for (int p = 0; p < 8; p++) {
      int i = p * 256 + tid;
      int mm = i >> 4, kk = i & 15;
      int gm = m0 + mm;
      As[kk][mm] = (gm < M && k0 + kk < K) ? A[(long)gm * K + k0 + kk] : 0.f;
    }
#pragma unroll
    for (int p = 0; p < 8; p++) {
      int i = p * 256 + tid;
      int nn = i >> 4, kk = i & 15;
      int gn = n0 + nn;
      Bs[kk][nn] = (gn < N && k0 + kk < K) ? B[(long)gn * K + k0 + kk] : 0.f;
    }
    __syncthreads();
#pragma unroll
    for (int kk = 0; kk < GBK; kk++) {
      float a[8], bb[8];
      *(float4*)&a[0] = *(const float4*)&As[kk][ty * 8];
      *(float4*)&a[4] = *(const float4*)&As[kk][ty * 8 + 4];
      *(float4*)&bb[0] = *(const float4*)&Bs[kk][tx * 8];
      *(float4*)&bb[4] = *(const float4*)&Bs[kk][tx * 8 + 4];
#pragma unroll
      for (int i = 0; i < 8; i++)
#pragma unroll
        for (int j = 0; j < 8; j++) acc[i][j] += a[i] * bb[j];
    }
    __syncthreads();
  }

  for (int i = 0; i < 8; i++) {
    int gm = m0 + ty * 8 + i;
    if (gm >= M) break;
    long rowoff = (long)gm * N;
    for (int j = 0; j < 8; j++) {
      int gn = n0 + tx * 8 + j;
      if (gn < N) {
        float v = acc[i][j];
        if (bias) v += bias[gn];
        if (addend) v += addend[rowoff + gn];
        if (relu) v = fmaxf(v, 0.f);
        C[rowoff + gn] = v;
      }
    }
  }
}

// ================= bf16 MFMA GEMM: C = A @ B^T, f32 in/out, cvt in staging ==========
// Tile 128x128xK64, 4 waves, per-wave 64x64 via 4x4 frags of 16x16x32.
// Epilogue extras: bias[N], addend[M,ldc], pe (pos-emb, row t=gr&1023), Nreal col mask, ldc.
constexpr int TAPAD = 72;

__global__ __launch_bounds__(256) void mfma_gemm(const float* __restrict__ A,
                                                 const float* __restrict__ B,
                                                 const float* __restrict__ bias,
                                                 const float* __restrict__ addend,
                                                 const float* __restrict__ pe,
                                                 float* __restrict__ C, int M, int N, int K,
                                                 long sA, long sB, long sC, int relu, int Nreal,
                                                 int ldc) {
  __shared__ short As[128 * TAPAD];
  __shared__ short Bs[128 * TAPAD];
  int z = blockIdx.z;
  A += (long)z * sA;
  B += (long)z * sB;
  C += (long)z * sC;
  const float* Ad = addend ? addend + (long)z * sC : nullptr;
  int n0 = blockIdx.x * 128, m0 = blockIdx.y * 128;
  int tid = threadIdx.x;
  int lane = tid & 63;
  int w = tid >> 6;
  int wm = w & 1, wn = w >> 1;
  int lr = lane & 15, lg = lane >> 4;

  float4v acc[4][4];
#pragma unroll
  for (int i = 0; i < 4; i++)
#pragma unroll
    for (int j = 0; j < 4; j++) acc[i][j] = (float4v){0.f, 0.f, 0.f, 0.f};

  for (int k0 = 0; k0 < K; k0 += 64) {
#pragma unroll
    for (int p = 0; p < 8; p++) {
      int fi = p * 256 + tid;
      int row = fi >> 4;
      int c4 = fi & 15;
      float4 v = *(const float4*)&A[(long)(m0 + row) * K + k0 + c4 * 4];
      unsigned int lo = (unsigned int)f2bf(v.x) | ((unsigned int)f2bf(v.y) << 16);
      unsigned int hi = (unsigned int)f2bf(v.z) | ((unsigned int)f2bf(v.w) << 16);
      *(uint2*)&As[row * TAPAD + c4 * 4] = make_uint2(lo, hi);
    }
#pragma unroll
    for (int p = 0; p < 8; p++) {
      int fi = p * 256 + tid;
      int row = fi >> 4;
      int c4 = fi & 15;
      float4 v = *(const float4*)&B[(long)(n0 + row) * K + k0 + c4 * 4];
      unsigned int lo = (unsigned int)f2bf(v.x) | ((unsigned int)f2bf(v.y) << 16);
      unsigned int hi = (unsigned int)f2bf(v.z) | ((unsigned int)f2bf(v.w) << 16);
      *(uint2*)&Bs[row * TAPAD + c4 * 4] = make_uint2(lo, hi);
    }
    __syncthreads();
#pragma unroll
    for (int ks = 0; ks < 2; ks++) {
      short8v af[4], bf[4];
#pragma unroll
      for (int mi = 0; mi < 4; mi++)
        af[mi] = *(const short8v*)&As[(wm * 64 + mi * 16 + lr) * TAPAD + ks * 32 + lg * 8];
#pragma unroll
      for (int ni = 0; ni < 4; ni++)
        bf[ni] = *(const short8v*)&Bs[(wn * 64 + ni * 16 + lr) * TAPAD + ks * 32 + lg * 8];
#pragma unroll
      for (int mi = 0; mi < 4; mi++)
#pragma unroll
        for (int ni = 0; ni < 4; ni++)
          acc[mi][ni] =
              __builtin_amdgcn_mfma_f32_16x16x32_bf16(af[mi], bf[ni], acc[mi][ni], 0, 0, 0);
    }
    __syncthreads();
  }

#pragma unroll
  for (int mi = 0; mi < 4; mi++) {
#pragma unroll
    for (int i = 0; i < 4; i++) {
      int gr = m0 + wm * 64 + mi * 16 + lg * 4 + i;
      long rowoff = (long)gr * ldc;
#pragma unroll
      for (int ni = 0; ni < 4; ni++) {
        int gc = n0 + wn * 64 + ni * 16 + lr;
        if (gc < Nreal) {
          float v = acc[mi][ni][i];
          if (bias) v += bias[gc];
          if (pe) v += pe[((gr & (cL - 1)) << 9) + gc];
          if (Ad) v += Ad[rowoff + gc];
          if (relu) v = fmaxf(v, 0.f);
          C[rowoff + gc] = v;
        }
      }
    }
  }
}

} // namespace

extern "C" void kernel_launch(void* const* d_in, const int* in_sizes, int n_in, void* d_out,
                              int out_size, void* d_ws, size_t ws_size, hipStream_t stream) {
  const float* x_enc = (const float*)d_in[0];
  const float* tok_W = (const float*)d_in[1];
  const float* enc_Wq = (const float*)d_in[2];
  const float* enc_Wo = (const float*)d_in[5];
  const float* enc_bq = (const float*)d_in[6];
  const float* enc_bo = (const float*)d_in[9];
  const float* dsWq = (const float*)d_in[10];
  const float* dsWo = (const float*)d_in[13];
  const float* dsbq = (const float*)d_in[14];
  const float* dsbo = (const float*)d_in[17];
  const float* dcWq = (const float*)d_in[18];
  const float* dcWk = (const float*)d_in[19];
  const float* dcWo = (const float*)d_in[21];
  const float* dcbq = (const float*)d_in[22];
  const float* dcbk = (const float*)d_in[23];
  const float* dcbo = (const float*)d_in[25];
  const float* enc_c1W = (const float*)d_in[26];
  const float* enc_c1b = (const float*)d_in[27];
  const float* enc_c2W = (const float*)d_in[28];
  const float* enc_c2b = (const float*)d_in[29];
  const float* dec_c1W = (const float*)d_in[30];
  const float* dec_c1b = (const float*)d_in[31];
  const float* dec_c2W = (const float*)d_in[32];
  const float* dec_c2b = (const float*)d_in[33];
  const float* dec_trW = (const float*)d_in[34];
  const float* fb_enc = (const float*)d_in[35];
  const float* fb_dec = (const float*)d_in[36];
  const float* fc_w = (const float*)d_in[37];
  const float* p1W = (const float*)d_in[38];
  const float* p1b = (const float*)d_in[39];
  const float* p2W = (const float*)d_in[40];
  const float* p2b = (const float*)d_in[41];
  const float* p3W = (const float*)d_in[42];
  const float* p3b = (const float*)d_in[43];

  auto need_bytes = [&](int BG, long RH) -> size_t {
    long G = (long)BG * cL * cDM;
    long tot = 2L * M2 * cL + (long)cL * cDM /*pe*/ + 180352 /*prep*/ + 4 * G + RH * cDFF +
               G / 4 /*win*/ + 2L * BG * cDM * M2 + (long)BG * cH * cM * cM * 2 +
               3L * BG * cL * cCIN;
    return (size_t)tot * 4;
  };
  int BG = cB;
  long RH = 2048;
  while (BG > 1 && need_bytes(BG, RH) > ws_size) BG >>= 1;
  while (RH > 256 && need_bytes(BG, RH) > ws_size) RH >>= 1;
  if (RH > (long)BG * cL) RH = (long)BG * cL;

  long G = (long)BG * cL * cDM;
  float* ws = (float*)d_ws;
  long off = 0;
  float* basisd = ws + off; off += (long)M2 * cL;
  float* basisi = ws + off; off += (long)cL * M2;
  float* pe = ws + off; off += (long)cL * cDM;
  float* Bpad = ws + off; off += 512 * 128;
  float* WJt = ws + off; off += 3 * 32 * 512;
  float* p3pad = ws + off; off += 128 * 512;
  float* p3bpad = ws + off; off += 128;
  float* ENC = ws + off; off += G;
  float* X = ws + off; off += G;
  float* A = ws + off; off += G;
  float* S = ws + off; off += G;
  float* HD = ws + off; off += RH * cDFF;
  float* win = ws + off; off += G / 4;
  float* Fq = ws + off; off += (long)BG * cDM * M2;
  float* Fk = ws + off; off += (long)BG * cDM * M2;
  float* QKb = ws + off; off += (long)BG * cH * cM * cM * 2;
  float* TRD = ws + off; off += (long)BG * cL * cCIN;
  float* O1 = ws + off; off += (long)BG * cL * cCIN;
  float* O2 = ws + off; off += (long)BG * cL * cCIN;

  auto mgemm = [&](const float* Am, const float* Bm, const float* bias, const float* add,
                   const float* peA, float* C, int Mm, int Nn, int Kk, long sA, long sB, long sC,
                   int batch, int relu, int Nreal, int ldc) {
    dim3 g(Nn / 128, Mm / 128, batch);
    mfma_gemm<<<g, 256, 0, stream>>>(Am, Bm, bias, add, peA, C, Mm, Nn, Kk, sA, sB, sC, relu,
                                     Nreal, ldc);
  };
  // dft via transpose (xin [BG][1024][512] -> xt [BG][512][1024]) + MFMA NT
  auto dftT = [&](const float* xin, float* xt, float* F) {
    transpose_kernel<<<dim3(16, 32, BG), 256, 0, stream>>>(xin, xt);
    mgemm(xt, basisd, nullptr, nullptr, nullptr, F, cDM, M2, cL, (long)cDM * cL, 0,
          (long)cDM * M2, BG, 0, M2, M2);
  };
  auto idft = [&](const float* F, float* o) {
    mgemm(basisi, F, nullptr, nullptr, nullptr, o, cL, cDM, M2, 0, (long)cDM * M2, (long)cL * cDM,
          BG, 0, cDM, cDM);
  };
  auto decomp = [&](const float* x, float* seasonal, float* ma, long total, int C_) {
    decomp_kernel<<<(total + 255) / 256, 256, 0, stream>>>(x, seasonal, ma, (int)total, C_);
  };
  auto ffn = [&](const float* in, float* out, const float* c1W, const float* c1b,
                 const float* c2W, const float* c2b) {
    long R = (long)BG * cL;
    for (long r = 0; r < R; r += RH) {
      long o2 = r * cDM;
      mgemm(in + o2, c1W, c1b, nullptr, nullptr, HD, (int)RH, cDFF, cDM, 0, 0, 0, 1, 1, cDFF,
            cDFF);
      mgemm(HD, c2W, c2b, in + o2, nullptr, out + o2, (int)RH, cDM, cDFF, 0, 0, 0, 1, 0, cDM,
            cDM);
    }
  };
  auto trendconv = [&](const float* ma) {
    trendconv_kernel<<<((long)BG * cL * cCIN) / 256, 256, 0, stream>>>(ma, WJt, TRD);
  };
  auto mix = [&](float* F, const float* W, float scale) {
    modemix_kernel<<<dim3(BG, cH), 256, 0, stream>>>(F, W, F, scale);
  };

  // ---- one-time setup ----
  basis_kernel<<<(M2 * cL) / 256, 256, 0, stream>>>(basisd, basisi);
  pe_kernel<<<(cL * cDM) / 256, 256, 0, stream>>>(pe);
  prep_kernel<<<256, 256, 0, stream>>>(tok_W, dec_trW, p3W, p3b, Bpad, WJt, p3pad, p3bpad);

  for (int b0 = 0; b0 < cB; b0 += BG) {
    const float* xg = x_enc + (long)b0 * cL * cCIN;
    long GBL = (long)BG * cL;

    decomp(xg, nullptr, TRD, GBL * cCIN, cCIN);
    // embedding: win-gemm + pos-emb epilogue
    winbuild_kernel<<<(int)(GBL * cCIN / 256), 256, 0, stream>>>(xg, win);
    mgemm(win, Bpad, nullptr, nullptr, pe, ENC, (int)GBL, cDM, 128, 0, 0, 0, 1, 0, cDM, cDM);

    // ---- encoder ----
    for (int l = 0; l < 2; l++) {
      const float* Wq = enc_Wq + (long)l * cDM * cDM;
      const float* Wo = enc_Wo + (long)l * cDM * cDM;
      mgemm(ENC, Wq, enc_bq + l * cDM, nullptr, nullptr, X, (int)GBL, cDM, cDM, 0, 0, 0, 1, 0,
            cDM, cDM);
      dftT(X, S, Fq);      // S free during encoder
      mix(Fq, fb_enc, 1.0f);
      idft(Fq, X);
      mgemm(X, Wo, enc_bo + l * cDM, ENC, nullptr, A, (int)GBL, cDM, cDM, 0, 0, 0, 1, 0, cDM,
            cDM);
      decomp(A, X, nullptr, GBL * cDM, cDM);
      ffn(X, A, enc_c1W + (long)l * cDFF * cDM, enc_c1b + l * cDFF,
          enc_c2W + (long)l * cDM * cDFF, enc_c2b + l * cDM);
      decomp(A, ENC, nullptr, GBL * cDM, cDM);
    }

    // ---- decoder ----
    mgemm(ENC, dsWq, dsbq, nullptr, nullptr, X, (int)GBL, cDM, cDM, 0, 0, 0, 1, 0, cDM, cDM);
    dftT(X, S, Fq);        // S free until it holds ma below
    mix(Fq, fb_dec, 1.0f);
    idft(Fq, X);
    mgemm(X, dsWo, dsbo, ENC, nullptr, A, (int)GBL, cDM, cDM, 0, 0, 0, 1, 0, cDM, cDM); // x1
    decomp(A, X, S, GBL * cDM, cDM);   // x2 -> X, ma -> S
    trendconv(S);                       // t1

    mgemm(X, dcWq, dcbq, nullptr, nullptr, A, (int)GBL, cDM, cDM, 0, 0, 0, 1, 0, cDM, cDM); // q2
    mgemm(ENC, dcWk, dcbk, nullptr, nullptr, S, (int)GBL, cDM, cDM, 0, 0, 0, 1, 0, cDM, cDM); // k
    dftT(A, ENC, Fq);      // ENC dead (cross k consumed it)
    dftT(S, A, Fk);        // A (=q2) dead after its dft
    crossqk_kernel<<<dim3(BG, cH), 256, 0, stream>>>(Fq, Fk, QKb);
    crossqkv_kernel<<<dim3(BG, cH), 256, 0, stream>>>(QKb, Fk, Fq);
    mix(Fq, fc_w, 1.0f / (float)(cDM * cDM));
    idft(Fq, A);
    mgemm(A, dcWo, dcbo, X, nullptr, ENC, (int)GBL, cDM, cDM, 0, 0, 0, 1, 0, cDM, cDM); // x3
    decomp(ENC, A, X, GBL * cDM, cDM);  // x4 -> A, ma -> X
    trendconv(X);                        // t2

    ffn(A, ENC, dec_c1W, dec_c1b, dec_c2W, dec_c2b);   // x4 + y -> ENC
    decomp(ENC, X, A, GBL * cDM, cDM);  // x5 -> X, ma -> A
    trendconv(A);                        // t3

    // ---- final projections ----
    mgemm(X, p3pad, p3bpad, TRD, nullptr, O1, (int)GBL, 128, cDM, 0, 0, 0, 1, 0, cCIN, cCIN);
    {
      dim3 g(1, (GBL + GBM - 1) / GBM, 1);
      gemm_kernel<<<g, 256, 0, stream>>>(O1, p1W, p1b, nullptr, O2, (int)GBL, cCIN, cCIN, 0);
    }
    p2_kernel<<<dim3(BG, 32), 256, 0, stream>>>(O2, p2W, p2b,
                                                (float*)d_out + (long)b0 * cPRED * cCIN);
  }
}

// Round 5
// 5279.115 us; speedup vs baseline: 9.2361x; 3.8335x over previous
//
#include <hip/hip_runtime.h>
#include <math.h>

namespace {

constexpr int cB = 32, cL = 1024, cCIN = 32, cDM = 512, cDFF = 2048;
constexpr int cH = 8, cE = 64, cM = 64, cPRED = 256;
constexpr int M2 = 2 * cM; // 128

typedef __attribute__((ext_vector_type(8))) short short8v;
typedef __attribute__((ext_vector_type(4))) float float4v;

__device__ inline unsigned short f2bf(float f) {
  unsigned int u = __builtin_bit_cast(unsigned int, f);
  u += 0x7FFFu + ((u >> 16) & 1u); // RNE
  return (unsigned short)(u >> 16);
}

typedef const __attribute__((address_space(1))) unsigned int gu32_t;
typedef __attribute__((address_space(3))) unsigned int lu32_t;
__device__ inline void gld16(const void* g, void* l) {
  __builtin_amdgcn_global_load_lds((gu32_t*)g, (lu32_t*)l, 16, 0, 0);
}

// ================= one-time tables =================
__global__ void basis_kernel(short* __restrict__ basisdb, short* __restrict__ basisib) {
  int idx = blockIdx.x * 256 + threadIdx.x;
  if (idx >= M2 * cL) return;
  int t = idx & (cL - 1);
  int m2 = idx >> 10;
  int m = m2 >> 1;
  float ang = 6.2831853071795864f * (float)((m * t) & (cL - 1)) / (float)cL;
  float cv = cosf(ang), sv = sinf(ang);
  float vd = (m2 & 1) ? -sv : cv;
  basisdb[idx] = (short)f2bf(vd);
  float s = (m == 0) ? ((m2 & 1) ? 0.f : (1.f / (float)cL)) : (2.f / (float)cL);
  basisib[t * M2 + m2] = (short)f2bf(vd * s);
}

__global__ void pe_kernel(float* __restrict__ pe) {
  int idx = blockIdx.x * 256 + threadIdx.x;
  int o = idx & (cDM - 1), t = idx >> 9;
  int i = o >> 1;
  float freq = __expf((float)(2 * i) * (-9.210340371976184f / (float)cDM));
  float ang = freq * (float)t;
  pe[idx] = (o & 1) ? cosf(ang) : sinf(ang);
}

__global__ void cvt_kernel(const float* __restrict__ in, short* __restrict__ out, int n) {
  for (int i = blockIdx.x * 256 + threadIdx.x; i < n; i += gridDim.x * 256)
    out[i] = (short)f2bf(in[i]);
}

// Bpadb[o][j*32+c]=tok_W[o][c][j]; Wtr3b[o][j*512+c]=trW[o][c][j] (o<32); p3padb; p3bpadf
__global__ void prep_kernel(const float* __restrict__ tok_W, const float* __restrict__ trW,
                            const float* __restrict__ p3W, const float* __restrict__ p3b,
                            short* __restrict__ Bpadb, short* __restrict__ Wtr3b,
                            short* __restrict__ p3padb, float* __restrict__ p3bpadf) {
  int idx = blockIdx.x * 256 + threadIdx.x;
  if (idx < 512 * 128) {
    int o = idx >> 7, s = idx & 127, j = s >> 5, c = s & 31;
    Bpadb[idx] = (j < 3) ? (short)f2bf(tok_W[o * 96 + c * 3 + j]) : (short)0;
  }
  if (idx < 128 * 1536) {
    int o = idx / 1536, r = idx % 1536, j = r >> 9, c = r & 511;
    Wtr3b[idx] = (o < 32) ? (short)f2bf(trW[(long)o * 1536 + c * 3 + j]) : (short)0;
  }
  if (idx < 128 * 512) {
    int o = idx >> 9, k = idx & 511;
    p3padb[idx] = (o < 32) ? (short)f2bf(p3W[o * 512 + k]) : (short)0;
  }
  if (idx < 128) p3bpadf[idx] = (idx < 32) ? p3b[idx] : 0.f;
}

// win[row][128] bf16 = [x[t-1,:], x[t,:], x[t+1,:], 0] circular
__global__ void winbuild_kernel(const float* __restrict__ x, short* __restrict__ win) {
  int idx = blockIdx.x * 256 + threadIdx.x; // over rows*32
  int s4 = idx & 31;
  int row = idx >> 5;
  int t = row & (cL - 1), b = row >> 10;
  int j = s4 >> 3, c4 = s4 & 7;
  unsigned int lo = 0, hi = 0;
  if (j < 3) {
    int ts = (t + j + cL - 1) & (cL - 1);
    float4 v = *(const float4*)&x[((long)b * cL + ts) * cCIN + c4 * 4];
    lo = (unsigned int)f2bf(v.x) | ((unsigned int)f2bf(v.y) << 16);
    hi = (unsigned int)f2bf(v.z) | ((unsigned int)f2bf(v.w) << 16);
  }
  *(uint2*)&win[row * 128 + s4 * 4] = make_uint2(lo, hi);
}

// batched bf16 transpose: in [B][1024][512] -> out [B][512][1024]
__global__ __launch_bounds__(256) void transpose_bf(const short* __restrict__ in,
                                                    short* __restrict__ out) {
  __shared__ short tile[32][33];
  int b = blockIdx.z;
  in += (long)b * cL * cDM;
  out += (long)b * cL * cDM;
  int c0 = blockIdx.x * 32, t0 = blockIdx.y * 32;
  int tx = threadIdx.x & 31, ty = threadIdx.x >> 5;
#pragma unroll
  for (int r = 0; r < 32; r += 8) tile[ty + r][tx] = in[(long)(t0 + ty + r) * cDM + c0 + tx];
  __syncthreads();
#pragma unroll
  for (int r = 0; r < 32; r += 8)
    out[(long)(c0 + ty + r) * cL + t0 + tx] = tile[tx][ty + r];
}

// ================= moving-average decomposition (f32 + optional bf16 shadows) =========
__global__ void decomp_kernel(const float* __restrict__ x, float* __restrict__ sf,
                              short* __restrict__ sb, float* __restrict__ maf,
                              short* __restrict__ mab, int total, int C) {
  int idx = blockIdx.x * 256 + threadIdx.x;
  if (idx >= total) return;
  int c = idx % C;
  int t = (idx / C) & (cL - 1);
  long base = (long)(idx / (C * cL)) * cL * C + c;
  float s = 0.f;
#pragma unroll
  for (int j = -12; j <= 12; j++) {
    int tt = t + j;
    tt = tt < 0 ? 0 : (tt >= cL ? cL - 1 : tt);
    s += x[base + (long)tt * C];
  }
  float ma = s * (1.0f / 25.0f);
  float se = x[idx] - ma;
  if (sf) sf[idx] = se;
  if (sb) sb[idx] = (short)f2bf(se);
  if (maf) maf[idx] = ma;
  if (mab) mab[idx] = (short)f2bf(ma);
}

// ================= final time projection =================
__global__ __launch_bounds__(256) void p2_kernel(const float* __restrict__ x,
                                                 const float* __restrict__ W,
                                                 const float* __restrict__ bias,
                                                 float* __restrict__ out) {
  __shared__ float tile[256 * 32];
  int b = blockIdx.x;
  int p0 = blockIdx.y * 8;
  int c = threadIdx.x & 31, pl = threadIdx.x >> 5;
  const float* xb = x + (long)b * cL * cCIN;
  const float* w = W + (long)(p0 + pl) * cL;
  float s = 0.f;
  for (int l0 = 0; l0 < cL; l0 += 256) {
    __syncthreads();
    for (int i = threadIdx.x; i < 256 * 32; i += 256) tile[i] = xb[(long)l0 * 32 + i];
    __syncthreads();
#pragma unroll 8
    for (int l = 0; l < 256; l++) s += tile[l * 32 + c] * w[l0 + l];
  }
  out[((long)b * cPRED + p0 + pl) * cCIN + c] = s + bias[p0 + pl];
}

// ================= per-(h,mode) complex mode mix (+ optional bf16 out) =================
__global__ __launch_bounds__(256) void modemix_kernel(const float* __restrict__ F,
                                                      const float* __restrict__ W,
                                                      float* __restrict__ out,
                                                      short* __restrict__ outb, float scale) {
  int b = blockIdx.x, h = blockIdx.y;
  __shared__ float2 Fs[cE][cM];
  const float* Fb = F + ((long)b * cDM + h * cE) * M2;
  for (int i = threadIdx.x; i < cE * cM; i += 256) {
    int e = i >> 6, x = i & 63;
    Fs[e][x] = ((const float2*)(Fb + (long)e * M2))[x];
  }
  __syncthreads();
  int x = threadIdx.x & 63, og = threadIdx.x >> 6;
  float2 acc[16];
#pragma unroll
  for (int i = 0; i < 16; i++) acc[i] = make_float2(0.f, 0.f);
  for (int e = 0; e < cE; e++) {
    float2 f = Fs[e][x];
#pragma unroll
    for (int i = 0; i < 16; i++) {
      int o = og * 16 + i;
      const float2 w = *(const float2*)(W + ((((long)h * cE + e) * cE + o) * cM + x) * 2);
      acc[i].x += f.x * w.x - f.y * w.y;
      acc[i].y += f.x * w.y + f.y * w.x;
    }
  }
  long ob = ((long)b * cDM + h * cE) * M2;
#pragma unroll
  for (int i = 0; i < 16; i++) {
    int o = og * 16 + i;
    float rx = acc[i].x * scale, ry = acc[i].y * scale;
    ((float2*)(out + ob + (long)o * M2))[x] = make_float2(rx, ry);
    if (outb) {
      unsigned int pk = (unsigned int)f2bf(rx) | ((unsigned int)f2bf(ry) << 16);
      *(unsigned int*)&outb[ob + (long)o * M2 + 2 * x] = pk;
    }
  }
}

// ================= fourier_cross =================
__global__ __launch_bounds__(256) void crossqk_kernel(const float* __restrict__ Fq,
                                                      const float* __restrict__ Fk,
                                                      float* __restrict__ QKb) {
  int b = blockIdx.x, h = blockIdx.y;
  __shared__ float2 Ks[cE][cM];
  const float* kb = Fk + ((long)b * cDM + h * cE) * M2;
  for (int i = threadIdx.x; i < cE * cM; i += 256) {
    int e = i >> 6, y = i & 63;
    Ks[e][y] = ((const float2*)(kb + (long)e * M2))[y];
  }
  __syncthreads();
  int x = threadIdx.x & 63, yg = threadIdx.x >> 6;
  const float* qb = Fq + ((long)b * cDM + h * cE) * M2;
  float2 acc[16];
#pragma unroll
  for (int i = 0; i < 16; i++) acc[i] = make_float2(0.f, 0.f);
  for (int e = 0; e < cE; e++) {
    float2 q = ((const float2*)(qb + (long)e * M2))[x];
#pragma unroll
    for (int i = 0; i < 16; i++) {
      float2 k = Ks[e][yg * 16 + i];
      acc[i].x += q.x * k.x - q.y * k.y;
      acc[i].y += q.x * k.y + q.y * k.x;
    }
  }
  float2* qkb = (float2*)(QKb) + (((long)b * cH + h) * cM * cM);
#pragma unroll
  for (int i = 0; i < 16; i++) {
    int y = yg * 16 + i;
    float a = acc[i].x, bi = acc[i].y;
    float re, im;
    float t2a = 2.f * a;
    if (fabsf(t2a) > 60.f) {
      re = t2a > 0.f ? 1.f : -1.f;
      im = 0.f;
    } else {
      float denom = coshf(t2a) + cosf(2.f * bi);
      re = sinhf(t2a) / denom;
      im = sinf(2.f * bi) / denom;
    }
    qkb[x * cM + y] = make_float2(re, im);
  }
}

__global__ __launch_bounds__(256) void crossqkv_kernel(const float* __restrict__ QKb,
                                                       const float* __restrict__ Fk,
                                                       float* __restrict__ Fq) {
  int b = blockIdx.x, h = blockIdx.y;
  __shared__ float2 qks[cM][cM];
  const float2* qkb = (const float2*)(QKb) + (((long)b * cH + h) * cM * cM);
  for (int i = threadIdx.x; i < cM * cM; i += 256) qks[i >> 6][i & 63] = qkb[i];
  __syncthreads();
  int e = threadIdx.x & 63, xg = threadIdx.x >> 6;
  const float* kb = Fk + ((long)b * cDM + h * cE) * M2;
  float2 acc[16];
#pragma unroll
  for (int i = 0; i < 16; i++) acc[i] = make_float2(0.f, 0.f);
  for (int y = 0; y < cM; y++) {
    float2 k = ((const float2*)(kb + (long)e * M2))[y];
#pragma unroll
    for (int i = 0; i < 16; i++) {
      float2 qk = qks[xg * 16 + i][y];
      acc[i].x += qk.x * k.x - qk.y * k.y;
      acc[i].y += qk.x * k.y + qk.y * k.x;
    }
  }
  float* ob = Fq + ((long)b * cDM + h * cE) * M2;
#pragma unroll
  for (int i = 0; i < 16; i++) {
    int x = xg * 16 + i;
    ((float2*)(ob + (long)e * M2))[x] = acc[i];
  }
}

// ================= f32 shader GEMM (tiny p1 only) =================
constexpr int GBM = 128, GBN = 128, GBK = 16, LPAD = 132;

__global__ __launch_bounds__(256) void gemm_kernel(const float* __restrict__ A,
                                                   const float* __restrict__ B,
                                                   const float* __restrict__ bias,
                                                   float* __restrict__ C, int M, int N, int K) {
  __shared__ float As[GBK][LPAD];
  __shared__ float Bs[GBK][LPAD];
  int n0 = blockIdx.x * GBN, m0 = blockIdx.y * GBM;
  int tid = threadIdx.x;
  int tx = tid & 15, ty = tid >> 4;
  float acc[8][8];
#pragma unroll
  for (int i = 0; i < 8; i++)
#pragma unroll
    for (int j = 0; j < 8; j++) acc[i][j] = 0.f;

  for (int k0 = 0; k0 < K; k0 += GBK) {
#pragma unroll
    for (int p = 0; p < 8; p++) {
      int i = p * 256 + tid;
      int mm = i >> 4, kk = i & 15;
      int gm = m0 + mm;
      As[kk][mm] = (gm < M && k0 + kk < K) ? A[(long)gm * K + k0 + kk] : 0.f;
    }
#pragma unroll
    for (int p = 0; p < 8; p++) {
      int i = p * 256 + tid;
      int nn = i >> 4, kk = i & 15;
      int gn = n0 + nn;
      Bs[kk][nn] = (gn < N && k0 + kk < K) ? B[(long)gn * K + k0 + kk] : 0.f;
    }
    __syncthreads();
#pragma unroll
    for (int kk = 0; kk < GBK; kk++) {
      float a[8], bb[8];
      *(float4*)&a[0] = *(const float4*)&As[kk][ty * 8];
      *(float4*)&a[4] = *(const float4*)&As[kk][ty * 8 + 4];
      *(float4*)&bb[0] = *(const float4*)&Bs[kk][tx * 8];
      *(float4*)&bb[4] = *(const float4*)&Bs[kk][tx * 8 + 4];
#pragma unroll
      for (int i = 0; i < 8; i++)
#pragma unroll
        for (int j = 0; j < 8; j++) acc[i][j] += a[i] * bb[j];
    }
    __syncthreads();
  }

  for (int i = 0; i < 8; i++) {
    int gm = m0 + ty * 8 + i;
    if (gm >= M) break;
    long rowoff = (long)gm * N;
    for (int j = 0; j < 8; j++) {
      int gn = n0 + tx * 8 + j;
      if (gn < N) C[rowoff + gn] = acc[i][j] + (bias ? bias[gn] : 0.f);
    }
  }
}

// ================= bf16 MFMA GEMM, global_load_lds staging (m97 structure) ==========
// C = A @ B^T; A [M][lda] bf16, B [N][K] bf16. amode=1: A rows are (b,t) pairs with
// circular t-shift by (k0>>9)-1 over a 512-wide ma buffer (virtual K=1536).
// Epilogue: +bias(f32) +pe(+row-pos table) +addend(f32) relu; writes Cf (f32) and/or Cb (bf16).
__global__ __launch_bounds__(256) void mfma_gemm_bf(const short* __restrict__ A,
                                                    const short* __restrict__ B,
                                                    const float* __restrict__ bias,
                                                    const float* __restrict__ addend,
                                                    const float* __restrict__ pe,
                                                    float* __restrict__ Cf, short* __restrict__ Cb,
                                                    int M, int N, int K, int lda, long sA, long sB,
                                                    long sC, int relu, int Nreal, int ldc,
                                                    int amode) {
  __shared__ __align__(16) short As[128 * 64];
  __shared__ __align__(16) short Bs[128 * 64];
  int z = blockIdx.z;
  A += (long)z * sA;
  B += (long)z * sB;
  if (Cf) Cf += (long)z * sC;
  if (Cb) Cb += (long)z * sC;
  const float* Ad = addend ? addend + (long)z * sC : nullptr;
  int n0 = blockIdx.x * 128, m0 = blockIdx.y * 128;
  int tid = threadIdx.x;
  int lane = tid & 63;
  int w = tid >> 6;
  int wm = w & 1, wn = w >> 1;
  int lr = lane & 15, lg = lane >> 4;
  int lrow = lane >> 3, lcol = (lane & 7) * 8; // staging: 8 rows x 8 shorts per lane-slot

  float4v acc[4][4];
#pragma unroll
  for (int i = 0; i < 4; i++)
#pragma unroll
    for (int j = 0; j < 4; j++) acc[i][j] = (float4v){0.f, 0.f, 0.f, 0.f};

  for (int k0 = 0; k0 < K; k0 += 64) {
#pragma unroll
    for (int j = 0; j < 4; j++) {
      int seg = w * 4 + j;
      int row = seg * 8 + lrow;
      const short* ga;
      if (amode == 0) {
        ga = A + (long)(m0 + row) * lda + k0 + lcol;
      } else {
        int r = m0 + row;
        int bb = r >> 10, t = r & 1023;
        int jj = k0 >> 9, c0 = k0 & 511;
        ga = A + ((((long)(bb << 10)) | ((t + jj + 1023) & 1023)) << 9) + c0 + lcol;
      }
      gld16(ga, &As[seg * 512]);
      const short* gb = B + (long)(n0 + row) * K + k0 + lcol;
      gld16(gb, &Bs[seg * 512]);
    }
    asm volatile("s_waitcnt vmcnt(0)" ::: "memory");
    __syncthreads();
#pragma unroll
    for (int ks = 0; ks < 2; ks++) {
      short8v af[4], bf[4];
#pragma unroll
      for (int mi = 0; mi < 4; mi++)
        af[mi] = *(const short8v*)&As[(wm * 64 + mi * 16 + lr) * 64 + ks * 32 + lg * 8];
#pragma unroll
      for (int ni = 0; ni < 4; ni++)
        bf[ni] = *(const short8v*)&Bs[(wn * 64 + ni * 16 + lr) * 64 + ks * 32 + lg * 8];
#pragma unroll
      for (int mi = 0; mi < 4; mi++)
#pragma unroll
        for (int ni = 0; ni < 4; ni++)
          acc[mi][ni] =
              __builtin_amdgcn_mfma_f32_16x16x32_bf16(af[mi], bf[ni], acc[mi][ni], 0, 0, 0);
    }
    __syncthreads();
  }

#pragma unroll
  for (int mi = 0; mi < 4; mi++) {
#pragma unroll
    for (int i = 0; i < 4; i++) {
      int gr = m0 + wm * 64 + mi * 16 + lg * 4 + i;
      long rowoff = (long)gr * ldc;
#pragma unroll
      for (int ni = 0; ni < 4; ni++) {
        int gc = n0 + wn * 64 + ni * 16 + lr;
        if (gc < Nreal) {
          float v = acc[mi][ni][i];
          if (bias) v += bias[gc];
          if (pe) v += pe[((gr & (cL - 1)) << 9) + gc];
          if (Ad) v += Ad[rowoff + gc];
          if (relu) v = fmaxf(v, 0.f);
          if (Cf) Cf[rowoff + gc] = v;
          if (Cb) Cb[rowoff + gc] = (short)f2bf(v);
        }
      }
    }
  }
}

} // namespace

extern "C" void kernel_launch(void* const* d_in, const int* in_sizes, int n_in, void* d_out,
                              int out_size, void* d_ws, size_t ws_size, hipStream_t stream) {
  const float* x_enc = (const float*)d_in[0];
  const float* tok_W = (const float*)d_in[1];
  const float* enc_Wq = (const float*)d_in[2];
  const float* enc_Wo = (const float*)d_in[5];
  const float* enc_bq = (const float*)d_in[6];
  const float* enc_bo = (const float*)d_in[9];
  const float* dsWq = (const float*)d_in[10];
  const float* dsWo = (const float*)d_in[13];
  const float* dsbq = (const float*)d_in[14];
  const float* dsbo = (const float*)d_in[17];
  const float* dcWq = (const float*)d_in[18];
  const float* dcWk = (const float*)d_in[19];
  const float* dcWo = (const float*)d_in[21];
  const float* dcbq = (const float*)d_in[22];
  const float* dcbk = (const float*)d_in[23];
  const float* dcbo = (const float*)d_in[25];
  const float* enc_c1W = (const float*)d_in[26];
  const float* enc_c1b = (const float*)d_in[27];
  const float* enc_c2W = (const float*)d_in[28];
  const float* enc_c2b = (const float*)d_in[29];
  const float* dec_c1W = (const float*)d_in[30];
  const float* dec_c1b = (const float*)d_in[31];
  const float* dec_c2W = (const float*)d_in[32];
  const float* dec_c2b = (const float*)d_in[33];
  const float* dec_trW = (const float*)d_in[34];
  const float* fb_enc = (const float*)d_in[35];
  const float* fb_dec = (const float*)d_in[36];
  const float* fc_w = (const float*)d_in[37];
  const float* p1W = (const float*)d_in[38];
  const float* p1b = (const float*)d_in[39];
  const float* p2W = (const float*)d_in[40];
  const float* p2b = (const float*)d_in[41];
  // d_in[42] p3W, d_in[43] p3b consumed via prep
  const float* p3W = (const float*)d_in[42];
  const float* p3b = (const float*)d_in[43];

  // ---- fit: BG batch-group, RH ffn row-chunk ----
  auto need = [&](long BG, long RH) -> size_t {
    return 24000000UL + (size_t)BG * 13107200UL + (size_t)RH * 4096UL;
  };
  int BG = cB;
  while (BG > 1 && need(BG, (BG * 1024 < 4096) ? BG * 1024 : 4096) > ws_size) BG >>= 1;
  long RH = (BG * 1024 < 4096) ? BG * 1024 : 4096;
  while (RH > 512 && need(BG, RH) > ws_size) RH >>= 1;

  long GBL = (long)BG * cL;
  char* base = (char*)d_ws;
  size_t off = 0;
  auto alloc = [&](size_t bytes) -> void* {
    void* p = base + off;
    off = (off + bytes + 255) & ~(size_t)255;
    return p;
  };
  // bf16 weights
  short* WqbE = (short*)alloc(2 * 262144 * 2);
  short* WobE = (short*)alloc(2 * 262144 * 2);
  short* dsWqb = (short*)alloc(262144 * 2);
  short* dsWob = (short*)alloc(262144 * 2);
  short* dcWqb = (short*)alloc(262144 * 2);
  short* dcWkb = (short*)alloc(262144 * 2);
  short* dcWob = (short*)alloc(262144 * 2);
  short* c1bE = (short*)alloc(2 * 1048576 * 2);
  short* c2bE = (short*)alloc(2 * 1048576 * 2);
  short* c1bD = (short*)alloc(1048576 * 2);
  short* c2bD = (short*)alloc(1048576 * 2);
  short* basisdb = (short*)alloc(131072 * 2);
  short* basisib = (short*)alloc(131072 * 2);
  short* Bpadb = (short*)alloc(65536 * 2);
  short* Wtr3b = (short*)alloc(196608 * 2);
  short* p3padb = (short*)alloc(65536 * 2);
  float* p3bpadf = (float*)alloc(128 * 4);
  float* pe = (float*)alloc(524288 * 4);
  // activations
  long GA = GBL * cDM;
  float* E = (float*)alloc(GA * 4);
  float* X = (float*)alloc(GA * 4);
  float* A = (float*)alloc(GA * 4);
  short* Eb = (short*)alloc(GA * 2);
  short* Xb = (short*)alloc(GA * 2);
  short* Ab = (short*)alloc(GA * 2);
  short* Sb = (short*)alloc(GA * 2);
  short* Tb = (short*)alloc(GA * 2);
  short* winb = (short*)alloc(GBL * 128 * 2);
  short* HDb = (short*)alloc(RH * cDFF * 2);
  float* Fq = (float*)alloc(GBL / cL * 65536 * 4);
  float* Fk = (float*)alloc(GBL / cL * 65536 * 4);
  short* Fqb = (short*)alloc(GBL / cL * 65536 * 2);
  float* QKb = (float*)alloc(GBL / cL * 65536 * 4);
  float* TRD = (float*)alloc(GBL * cCIN * 4);
  float* O1 = (float*)alloc(GBL * cCIN * 4);
  float* O2 = (float*)alloc(GBL * cCIN * 4);

  auto mg = [&](const short* Am, const short* Bm, const float* bias, const float* add,
                const float* peA, float* Cf, short* Cb, int Mm, int Nn, int Kk, int lda, long sA,
                long sB, long sC, int batch, int relu, int Nreal, int ldc, int amode) {
    dim3 g(Nn / 128, Mm / 128, batch);
    mfma_gemm_bf<<<g, 256, 0, stream>>>(Am, Bm, bias, add, peA, Cf, Cb, Mm, Nn, Kk, lda, sA, sB,
                                        sC, relu, Nreal, ldc, amode);
  };
  auto cvt = [&](const float* in, short* out, int n) {
    int g = (n + 255) / 256;
    if (g > 4096) g = 4096;
    cvt_kernel<<<g, 256, 0, stream>>>(in, out, n);
  };
  auto decomp = [&](const float* x, float* sf, short* sb, float* maf, short* mab, long total,
                    int C_) {
    decomp_kernel<<<(int)(total / 256), 256, 0, stream>>>(x, sf, sb, maf, mab, (int)total, C_);
  };
  // dft: transpose src (bf16 [b][1024][512] -> Tb [b][512][1024]), then F = Tb @ basisd^T
  auto dftT = [&](const short* srcb, float* F) {
    transpose_bf<<<dim3(16, 32, BG), 256, 0, stream>>>(srcb, Tb);
    mg(Tb, basisdb, nullptr, nullptr, nullptr, F, nullptr, cDM, M2, cL, cL, (long)cDM * cL, 0,
       65536, BG, 0, M2, M2, 0);
  };
  auto idft = [&](const short* Fb, short* ob) { // o[t][dm] bf16 = basisi @ F^T
    mg(basisib, Fb, nullptr, nullptr, nullptr, nullptr, ob, cL, cDM, M2, M2, 0, 65536,
       (long)cL * cDM, BG, 0, cDM, cDM, 0);
  };
  auto ffn = [&](const short* inb, const float* addf, float* outf, const short* c1w,
                 const float* c1bias, const short* c2w, const float* c2bias) {
    for (long r = 0; r < GBL; r += RH) {
      mg(inb + r * cDM, c1w, c1bias, nullptr, nullptr, nullptr, HDb, (int)RH, cDFF, cDM, cDM, 0,
         0, 0, 1, 1, cDFF, cDFF, 0);
      mg(HDb, c2w, c2bias, addf + r * cDM, nullptr, outf + r * cDM, nullptr, (int)RH, cDM, cDFF,
         cDFF, 0, 0, 0, 1, 0, cDM, cDM, 0);
    }
  };
  auto trendg = [&](const short* mab) { // TRD += shift(ma) conv weights, via K=1536 gemm
    mg(mab, Wtr3b, nullptr, TRD, nullptr, TRD, nullptr, (int)GBL, 128, 1536, 512, 0, 0, 0, 1, 0,
       cCIN, cCIN, 1);
  };
  auto mix = [&](float* F, short* Fb, const float* W, float scale) {
    modemix_kernel<<<dim3(BG, cH), 256, 0, stream>>>(F, W, F, Fb, scale);
  };

  // ---- one-time setup ----
  basis_kernel<<<(M2 * cL) / 256, 256, 0, stream>>>(basisdb, basisib);
  pe_kernel<<<(cL * cDM) / 256, 256, 0, stream>>>(pe);
  prep_kernel<<<768, 256, 0, stream>>>(tok_W, dec_trW, p3W, p3b, Bpadb, Wtr3b, p3padb, p3bpadf);
  cvt(enc_Wq, WqbE, 524288);
  cvt(enc_Wo, WobE, 524288);
  cvt(dsWq, dsWqb, 262144);
  cvt(dsWo, dsWob, 262144);
  cvt(dcWq, dcWqb, 262144);
  cvt(dcWk, dcWkb, 262144);
  cvt(dcWo, dcWob, 262144);
  cvt(enc_c1W, c1bE, 2097152);
  cvt(enc_c2W, c2bE, 2097152);
  cvt(dec_c1W, c1bD, 1048576);
  cvt(dec_c2W, c2bD, 1048576);

  for (int b0 = 0; b0 < cB; b0 += BG) {
    const float* xg = x_enc + (long)b0 * cL * cCIN;

    decomp(xg, nullptr, nullptr, TRD, nullptr, GBL * cCIN, cCIN); // trend_init -> TRD
    winbuild_kernel<<<(int)(GBL * 32 / 256), 256, 0, stream>>>(xg, winb);
    mg(winb, Bpadb, nullptr, nullptr, pe, E, Eb, (int)GBL, cDM, 128, 128, 0, 0, 0, 1, 0, cDM,
       cDM, 0); // embedding

    // ---- encoder ----
    for (int l = 0; l < 2; l++) {
      mg(Eb, WqbE + (long)l * 262144, enc_bq + l * cDM, nullptr, nullptr, nullptr, Xb, (int)GBL,
         cDM, cDM, cDM, 0, 0, 0, 1, 0, cDM, cDM, 0);                       // q -> Xb
      dftT(Xb, Fq);
      mix(Fq, Fqb, fb_enc, 1.0f);
      idft(Fqb, Xb);                                                        // o -> Xb
      mg(Xb, WobE + (long)l * 262144, enc_bo + l * cDM, E, nullptr, A, nullptr, (int)GBL, cDM,
         cDM, cDM, 0, 0, 0, 1, 0, cDM, cDM, 0);                            // x+attn -> A
      decomp(A, X, Xb, nullptr, nullptr, GA, cDM);                         // h -> X,Xb
      ffn(Xb, X, A, c1bE + (long)l * 1048576, enc_c1b + l * cDFF, c2bE + (long)l * 1048576,
          enc_c2b + l * cDM);                                              // h+y -> A
      decomp(A, E, Eb, nullptr, nullptr, GA, cDM);                         // stream -> E,Eb
    }

    // ---- decoder ----
    mg(Eb, dsWqb, dsbq, nullptr, nullptr, nullptr, Xb, (int)GBL, cDM, cDM, cDM, 0, 0, 0, 1, 0,
       cDM, cDM, 0);
    dftT(Xb, Fq);
    mix(Fq, Fqb, fb_dec, 1.0f);
    idft(Fqb, Xb);
    mg(Xb, dsWob, dsbo, E, nullptr, A, nullptr, (int)GBL, cDM, cDM, cDM, 0, 0, 0, 1, 0, cDM, cDM,
       0);                                                                  // x1 -> A
    decomp(A, X, Xb, nullptr, Sb, GA, cDM);                                 // x2 -> X,Xb; ma -> Sb
    trendg(Sb);                                                             // t1
    mg(Xb, dcWqb, dcbq, nullptr, nullptr, nullptr, Ab, (int)GBL, cDM, cDM, cDM, 0, 0, 0, 1, 0,
       cDM, cDM, 0);                                                        // q2 -> Ab
    mg(Eb, dcWkb, dcbk, nullptr, nullptr, nullptr, Sb, (int)GBL, cDM, cDM, cDM, 0, 0, 0, 1, 0,
       cDM, cDM, 0);                                                        // k -> Sb
    dftT(Ab, Fq);
    dftT(Sb, Fk);
    crossqk_kernel<<<dim3(BG, cH), 256, 0, stream>>>(Fq, Fk, QKb);
    crossqkv_kernel<<<dim3(BG, cH), 256, 0, stream>>>(QKb, Fk, Fq);
    mix(Fq, Fqb, fc_w, 1.0f / (float)(cDM * cDM));
    idft(Fqb, Ab);                                                          // o -> Ab
    mg(Ab, dcWob, dcbo, X, nullptr, E, nullptr, (int)GBL, cDM, cDM, cDM, 0, 0, 0, 1, 0, cDM, cDM,
       0);                                                                  // x3 -> E
    decomp(E, A, Ab, nullptr, Sb, GA, cDM);                                 // x4 -> A,Ab; ma->Sb
    trendg(Sb);                                                             // t2
    ffn(Ab, A, E, c1bD, dec_c1b, c2bD, dec_c2b);                            // x4+y -> E
    decomp(E, nullptr, Xb, nullptr, Sb, GA, cDM);                           // x5 -> Xb; ma -> Sb
    trendg(Sb);                                                             // t3

    // ---- final projections ----
    mg(Xb, p3padb, p3bpadf, TRD, nullptr, O1, nullptr, (int)GBL, 128, cDM, cDM, 0, 0, 0, 1, 0,
       cCIN, cCIN, 0);                                                      // trend + x@p3
    gemm_kernel<<<dim3(1, (int)(GBL / 128)), 256, 0, stream>>>(O1, p1W, p1b, O2, (int)GBL, cCIN,
                                                               cCIN);
    p2_kernel<<<dim3(BG, 32), 256, 0, stream>>>(O2, p2W, p2b,
                                                (float*)d_out + (long)b0 * cPRED * cCIN);
  }
}

// Round 6
// 4932.738 us; speedup vs baseline: 9.8847x; 1.0702x over previous
//
#include <hip/hip_runtime.h>
#include <math.h>

namespace {

constexpr int cB = 32, cL = 1024, cCIN = 32, cDM = 512, cDFF = 2048;
constexpr int cH = 8, cE = 64, cM = 64, cPRED = 256;
constexpr int M2 = 2 * cM; // 128

typedef __attribute__((ext_vector_type(8))) short short8v;
typedef __attribute__((ext_vector_type(4))) float float4v;

__device__ inline unsigned short f2bf(float f) {
  unsigned int u = __builtin_bit_cast(unsigned int, f);
  u += 0x7FFFu + ((u >> 16) & 1u); // RNE
  return (unsigned short)(u >> 16);
}

typedef const __attribute__((address_space(1))) unsigned int gu32_t;
typedef __attribute__((address_space(3))) unsigned int lu32_t;
__device__ inline void gld16(const void* g, void* l) {
  __builtin_amdgcn_global_load_lds((gu32_t*)g, (lu32_t*)l, 16, 0, 0);
}

// ================= one-time tables =================
__global__ void basis_kernel(short* __restrict__ basisdb, short* __restrict__ basisib) {
  int idx = blockIdx.x * 256 + threadIdx.x;
  if (idx >= M2 * cL) return;
  int t = idx & (cL - 1);
  int m2 = idx >> 10;
  int m = m2 >> 1;
  float ang = 6.2831853071795864f * (float)((m * t) & (cL - 1)) / (float)cL;
  float cv = cosf(ang), sv = sinf(ang);
  float vd = (m2 & 1) ? -sv : cv;
  basisdb[idx] = (short)f2bf(vd);
  float s = (m == 0) ? ((m2 & 1) ? 0.f : (1.f / (float)cL)) : (2.f / (float)cL);
  basisib[t * M2 + m2] = (short)f2bf(vd * s);
}

__global__ void pe_kernel(float* __restrict__ pe) {
  int idx = blockIdx.x * 256 + threadIdx.x;
  int o = idx & (cDM - 1), t = idx >> 9;
  int i = o >> 1;
  float freq = __expf((float)(2 * i) * (-9.210340371976184f / (float)cDM));
  float ang = freq * (float)t;
  pe[idx] = (o & 1) ? cosf(ang) : sinf(ang);
}

__global__ void cvt_kernel(const float* __restrict__ in, short* __restrict__ out, int n) {
  for (int i = blockIdx.x * 256 + threadIdx.x; i < n; i += gridDim.x * 256)
    out[i] = (short)f2bf(in[i]);
}

// Bpadb[o][j*32+c]=tok_W[o][c][j]; Wtr3b[o][j*512+c]=trW[o][c][j] (o<32); p3padb; p3bpadf
__global__ void prep_kernel(const float* __restrict__ tok_W, const float* __restrict__ trW,
                            const float* __restrict__ p3W, const float* __restrict__ p3b,
                            short* __restrict__ Bpadb, short* __restrict__ Wtr3b,
                            short* __restrict__ p3padb, float* __restrict__ p3bpadf) {
  int idx = blockIdx.x * 256 + threadIdx.x;
  if (idx < 512 * 128) {
    int o = idx >> 7, s = idx & 127, j = s >> 5, c = s & 31;
    Bpadb[idx] = (j < 3) ? (short)f2bf(tok_W[o * 96 + c * 3 + j]) : (short)0;
  }
  if (idx < 128 * 1536) {
    int o = idx / 1536, r = idx % 1536, j = r >> 9, c = r & 511;
    Wtr3b[idx] = (o < 32) ? (short)f2bf(trW[(long)o * 1536 + c * 3 + j]) : (short)0;
  }
  if (idx < 128 * 512) {
    int o = idx >> 9, k = idx & 511;
    p3padb[idx] = (o < 32) ? (short)f2bf(p3W[o * 512 + k]) : (short)0;
  }
  if (idx < 128) p3bpadf[idx] = (idx < 32) ? p3b[idx] : 0.f;
}

// win[row][128] bf16 = [x[t-1,:], x[t,:], x[t+1,:], 0] circular
__global__ void winbuild_kernel(const float* __restrict__ x, short* __restrict__ win) {
  int idx = blockIdx.x * 256 + threadIdx.x; // over rows*32
  int s4 = idx & 31;
  int row = idx >> 5;
  int t = row & (cL - 1), b = row >> 10;
  int j = s4 >> 3, c4 = s4 & 7;
  unsigned int lo = 0, hi = 0;
  if (j < 3) {
    int ts = (t + j + cL - 1) & (cL - 1);
    float4 v = *(const float4*)&x[((long)b * cL + ts) * cCIN + c4 * 4];
    lo = (unsigned int)f2bf(v.x) | ((unsigned int)f2bf(v.y) << 16);
    hi = (unsigned int)f2bf(v.z) | ((unsigned int)f2bf(v.w) << 16);
  }
  *(uint2*)&win[row * 128 + s4 * 4] = make_uint2(lo, hi);
}

// batched bf16 transpose: in [B][1024][512] -> out [B][512][1024]
__global__ __launch_bounds__(256) void transpose_bf(const short* __restrict__ in,
                                                    short* __restrict__ out) {
  __shared__ short tile[32][33];
  int b = blockIdx.z;
  in += (long)b * cL * cDM;
  out += (long)b * cL * cDM;
  int c0 = blockIdx.x * 32, t0 = blockIdx.y * 32;
  int tx = threadIdx.x & 31, ty = threadIdx.x >> 5;
#pragma unroll
  for (int r = 0; r < 32; r += 8) tile[ty + r][tx] = in[(long)(t0 + ty + r) * cDM + c0 + tx];
  __syncthreads();
#pragma unroll
  for (int r = 0; r < 32; r += 8)
    out[(long)(c0 + ty + r) * cL + t0 + tx] = tile[tx][ty + r];
}

// ================= moving-average decomposition (f32 + optional bf16 shadows) =========
__global__ void decomp_kernel(const float* __restrict__ x, float* __restrict__ sf,
                              short* __restrict__ sb, float* __restrict__ maf,
                              short* __restrict__ mab, int total, int C) {
  int idx = blockIdx.x * 256 + threadIdx.x;
  if (idx >= total) return;
  int c = idx % C;
  int t = (idx / C) & (cL - 1);
  long base = (long)(idx / (C * cL)) * cL * C + c;
  float s = 0.f;
#pragma unroll
  for (int j = -12; j <= 12; j++) {
    int tt = t + j;
    tt = tt < 0 ? 0 : (tt >= cL ? cL - 1 : tt);
    s += x[base + (long)tt * C];
  }
  float ma = s * (1.0f / 25.0f);
  float se = x[idx] - ma;
  if (sf) sf[idx] = se;
  if (sb) sb[idx] = (short)f2bf(se);
  if (maf) maf[idx] = ma;
  if (mab) mab[idx] = (short)f2bf(ma);
}

// ================= final time projection =================
__global__ __launch_bounds__(256) void p2_kernel(const float* __restrict__ x,
                                                 const float* __restrict__ W,
                                                 const float* __restrict__ bias,
                                                 float* __restrict__ out) {
  __shared__ float tile[256 * 32];
  int b = blockIdx.x;
  int p0 = blockIdx.y * 8;
  int c = threadIdx.x & 31, pl = threadIdx.x >> 5;
  const float* xb = x + (long)b * cL * cCIN;
  const float* w = W + (long)(p0 + pl) * cL;
  float s = 0.f;
  for (int l0 = 0; l0 < cL; l0 += 256) {
    __syncthreads();
    for (int i = threadIdx.x; i < 256 * 32; i += 256) tile[i] = xb[(long)l0 * 32 + i];
    __syncthreads();
#pragma unroll 8
    for (int l = 0; l < 256; l++) s += tile[l * 32 + c] * w[l0 + l];
  }
  out[((long)b * cPRED + p0 + pl) * cCIN + c] = s + bias[p0 + pl];
}

// ================= per-(h,mode) complex mode mix (+ optional bf16 out) =================
__global__ __launch_bounds__(256) void modemix_kernel(const float* __restrict__ F,
                                                      const float* __restrict__ W,
                                                      float* __restrict__ out,
                                                      short* __restrict__ outb, float scale) {
  int b = blockIdx.x, h = blockIdx.y;
  __shared__ float2 Fs[cE][cM];
  const float* Fb = F + ((long)b * cDM + h * cE) * M2;
  for (int i = threadIdx.x; i < cE * cM; i += 256) {
    int e = i >> 6, x = i & 63;
    Fs[e][x] = ((const float2*)(Fb + (long)e * M2))[x];
  }
  __syncthreads();
  int x = threadIdx.x & 63, og = threadIdx.x >> 6;
  float2 acc[16];
#pragma unroll
  for (int i = 0; i < 16; i++) acc[i] = make_float2(0.f, 0.f);
  for (int e = 0; e < cE; e++) {
    float2 f = Fs[e][x];
#pragma unroll
    for (int i = 0; i < 16; i++) {
      int o = og * 16 + i;
      const float2 w = *(const float2*)(W + ((((long)h * cE + e) * cE + o) * cM + x) * 2);
      acc[i].x += f.x * w.x - f.y * w.y;
      acc[i].y += f.x * w.y + f.y * w.x;
    }
  }
  long ob = ((long)b * cDM + h * cE) * M2;
#pragma unroll
  for (int i = 0; i < 16; i++) {
    int o = og * 16 + i;
    float rx = acc[i].x * scale, ry = acc[i].y * scale;
    ((float2*)(out + ob + (long)o * M2))[x] = make_float2(rx, ry);
    if (outb) {
      unsigned int pk = (unsigned int)f2bf(rx) | ((unsigned int)f2bf(ry) << 16);
      *(unsigned int*)&outb[ob + (long)o * M2 + 2 * x] = pk;
    }
  }
}

// ================= fourier_cross =================
__global__ __launch_bounds__(256) void crossqk_kernel(const float* __restrict__ Fq,
                                                      const float* __restrict__ Fk,
                                                      float* __restrict__ QKb) {
  int b = blockIdx.x, h = blockIdx.y;
  __shared__ float2 Ks[cE][cM];
  const float* kb = Fk + ((long)b * cDM + h * cE) * M2;
  for (int i = threadIdx.x; i < cE * cM; i += 256) {
    int e = i >> 6, y = i & 63;
    Ks[e][y] = ((const float2*)(kb + (long)e * M2))[y];
  }
  __syncthreads();
  int x = threadIdx.x & 63, yg = threadIdx.x >> 6;
  const float* qb = Fq + ((long)b * cDM + h * cE) * M2;
  float2 acc[16];
#pragma unroll
  for (int i = 0; i < 16; i++) acc[i] = make_float2(0.f, 0.f);
  for (int e = 0; e < cE; e++) {
    float2 q = ((const float2*)(qb + (long)e * M2))[x];
#pragma unroll
    for (int i = 0; i < 16; i++) {
      float2 k = Ks[e][yg * 16 + i];
      acc[i].x += q.x * k.x - q.y * k.y;
      acc[i].y += q.x * k.y + q.y * k.x;
    }
  }
  float2* qkb = (float2*)(QKb) + (((long)b * cH + h) * cM * cM);
#pragma unroll
  for (int i = 0; i < 16; i++) {
    int y = yg * 16 + i;
    float a = acc[i].x, bi = acc[i].y;
    float re, im;
    float t2a = 2.f * a;
    if (fabsf(t2a) > 60.f) {
      re = t2a > 0.f ? 1.f : -1.f;
      im = 0.f;
    } else {
      float denom = coshf(t2a) + cosf(2.f * bi);
      re = sinhf(t2a) / denom;
      im = sinf(2.f * bi) / denom;
    }
    qkb[x * cM + y] = make_float2(re, im);
  }
}

__global__ __launch_bounds__(256) void crossqkv_kernel(const float* __restrict__ QKb,
                                                       const float* __restrict__ Fk,
                                                       float* __restrict__ Fq) {
  int b = blockIdx.x, h = blockIdx.y;
  __shared__ float2 qks[cM][cM];
  const float2* qkb = (const float2*)(QKb) + (((long)b * cH + h) * cM * cM);
  for (int i = threadIdx.x; i < cM * cM; i += 256) qks[i >> 6][i & 63] = qkb[i];
  __syncthreads();
  int e = threadIdx.x & 63, xg = threadIdx.x >> 6;
  const float* kb = Fk + ((long)b * cDM + h * cE) * M2;
  float2 acc[16];
#pragma unroll
  for (int i = 0; i < 16; i++) acc[i] = make_float2(0.f, 0.f);
  for (int y = 0; y < cM; y++) {
    float2 k = ((const float2*)(kb + (long)e * M2))[y];
#pragma unroll
    for (int i = 0; i < 16; i++) {
      float2 qk = qks[xg * 16 + i][y];
      acc[i].x += qk.x * k.x - qk.y * k.y;
      acc[i].y += qk.x * k.y + qk.y * k.x;
    }
  }
  float* ob = Fq + ((long)b * cDM + h * cE) * M2;
#pragma unroll
  for (int i = 0; i < 16; i++) {
    int x = xg * 16 + i;
    ((float2*)(ob + (long)e * M2))[x] = acc[i];
  }
}

// ================= f32 shader GEMM (tiny p1 only) =================
constexpr int GBM = 128, GBN = 128, GBK = 16, LPAD = 132;

__global__ __launch_bounds__(256) void gemm_kernel(const float* __restrict__ A,
                                                   const float* __restrict__ B,
                                                   const float* __restrict__ bias,
                                                   float* __restrict__ C, int M, int N, int K) {
  __shared__ float As[GBK][LPAD];
  __shared__ float Bs[GBK][LPAD];
  int n0 = blockIdx.x * GBN, m0 = blockIdx.y * GBM;
  int tid = threadIdx.x;
  int tx = tid & 15, ty = tid >> 4;
  float acc[8][8];
#pragma unroll
  for (int i = 0; i < 8; i++)
#pragma unroll
    for (int j = 0; j < 8; j++) acc[i][j] = 0.f;

  for (int k0 = 0; k0 < K; k0 += GBK) {
#pragma unroll
    for (int p = 0; p < 8; p++) {
      int i = p * 256 + tid;
      int mm = i >> 4, kk = i & 15;
      int gm = m0 + mm;
      As[kk][mm] = (gm < M && k0 + kk < K) ? A[(long)gm * K + k0 + kk] : 0.f;
    }
#pragma unroll
    for (int p = 0; p < 8; p++) {
      int i = p * 256 + tid;
      int nn = i >> 4, kk = i & 15;
      int gn = n0 + nn;
      Bs[kk][nn] = (gn < N && k0 + kk < K) ? B[(long)gn * K + k0 + kk] : 0.f;
    }
    __syncthreads();
#pragma unroll
    for (int kk = 0; kk < GBK; kk++) {
      float a[8], bb[8];
      *(float4*)&a[0] = *(const float4*)&As[kk][ty * 8];
      *(float4*)&a[4] = *(const float4*)&As[kk][ty * 8 + 4];
      *(float4*)&bb[0] = *(const float4*)&Bs[kk][tx * 8];
      *(float4*)&bb[4] = *(const float4*)&Bs[kk][tx * 8 + 4];
#pragma unroll
      for (int i = 0; i < 8; i++)
#pragma unroll
        for (int j = 0; j < 8; j++) acc[i][j] += a[i] * bb[j];
    }
    __syncthreads();
  }

  for (int i = 0; i < 8; i++) {
    int gm = m0 + ty * 8 + i;
    if (gm >= M) break;
    long rowoff = (long)gm * N;
    for (int j = 0; j < 8; j++) {
      int gn = n0 + tx * 8 + j;
      if (gn < N) C[rowoff + gn] = acc[i][j] + (bias ? bias[gn] : 0.f);
    }
  }
}

// ================= bf16 MFMA GEMM: 2-phase dbuf pipeline + XOR-swizzled LDS ==========
// C = A @ B^T; A [M][lda] bf16, B [N][K] bf16. amode=1: circular t-shift rows (trend conv).
// Staging: global_load_lds 16B, LINEAR LDS dest; the bank-conflict swizzle is applied by
// pre-swizzling the per-lane GLOBAL source column (scol) and XOR-ing the ds_read col (G21).
__global__ __launch_bounds__(256) void mfma_gemm_bf(const short* __restrict__ A,
                                                    const short* __restrict__ B,
                                                    const float* __restrict__ bias,
                                                    const float* __restrict__ addend,
                                                    const float* __restrict__ pe,
                                                    float* __restrict__ Cf, short* __restrict__ Cb,
                                                    int M, int N, int K, int lda, long sA, long sB,
                                                    long sC, int relu, int Nreal, int ldc,
                                                    int amode) {
  __shared__ __align__(16) short As[2][8192];
  __shared__ __align__(16) short Bs[2][8192];
  int z = blockIdx.z;
  A += (long)z * sA;
  B += (long)z * sB;
  if (Cf) Cf += (long)z * sC;
  if (Cb) Cb += (long)z * sC;
  const float* Ad = addend ? addend + (long)z * sC : nullptr;
  int n0 = blockIdx.x * 128, m0 = blockIdx.y * 128;
  int tid = threadIdx.x;
  int lane = tid & 63;
  int w = tid >> 6;
  int wm = w & 1, wn = w >> 1;
  int lr = lane & 15, lg = lane >> 4;
  int lrow = lane >> 3;                      // staging row within 8-row segment
  int scol = ((lane & 7) * 8) ^ (lrow << 3); // swizzled source column (shorts)

  float4v acc[4][4];
#pragma unroll
  for (int i = 0; i < 4; i++)
#pragma unroll
    for (int j = 0; j < 4; j++) acc[i][j] = (float4v){0.f, 0.f, 0.f, 0.f};

  auto stage = [&](int buf, int k0) {
#pragma unroll
    for (int j = 0; j < 4; j++) {
      int seg = w * 4 + j;
      int row = seg * 8 + lrow;
      const short* ga;
      if (amode == 0) {
        ga = A + (long)(m0 + row) * lda + k0 + scol;
      } else {
        int r = m0 + row;
        int bb = r >> 10, t = r & 1023;
        int jj = k0 >> 9, c0 = k0 & 511;
        ga = A + ((((long)(bb << 10)) | ((t + jj + 1023) & 1023)) << 9) + c0 + scol;
      }
      gld16(ga, &As[buf][seg * 512]);
      const short* gb = B + (long)(n0 + row) * K + k0 + scol;
      gld16(gb, &Bs[buf][seg * 512]);
    }
  };

  int nk = K >> 6;
  stage(0, 0);
  asm volatile("s_waitcnt vmcnt(0)" ::: "memory");
  __syncthreads();

  int swr = (lr & 7) << 3; // read-side XOR (shorts)
  for (int t = 0; t < nk; ++t) {
    int cur = t & 1;
    if (t + 1 < nk) stage(cur ^ 1, (t + 1) << 6); // prefetch next tile (in flight under compute)
#pragma unroll
    for (int ks = 0; ks < 2; ks++) {
      short8v af[4], bfr[4];
#pragma unroll
      for (int mi = 0; mi < 4; mi++)
        af[mi] =
            *(const short8v*)&As[cur][(wm * 64 + mi * 16 + lr) * 64 + ((ks * 32 + lg * 8) ^ swr)];
#pragma unroll
      for (int ni = 0; ni < 4; ni++)
        bfr[ni] =
            *(const short8v*)&Bs[cur][(wn * 64 + ni * 16 + lr) * 64 + ((ks * 32 + lg * 8) ^ swr)];
#pragma unroll
      for (int mi = 0; mi < 4; mi++)
#pragma unroll
        for (int ni = 0; ni < 4; ni++)
          acc[mi][ni] =
              __builtin_amdgcn_mfma_f32_16x16x32_bf16(af[mi], bfr[ni], acc[mi][ni], 0, 0, 0);
    }
    if (t + 1 < nk) asm volatile("s_waitcnt vmcnt(0)" ::: "memory");
    __syncthreads();
  }

#pragma unroll
  for (int mi = 0; mi < 4; mi++) {
#pragma unroll
    for (int i = 0; i < 4; i++) {
      int gr = m0 + wm * 64 + mi * 16 + lg * 4 + i;
      long rowoff = (long)gr * ldc;
#pragma unroll
      for (int ni = 0; ni < 4; ni++) {
        int gc = n0 + wn * 64 + ni * 16 + lr;
        if (gc < Nreal) {
          float v = acc[mi][ni][i];
          if (bias) v += bias[gc];
          if (pe) v += pe[((gr & (cL - 1)) << 9) + gc];
          if (Ad) v += Ad[rowoff + gc];
          if (relu) v = fmaxf(v, 0.f);
          if (Cf) Cf[rowoff + gc] = v;
          if (Cb) Cb[rowoff + gc] = (short)f2bf(v);
        }
      }
    }
  }
}

} // namespace

extern "C" void kernel_launch(void* const* d_in, const int* in_sizes, int n_in, void* d_out,
                              int out_size, void* d_ws, size_t ws_size, hipStream_t stream) {
  const float* x_enc = (const float*)d_in[0];
  const float* tok_W = (const float*)d_in[1];
  const float* enc_Wq = (const float*)d_in[2];
  const float* enc_Wo = (const float*)d_in[5];
  const float* enc_bq = (const float*)d_in[6];
  const float* enc_bo = (const float*)d_in[9];
  const float* dsWq = (const float*)d_in[10];
  const float* dsWo = (const float*)d_in[13];
  const float* dsbq = (const float*)d_in[14];
  const float* dsbo = (const float*)d_in[17];
  const float* dcWq = (const float*)d_in[18];
  const float* dcWk = (const float*)d_in[19];
  const float* dcWo = (const float*)d_in[21];
  const float* dcbq = (const float*)d_in[22];
  const float* dcbk = (const float*)d_in[23];
  const float* dcbo = (const float*)d_in[25];
  const float* enc_c1W = (const float*)d_in[26];
  const float* enc_c1b = (const float*)d_in[27];
  const float* enc_c2W = (const float*)d_in[28];
  const float* enc_c2b = (const float*)d_in[29];
  const float* dec_c1W = (const float*)d_in[30];
  const float* dec_c1b = (const float*)d_in[31];
  const float* dec_c2W = (const float*)d_in[32];
  const float* dec_c2b = (const float*)d_in[33];
  const float* dec_trW = (const float*)d_in[34];
  const float* fb_enc = (const float*)d_in[35];
  const float* fb_dec = (const float*)d_in[36];
  const float* fc_w = (const float*)d_in[37];
  const float* p1W = (const float*)d_in[38];
  const float* p1b = (const float*)d_in[39];
  const float* p2W = (const float*)d_in[40];
  const float* p2b = (const float*)d_in[41];
  const float* p3W = (const float*)d_in[42];
  const float* p3b = (const float*)d_in[43];

  // ---- fit: BG batch-group, RH ffn row-chunk ----
  auto need = [&](long BG, long RH) -> size_t {
    return 24000000UL + (size_t)BG * 13107200UL + (size_t)RH * 4096UL;
  };
  int BG = cB;
  while (BG > 1 && need(BG, (BG * 1024 < 4096) ? BG * 1024 : 4096) > ws_size) BG >>= 1;
  long RH = (BG * 1024 < 4096) ? BG * 1024 : 4096;
  while (RH > 512 && need(BG, RH) > ws_size) RH >>= 1;

  long GBL = (long)BG * cL;
  char* base = (char*)d_ws;
  size_t off = 0;
  auto alloc = [&](size_t bytes) -> void* {
    void* p = base + off;
    off = (off + bytes + 255) & ~(size_t)255;
    return p;
  };
  // bf16 weights
  short* WqbE = (short*)alloc(2 * 262144 * 2);
  short* WobE = (short*)alloc(2 * 262144 * 2);
  short* dsWqb = (short*)alloc(262144 * 2);
  short* dsWob = (short*)alloc(262144 * 2);
  short* dcWqb = (short*)alloc(262144 * 2);
  short* dcWkb = (short*)alloc(262144 * 2);
  short* dcWob = (short*)alloc(262144 * 2);
  short* c1bE = (short*)alloc(2 * 1048576 * 2);
  short* c2bE = (short*)alloc(2 * 1048576 * 2);
  short* c1bD = (short*)alloc(1048576 * 2);
  short* c2bD = (short*)alloc(1048576 * 2);
  short* basisdb = (short*)alloc(131072 * 2);
  short* basisib = (short*)alloc(131072 * 2);
  short* Bpadb = (short*)alloc(65536 * 2);
  short* Wtr3b = (short*)alloc(196608 * 2);
  short* p3padb = (short*)alloc(65536 * 2);
  float* p3bpadf = (float*)alloc(128 * 4);
  float* pe = (float*)alloc(524288 * 4);
  // activations
  long GA = GBL * cDM;
  float* E = (float*)alloc(GA * 4);
  float* X = (float*)alloc(GA * 4);
  float* A = (float*)alloc(GA * 4);
  short* Eb = (short*)alloc(GA * 2);
  short* Xb = (short*)alloc(GA * 2);
  short* Ab = (short*)alloc(GA * 2);
  short* Sb = (short*)alloc(GA * 2);
  short* Tb = (short*)alloc(GA * 2);
  short* winb = (short*)alloc(GBL * 128 * 2);
  short* HDb = (short*)alloc(RH * cDFF * 2);
  float* Fq = (float*)alloc(GBL / cL * 65536 * 4);
  float* Fk = (float*)alloc(GBL / cL * 65536 * 4);
  short* Fqb = (short*)alloc(GBL / cL * 65536 * 2);
  float* QKb = (float*)alloc(GBL / cL * 65536 * 4);
  float* TRD = (float*)alloc(GBL * cCIN * 4);
  float* O1 = (float*)alloc(GBL * cCIN * 4);
  float* O2 = (float*)alloc(GBL * cCIN * 4);

  auto mg = [&](const short* Am, const short* Bm, const float* bias, const float* add,
                const float* peA, float* Cf, short* Cb, int Mm, int Nn, int Kk, int lda, long sA,
                long sB, long sC, int batch, int relu, int Nreal, int ldc, int amode) {
    dim3 g(Nn / 128, Mm / 128, batch);
    mfma_gemm_bf<<<g, 256, 0, stream>>>(Am, Bm, bias, add, peA, Cf, Cb, Mm, Nn, Kk, lda, sA, sB,
                                        sC, relu, Nreal, ldc, amode);
  };
  auto cvt = [&](const float* in, short* out, int n) {
    int g = (n + 255) / 256;
    if (g > 4096) g = 4096;
    cvt_kernel<<<g, 256, 0, stream>>>(in, out, n);
  };
  auto decomp = [&](const float* x, float* sf, short* sb, float* maf, short* mab, long total,
                    int C_) {
    decomp_kernel<<<(int)(total / 256), 256, 0, stream>>>(x, sf, sb, maf, mab, (int)total, C_);
  };
  // dft: transpose src (bf16 [b][1024][512] -> Tb [b][512][1024]), then F = Tb @ basisd^T
  auto dftT = [&](const short* srcb, float* F) {
    transpose_bf<<<dim3(16, 32, BG), 256, 0, stream>>>(srcb, Tb);
    mg(Tb, basisdb, nullptr, nullptr, nullptr, F, nullptr, cDM, M2, cL, cL, (long)cDM * cL, 0,
       65536, BG, 0, M2, M2, 0);
  };
  auto idft = [&](const short* Fb, short* ob) { // o[t][dm] bf16 = basisi @ F^T
    mg(basisib, Fb, nullptr, nullptr, nullptr, nullptr, ob, cL, cDM, M2, M2, 0, 65536,
       (long)cL * cDM, BG, 0, cDM, cDM, 0);
  };
  auto ffn = [&](const short* inb, const float* addf, float* outf, const short* c1w,
                 const float* c1bias, const short* c2w, const float* c2bias) {
    for (long r = 0; r < GBL; r += RH) {
      mg(inb + r * cDM, c1w, c1bias, nullptr, nullptr, nullptr, HDb, (int)RH, cDFF, cDM, cDM, 0,
         0, 0, 1, 1, cDFF, cDFF, 0);
      mg(HDb, c2w, c2bias, addf + r * cDM, nullptr, outf + r * cDM, nullptr, (int)RH, cDM, cDFF,
         cDFF, 0, 0, 0, 1, 0, cDM, cDM, 0);
    }
  };
  auto trendg = [&](const short* mab) { // TRD += shift(ma) conv weights, via K=1536 gemm
    mg(mab, Wtr3b, nullptr, TRD, nullptr, TRD, nullptr, (int)GBL, 128, 1536, 512, 0, 0, 0, 1, 0,
       cCIN, cCIN, 1);
  };
  auto mix = [&](float* F, short* Fb, const float* W, float scale) {
    modemix_kernel<<<dim3(BG, cH), 256, 0, stream>>>(F, W, F, Fb, scale);
  };

  // ---- one-time setup ----
  basis_kernel<<<(M2 * cL) / 256, 256, 0, stream>>>(basisdb, basisib);
  pe_kernel<<<(cL * cDM) / 256, 256, 0, stream>>>(pe);
  prep_kernel<<<768, 256, 0, stream>>>(tok_W, dec_trW, p3W, p3b, Bpadb, Wtr3b, p3padb, p3bpadf);
  cvt(enc_Wq, WqbE, 524288);
  cvt(enc_Wo, WobE, 524288);
  cvt(dsWq, dsWqb, 262144);
  cvt(dsWo, dsWob, 262144);
  cvt(dcWq, dcWqb, 262144);
  cvt(dcWk, dcWkb, 262144);
  cvt(dcWo, dcWob, 262144);
  cvt(enc_c1W, c1bE, 2097152);
  cvt(enc_c2W, c2bE, 2097152);
  cvt(dec_c1W, c1bD, 1048576);
  cvt(dec_c2W, c2bD, 1048576);

  for (int b0 = 0; b0 < cB; b0 += BG) {
    const float* xg = x_enc + (long)b0 * cL * cCIN;

    decomp(xg, nullptr, nullptr, TRD, nullptr, GBL * cCIN, cCIN); // trend_init -> TRD
    winbuild_kernel<<<(int)(GBL * 32 / 256), 256, 0, stream>>>(xg, winb);
    mg(winb, Bpadb, nullptr, nullptr, pe, E, Eb, (int)GBL, cDM, 128, 128, 0, 0, 0, 1, 0, cDM,
       cDM, 0); // embedding

    // ---- encoder ----
    for (int l = 0; l < 2; l++) {
      mg(Eb, WqbE + (long)l * 262144, enc_bq + l * cDM, nullptr, nullptr, nullptr, Xb, (int)GBL,
         cDM, cDM, cDM, 0, 0, 0, 1, 0, cDM, cDM, 0);                       // q -> Xb
      dftT(Xb, Fq);
      mix(Fq, Fqb, fb_enc, 1.0f);
      idft(Fqb, Xb);                                                        // o -> Xb
      mg(Xb, WobE + (long)l * 262144, enc_bo + l * cDM, E, nullptr, A, nullptr, (int)GBL, cDM,
         cDM, cDM, 0, 0, 0, 1, 0, cDM, cDM, 0);                            // x+attn -> A
      decomp(A, X, Xb, nullptr, nullptr, GA, cDM);                         // h -> X,Xb
      ffn(Xb, X, A, c1bE + (long)l * 1048576, enc_c1b + l * cDFF, c2bE + (long)l * 1048576,
          enc_c2b + l * cDM);                                              // h+y -> A
      decomp(A, E, Eb, nullptr, nullptr, GA, cDM);                         // stream -> E,Eb
    }

    // ---- decoder ----
    mg(Eb, dsWqb, dsbq, nullptr, nullptr, nullptr, Xb, (int)GBL, cDM, cDM, cDM, 0, 0, 0, 1, 0,
       cDM, cDM, 0);
    dftT(Xb, Fq);
    mix(Fq, Fqb, fb_dec, 1.0f);
    idft(Fqb, Xb);
    mg(Xb, dsWob, dsbo, E, nullptr, A, nullptr, (int)GBL, cDM, cDM, cDM, 0, 0, 0, 1, 0, cDM, cDM,
       0);                                                                  // x1 -> A
    decomp(A, X, Xb, nullptr, Sb, GA, cDM);                                 // x2 -> X,Xb; ma -> Sb
    trendg(Sb);                                                             // t1
    mg(Xb, dcWqb, dcbq, nullptr, nullptr, nullptr, Ab, (int)GBL, cDM, cDM, cDM, 0, 0, 0, 1, 0,
       cDM, cDM, 0);                                                        // q2 -> Ab
    mg(Eb, dcWkb, dcbk, nullptr, nullptr, nullptr, Sb, (int)GBL, cDM, cDM, cDM, 0, 0, 0, 1, 0,
       cDM, cDM, 0);                                                        // k -> Sb
    dftT(Ab, Fq);
    dftT(Sb, Fk);
    crossqk_kernel<<<dim3(BG, cH), 256, 0, stream>>>(Fq, Fk, QKb);
    crossqkv_kernel<<<dim3(BG, cH), 256, 0, stream>>>(QKb, Fk, Fq);
    mix(Fq, Fqb, fc_w, 1.0f / (float)(cDM * cDM));
    idft(Fqb, Ab);                                                          // o -> Ab
    mg(Ab, dcWob, dcbo, X, nullptr, E, nullptr, (int)GBL, cDM, cDM, cDM, 0, 0, 0, 1, 0, cDM, cDM,
       0);                                                                  // x3 -> E
    decomp(E, A, Ab, nullptr, Sb, GA, cDM);                                 // x4 -> A,Ab; ma->Sb
    trendg(Sb);                                                             // t2
    ffn(Ab, A, E, c1bD, dec_c1b, c2bD, dec_c2b);                            // x4+y -> E
    decomp(E, nullptr, Xb, nullptr, Sb, GA, cDM);                           // x5 -> Xb; ma -> Sb
    trendg(Sb);                                                             // t3

    // ---- final projections ----
    mg(Xb, p3padb, p3bpadf, TRD, nullptr, O1, nullptr, (int)GBL, 128, cDM, cDM, 0, 0, 0, 1, 0,
       cCIN, cCIN, 0);                                                      // trend + x@p3
    gemm_kernel<<<dim3(1, (int)(GBL / 128)), 256, 0, stream>>>(O1, p1W, p1b, O2, (int)GBL, cCIN,
                                                               cCIN);
    p2_kernel<<<dim3(BG, 32), 256, 0, stream>>>(O2, p2W, p2b,
                                                (float*)d_out + (long)b0 * cPRED * cCIN);
  }
}

// Round 7
// 4192.958 us; speedup vs baseline: 11.6287x; 1.1764x over previous
//
#include <hip/hip_runtime.h>
#include <math.h>

namespace {

constexpr int cB = 32, cL = 1024, cCIN = 32, cDM = 512, cDFF = 2048;
constexpr int cH = 8, cE = 64, cM = 64, cPRED = 256;
constexpr int M2 = 2 * cM; // 128

typedef __attribute__((ext_vector_type(8))) short short8v;
typedef __attribute__((ext_vector_type(4))) float float4v;

__device__ inline unsigned short f2bf(float f) {
  unsigned int u = __builtin_bit_cast(unsigned int, f);
  u += 0x7FFFu + ((u >> 16) & 1u); // RNE
  return (unsigned short)(u >> 16);
}

typedef const __attribute__((address_space(1))) unsigned int gu32_t;
typedef __attribute__((address_space(3))) unsigned int lu32_t;
__device__ inline void gld16(const void* g, void* l) {
  __builtin_amdgcn_global_load_lds((gu32_t*)g, (lu32_t*)l, 16, 0, 0);
}

// ================= one-time tables =================
__global__ void basis_kernel(short* __restrict__ basisdb, short* __restrict__ basisib) {
  int idx = blockIdx.x * 256 + threadIdx.x;
  if (idx >= M2 * cL) return;
  int t = idx & (cL - 1);
  int m2 = idx >> 10;
  int m = m2 >> 1;
  float ang = 6.2831853071795864f * (float)((m * t) & (cL - 1)) / (float)cL;
  float cv = cosf(ang), sv = sinf(ang);
  float vd = (m2 & 1) ? -sv : cv;
  basisdb[idx] = (short)f2bf(vd);
  float s = (m == 0) ? ((m2 & 1) ? 0.f : (1.f / (float)cL)) : (2.f / (float)cL);
  basisib[t * M2 + m2] = (short)f2bf(vd * s);
}

__global__ void pe_kernel(float* __restrict__ pe) {
  int idx = blockIdx.x * 256 + threadIdx.x;
  int o = idx & (cDM - 1), t = idx >> 9;
  int i = o >> 1;
  float freq = __expf((float)(2 * i) * (-9.210340371976184f / (float)cDM));
  float ang = freq * (float)t;
  pe[idx] = (o & 1) ? cosf(ang) : sinf(ang);
}

__global__ void cvt_kernel(const float* __restrict__ in, short* __restrict__ out, int n) {
  for (int i = blockIdx.x * 256 + threadIdx.x; i < n; i += gridDim.x * 256)
    out[i] = (short)f2bf(in[i]);
}

// Bpadb[o][j*32+c]=tok_W[o][c][j]; Wtr3b[o][j*512+c]=trW[o][c][j] (o<32); p3padb; p3bpadf
__global__ void prep_kernel(const float* __restrict__ tok_W, const float* __restrict__ trW,
                            const float* __restrict__ p3W, const float* __restrict__ p3b,
                            short* __restrict__ Bpadb, short* __restrict__ Wtr3b,
                            short* __restrict__ p3padb, float* __restrict__ p3bpadf) {
  int idx = blockIdx.x * 256 + threadIdx.x;
  if (idx < 512 * 128) {
    int o = idx >> 7, s = idx & 127, j = s >> 5, c = s & 31;
    Bpadb[idx] = (j < 3) ? (short)f2bf(tok_W[o * 96 + c * 3 + j]) : (short)0;
  }
  if (idx < 128 * 1536) {
    int o = idx / 1536, r = idx % 1536, j = r >> 9, c = r & 511;
    Wtr3b[idx] = (o < 32) ? (short)f2bf(trW[(long)o * 1536 + c * 3 + j]) : (short)0;
  }
  if (idx < 128 * 512) {
    int o = idx >> 9, k = idx & 511;
    p3padb[idx] = (o < 32) ? (short)f2bf(p3W[o * 512 + k]) : (short)0;
  }
  if (idx < 128) p3bpadf[idx] = (idx < 32) ? p3b[idx] : 0.f;
}

// win[row][128] bf16 = [x[t-1,:], x[t,:], x[t+1,:], 0] circular
__global__ void winbuild_kernel(const float* __restrict__ x, short* __restrict__ win) {
  int idx = blockIdx.x * 256 + threadIdx.x; // over rows*32
  int s4 = idx & 31;
  int row = idx >> 5;
  int t = row & (cL - 1), b = row >> 10;
  int j = s4 >> 3, c4 = s4 & 7;
  unsigned int lo = 0, hi = 0;
  if (j < 3) {
    int ts = (t + j + cL - 1) & (cL - 1);
    float4 v = *(const float4*)&x[((long)b * cL + ts) * cCIN + c4 * 4];
    lo = (unsigned int)f2bf(v.x) | ((unsigned int)f2bf(v.y) << 16);
    hi = (unsigned int)f2bf(v.z) | ((unsigned int)f2bf(v.w) << 16);
  }
  *(uint2*)&win[row * 128 + s4 * 4] = make_uint2(lo, hi);
}

// batched bf16 transpose: in [B][1024][512] -> out [B][512][1024]
__global__ __launch_bounds__(256) void transpose_bf(const short* __restrict__ in,
                                                    short* __restrict__ out) {
  __shared__ short tile[32][33];
  int b = blockIdx.z;
  in += (long)b * cL * cDM;
  out += (long)b * cL * cDM;
  int c0 = blockIdx.x * 32, t0 = blockIdx.y * 32;
  int tx = threadIdx.x & 31, ty = threadIdx.x >> 5;
#pragma unroll
  for (int r = 0; r < 32; r += 8) tile[ty + r][tx] = in[(long)(t0 + ty + r) * cDM + c0 + tx];
  __syncthreads();
#pragma unroll
  for (int r = 0; r < 32; r += 8)
    out[(long)(c0 + ty + r) * cL + t0 + tx] = tile[tx][ty + r];
}

// ================= moving-average decomposition (f32 + optional bf16 shadows) =========
__global__ void decomp_kernel(const float* __restrict__ x, float* __restrict__ sf,
                              short* __restrict__ sb, float* __restrict__ maf,
                              short* __restrict__ mab, int total, int C) {
  int idx = blockIdx.x * 256 + threadIdx.x;
  if (idx >= total) return;
  int c = idx % C;
  int t = (idx / C) & (cL - 1);
  long base = (long)(idx / (C * cL)) * cL * C + c;
  float s = 0.f;
#pragma unroll
  for (int j = -12; j <= 12; j++) {
    int tt = t + j;
    tt = tt < 0 ? 0 : (tt >= cL ? cL - 1 : tt);
    s += x[base + (long)tt * C];
  }
  float ma = s * (1.0f / 25.0f);
  float se = x[idx] - ma;
  if (sf) sf[idx] = se;
  if (sb) sb[idx] = (short)f2bf(se);
  if (maf) maf[idx] = ma;
  if (mab) mab[idx] = (short)f2bf(ma);
}

// ================= final time projection =================
__global__ __launch_bounds__(256) void p2_kernel(const float* __restrict__ x,
                                                 const float* __restrict__ W,
                                                 const float* __restrict__ bias,
                                                 float* __restrict__ out) {
  __shared__ float tile[256 * 32];
  int b = blockIdx.x;
  int p0 = blockIdx.y * 8;
  int c = threadIdx.x & 31, pl = threadIdx.x >> 5;
  const float* xb = x + (long)b * cL * cCIN;
  const float* w = W + (long)(p0 + pl) * cL;
  float s = 0.f;
  for (int l0 = 0; l0 < cL; l0 += 256) {
    __syncthreads();
    for (int i = threadIdx.x; i < 256 * 32; i += 256) tile[i] = xb[(long)l0 * 32 + i];
    __syncthreads();
#pragma unroll 8
    for (int l = 0; l < 256; l++) s += tile[l * 32 + c] * w[l0 + l];
  }
  out[((long)b * cPRED + p0 + pl) * cCIN + c] = s + bias[p0 + pl];
}

// ================= per-(h,mode) complex mode mix (+ optional bf16 out) =================
__global__ __launch_bounds__(256) void modemix_kernel(const float* __restrict__ F,
                                                      const float* __restrict__ W,
                                                      float* __restrict__ out,
                                                      short* __restrict__ outb, float scale) {
  int b = blockIdx.x, h = blockIdx.y;
  __shared__ float2 Fs[cE][cM];
  const float* Fb = F + ((long)b * cDM + h * cE) * M2;
  for (int i = threadIdx.x; i < cE * cM; i += 256) {
    int e = i >> 6, x = i & 63;
    Fs[e][x] = ((const float2*)(Fb + (long)e * M2))[x];
  }
  __syncthreads();
  int x = threadIdx.x & 63, og = threadIdx.x >> 6;
  float2 acc[16];
#pragma unroll
  for (int i = 0; i < 16; i++) acc[i] = make_float2(0.f, 0.f);
  for (int e = 0; e < cE; e++) {
    float2 f = Fs[e][x];
#pragma unroll
    for (int i = 0; i < 16; i++) {
      int o = og * 16 + i;
      const float2 w = *(const float2*)(W + ((((long)h * cE + e) * cE + o) * cM + x) * 2);
      acc[i].x += f.x * w.x - f.y * w.y;
      acc[i].y += f.x * w.y + f.y * w.x;
    }
  }
  long ob = ((long)b * cDM + h * cE) * M2;
#pragma unroll
  for (int i = 0; i < 16; i++) {
    int o = og * 16 + i;
    float rx = acc[i].x * scale, ry = acc[i].y * scale;
    ((float2*)(out + ob + (long)o * M2))[x] = make_float2(rx, ry);
    if (outb) {
      unsigned int pk = (unsigned int)f2bf(rx) | ((unsigned int)f2bf(ry) << 16);
      *(unsigned int*)&outb[ob + (long)o * M2 + 2 * x] = pk;
    }
  }
}

// ================= fourier_cross =================
__global__ __launch_bounds__(256) void crossqk_kernel(const float* __restrict__ Fq,
                                                      const float* __restrict__ Fk,
                                                      float* __restrict__ QKb) {
  int b = blockIdx.x, h = blockIdx.y;
  __shared__ float2 Ks[cE][cM];
  const float* kb = Fk + ((long)b * cDM + h * cE) * M2;
  for (int i = threadIdx.x; i < cE * cM; i += 256) {
    int e = i >> 6, y = i & 63;
    Ks[e][y] = ((const float2*)(kb + (long)e * M2))[y];
  }
  __syncthreads();
  int x = threadIdx.x & 63, yg = threadIdx.x >> 6;
  const float* qb = Fq + ((long)b * cDM + h * cE) * M2;
  float2 acc[16];
#pragma unroll
  for (int i = 0; i < 16; i++) acc[i] = make_float2(0.f, 0.f);
  for (int e = 0; e < cE; e++) {
    float2 q = ((const float2*)(qb + (long)e * M2))[x];
#pragma unroll
    for (int i = 0; i < 16; i++) {
      float2 k = Ks[e][yg * 16 + i];
      acc[i].x += q.x * k.x - q.y * k.y;
      acc[i].y += q.x * k.y + q.y * k.x;
    }
  }
  float2* qkb = (float2*)(QKb) + (((long)b * cH + h) * cM * cM);
#pragma unroll
  for (int i = 0; i < 16; i++) {
    int y = yg * 16 + i;
    float a = acc[i].x, bi = acc[i].y;
    float re, im;
    float t2a = 2.f * a;
    if (fabsf(t2a) > 60.f) {
      re = t2a > 0.f ? 1.f : -1.f;
      im = 0.f;
    } else {
      float denom = coshf(t2a) + cosf(2.f * bi);
      re = sinhf(t2a) / denom;
      im = sinf(2.f * bi) / denom;
    }
    qkb[x * cM + y] = make_float2(re, im);
  }
}

__global__ __launch_bounds__(256) void crossqkv_kernel(const float* __restrict__ QKb,
                                                       const float* __restrict__ Fk,
                                                       float* __restrict__ Fq) {
  int b = blockIdx.x, h = blockIdx.y;
  __shared__ float2 qks[cM][cM];
  const float2* qkb = (const float2*)(QKb) + (((long)b * cH + h) * cM * cM);
  for (int i = threadIdx.x; i < cM * cM; i += 256) qks[i >> 6][i & 63] = qkb[i];
  __syncthreads();
  int e = threadIdx.x & 63, xg = threadIdx.x >> 6;
  const float* kb = Fk + ((long)b * cDM + h * cE) * M2;
  float2 acc[16];
#pragma unroll
  for (int i = 0; i < 16; i++) acc[i] = make_float2(0.f, 0.f);
  for (int y = 0; y < cM; y++) {
    float2 k = ((const float2*)(kb + (long)e * M2))[y];
#pragma unroll
    for (int i = 0; i < 16; i++) {
      float2 qk = qks[xg * 16 + i][y];
      acc[i].x += qk.x * k.x - qk.y * k.y;
      acc[i].y += qk.x * k.y + qk.y * k.x;
    }
  }
  float* ob = Fq + ((long)b * cDM + h * cE) * M2;
#pragma unroll
  for (int i = 0; i < 16; i++) {
    int x = xg * 16 + i;
    ((float2*)(ob + (long)e * M2))[x] = acc[i];
  }
}

// ================= f32 shader GEMM (tiny p1 only) =================
constexpr int GBM = 128, GBN = 128, GBK = 16, LPAD = 132;

__global__ __launch_bounds__(256) void gemm_kernel(const float* __restrict__ A,
                                                   const float* __restrict__ B,
                                                   const float* __restrict__ bias,
                                                   float* __restrict__ C, int M, int N, int K) {
  __shared__ float As[GBK][LPAD];
  __shared__ float Bs[GBK][LPAD];
  int n0 = blockIdx.x * GBN, m0 = blockIdx.y * GBM;
  int tid = threadIdx.x;
  int tx = tid & 15, ty = tid >> 4;
  float acc[8][8];
#pragma unroll
  for (int i = 0; i < 8; i++)
#pragma unroll
    for (int j = 0; j < 8; j++) acc[i][j] = 0.f;

  for (int k0 = 0; k0 < K; k0 += GBK) {
#pragma unroll
    for (int p = 0; p < 8; p++) {
      int i = p * 256 + tid;
      int mm = i >> 4, kk = i & 15;
      int gm = m0 + mm;
      As[kk][mm] = (gm < M && k0 + kk < K) ? A[(long)gm * K + k0 + kk] : 0.f;
    }
#pragma unroll
    for (int p = 0; p < 8; p++) {
      int i = p * 256 + tid;
      int nn = i >> 4, kk = i & 15;
      int gn = n0 + nn;
      Bs[kk][nn] = (gn < N && k0 + kk < K) ? B[(long)gn * K + k0 + kk] : 0.f;
    }
    __syncthreads();
#pragma unroll
    for (int kk = 0; kk < GBK; kk++) {
      float a[8], bb[8];
      *(float4*)&a[0] = *(const float4*)&As[kk][ty * 8];
      *(float4*)&a[4] = *(const float4*)&As[kk][ty * 8 + 4];
      *(float4*)&bb[0] = *(const float4*)&Bs[kk][tx * 8];
      *(float4*)&bb[4] = *(const float4*)&Bs[kk][tx * 8 + 4];
#pragma unroll
      for (int i = 0; i < 8; i++)
#pragma unroll
        for (int j = 0; j < 8; j++) acc[i][j] += a[i] * bb[j];
    }
    __syncthreads();
  }

  for (int i = 0; i < 8; i++) {
    int gm = m0 + ty * 8 + i;
    if (gm >= M) break;
    long rowoff = (long)gm * N;
    for (int j = 0; j < 8; j++) {
      int gn = n0 + tx * 8 + j;
      if (gn < N) C[rowoff + gn] = acc[i][j] + (bias ? bias[gn] : 0.f);
    }
  }
}

// ================= bf16 MFMA GEMM: 2-phase dbuf + XOR-swizzled LDS + XCD swizzle ======
// C = A @ B^T; A [M][lda] bf16, B [N][K] bf16. amode=1: circular t-shift rows (trend conv).
__global__ __launch_bounds__(256) void mfma_gemm_bf(const short* __restrict__ A,
                                                    const short* __restrict__ B,
                                                    const float* __restrict__ bias,
                                                    const float* __restrict__ addend,
                                                    const float* __restrict__ pe,
                                                    float* __restrict__ Cf, short* __restrict__ Cb,
                                                    int M, int N, int K, int lda, long sA, long sB,
                                                    long sC, int relu, int Nreal, int ldc,
                                                    int amode) {
  __shared__ __align__(16) short As[2][8192];
  __shared__ __align__(16) short Bs[2][8192];
  // bijective XCD-chunked remap (T1, m204): each XCD gets a contiguous block range
  int nwg = gridDim.x * gridDim.y * gridDim.z;
  int orig = blockIdx.x + gridDim.x * (blockIdx.y + gridDim.y * blockIdx.z);
  int q = nwg >> 3, r = nwg & 7;
  int xcd = orig & 7, ii = orig >> 3;
  int flat = (xcd < r ? xcd * (q + 1) : r * (q + 1) + (xcd - r) * q) + ii;
  int bx = flat % (int)gridDim.x;
  int tmp = flat / (int)gridDim.x;
  int by = tmp % (int)gridDim.y;
  int bz = tmp / (int)gridDim.y;

  int z = bz;
  A += (long)z * sA;
  B += (long)z * sB;
  if (Cf) Cf += (long)z * sC;
  if (Cb) Cb += (long)z * sC;
  const float* Ad = addend ? addend + (long)z * sC : nullptr;
  int n0 = bx * 128, m0 = by * 128;
  int tid = threadIdx.x;
  int lane = tid & 63;
  int w = tid >> 6;
  int wm = w & 1, wn = w >> 1;
  int lr = lane & 15, lg = lane >> 4;
  int lrow = lane >> 3;                      // staging row within 8-row segment
  int scol = ((lane & 7) * 8) ^ (lrow << 3); // swizzled source column (shorts)

  float4v acc[4][4];
#pragma unroll
  for (int i = 0; i < 4; i++)
#pragma unroll
    for (int j = 0; j < 4; j++) acc[i][j] = (float4v){0.f, 0.f, 0.f, 0.f};

  auto stage = [&](int buf, int k0) {
#pragma unroll
    for (int j = 0; j < 4; j++) {
      int seg = w * 4 + j;
      int row = seg * 8 + lrow;
      const short* ga;
      if (amode == 0) {
        ga = A + (long)(m0 + row) * lda + k0 + scol;
      } else {
        int r2 = m0 + row;
        int bb = r2 >> 10, t = r2 & 1023;
        int jj = k0 >> 9, c0 = k0 & 511;
        ga = A + ((((long)(bb << 10)) | ((t + jj + 1023) & 1023)) << 9) + c0 + scol;
      }
      gld16(ga, &As[buf][seg * 512]);
      const short* gb = B + (long)(n0 + row) * K + k0 + scol;
      gld16(gb, &Bs[buf][seg * 512]);
    }
  };

  int nk = K >> 6;
  stage(0, 0);
  asm volatile("s_waitcnt vmcnt(0)" ::: "memory");
  __syncthreads();

  int swr = (lr & 7) << 3; // read-side XOR (shorts)
  for (int t = 0; t < nk; ++t) {
    int cur = t & 1;
    if (t + 1 < nk) stage(cur ^ 1, (t + 1) << 6); // prefetch next tile in flight under compute
#pragma unroll
    for (int ks = 0; ks < 2; ks++) {
      short8v af[4], bfr[4];
#pragma unroll
      for (int mi = 0; mi < 4; mi++)
        af[mi] =
            *(const short8v*)&As[cur][(wm * 64 + mi * 16 + lr) * 64 + ((ks * 32 + lg * 8) ^ swr)];
#pragma unroll
      for (int ni = 0; ni < 4; ni++)
        bfr[ni] =
            *(const short8v*)&Bs[cur][(wn * 64 + ni * 16 + lr) * 64 + ((ks * 32 + lg * 8) ^ swr)];
#pragma unroll
      for (int mi = 0; mi < 4; mi++)
#pragma unroll
        for (int ni = 0; ni < 4; ni++)
          acc[mi][ni] =
              __builtin_amdgcn_mfma_f32_16x16x32_bf16(af[mi], bfr[ni], acc[mi][ni], 0, 0, 0);
    }
    if (t + 1 < nk) asm volatile("s_waitcnt vmcnt(0)" ::: "memory");
    __syncthreads();
  }

#pragma unroll
  for (int mi = 0; mi < 4; mi++) {
#pragma unroll
    for (int i = 0; i < 4; i++) {
      int gr = m0 + wm * 64 + mi * 16 + lg * 4 + i;
      long rowoff = (long)gr * ldc;
#pragma unroll
      for (int ni = 0; ni < 4; ni++) {
        int gc = n0 + wn * 64 + ni * 16 + lr;
        if (gc < Nreal) {
          float v = acc[mi][ni][i];
          if (bias) v += bias[gc];
          if (pe) v += pe[((gr & (cL - 1)) << 9) + gc];
          if (Ad) v += Ad[rowoff + gc];
          if (relu) v = fmaxf(v, 0.f);
          if (Cf) Cf[rowoff + gc] = v;
          if (Cb) Cb[rowoff + gc] = (short)f2bf(v);
        }
      }
    }
  }
}

} // namespace

extern "C" void kernel_launch(void* const* d_in, const int* in_sizes, int n_in, void* d_out,
                              int out_size, void* d_ws, size_t ws_size, hipStream_t stream) {
  const float* x_enc = (const float*)d_in[0];
  const float* tok_W = (const float*)d_in[1];
  const float* enc_Wq = (const float*)d_in[2];
  const float* enc_Wo = (const float*)d_in[5];
  const float* enc_bq = (const float*)d_in[6];
  const float* enc_bo = (const float*)d_in[9];
  const float* dsWq = (const float*)d_in[10];
  const float* dsWo = (const float*)d_in[13];
  const float* dsbq = (const float*)d_in[14];
  const float* dsbo = (const float*)d_in[17];
  const float* dcWq = (const float*)d_in[18];
  const float* dcWk = (const float*)d_in[19];
  const float* dcWo = (const float*)d_in[21];
  const float* dcbq = (const float*)d_in[22];
  const float* dcbk = (const float*)d_in[23];
  const float* dcbo = (const float*)d_in[25];
  const float* enc_c1W = (const float*)d_in[26];
  const float* enc_c1b = (const float*)d_in[27];
  const float* enc_c2W = (const float*)d_in[28];
  const float* enc_c2b = (const float*)d_in[29];
  const float* dec_c1W = (const float*)d_in[30];
  const float* dec_c1b = (const float*)d_in[31];
  const float* dec_c2W = (const float*)d_in[32];
  const float* dec_c2b = (const float*)d_in[33];
  const float* dec_trW = (const float*)d_in[34];
  const float* fb_enc = (const float*)d_in[35];
  const float* fb_dec = (const float*)d_in[36];
  const float* fc_w = (const float*)d_in[37];
  const float* p1W = (const float*)d_in[38];
  const float* p1b = (const float*)d_in[39];
  const float* p2W = (const float*)d_in[40];
  const float* p2b = (const float*)d_in[41];
  const float* p3W = (const float*)d_in[42];
  const float* p3b = (const float*)d_in[43];

  // ---- layout sizing (dry-run) ----
  auto layout_bytes = [&](long BG, long RH) -> size_t {
    size_t t = 0;
    auto add = [&](size_t b) { t = (t + b + 255) & ~(size_t)255; };
    add(2 * 262144 * 2); add(2 * 262144 * 2);                 // WqbE WobE
    add(262144 * 2); add(262144 * 2); add(262144 * 2); add(262144 * 2); add(262144 * 2);
    add(2 * 1048576 * 2); add(2 * 1048576 * 2); add(1048576 * 2); add(1048576 * 2);
    add(131072 * 2); add(131072 * 2); add(65536 * 2); add(196608 * 2); add(65536 * 2);
    add(128 * 4); add(524288 * 4);
    long GA = BG * cL * cDM;
    add(GA * 4); add(GA * 4); add(GA * 4);                     // E X A
    add(GA * 2); add(GA * 2); add(GA * 2); add(GA * 2);        // Eb Xb Ab Sb
    add(BG * cL * 128 * 2);                                    // winb
    size_t ub = (size_t)GA * 2;                                // Tb
    size_t hd = (size_t)RH * cDFF * 2;                         // HDb
    add(ub > hd ? ub : hd);                                    // UB (aliased)
    add(BG * 65536 * 4); add(BG * 65536 * 4); add(BG * 65536 * 2); add(BG * 65536 * 4);
    add(BG * cL * cCIN * 4); add(BG * cL * cCIN * 4); add(BG * cL * cCIN * 4);
    return t;
  };
  int BG = cB;
  while (BG > 1 && layout_bytes(BG, 512) > ws_size) BG >>= 1;
  long RH = (long)BG * cL;
  while (RH > 512 && layout_bytes(BG, RH) > ws_size) RH >>= 1;

  long GBL = (long)BG * cL;
  char* base = (char*)d_ws;
  size_t off = 0;
  auto alloc = [&](size_t bytes) -> void* {
    void* p = base + off;
    off = (off + bytes + 255) & ~(size_t)255;
    return p;
  };
  short* WqbE = (short*)alloc(2 * 262144 * 2);
  short* WobE = (short*)alloc(2 * 262144 * 2);
  short* dsWqb = (short*)alloc(262144 * 2);
  short* dsWob = (short*)alloc(262144 * 2);
  short* dcWqb = (short*)alloc(262144 * 2);
  short* dcWkb = (short*)alloc(262144 * 2);
  short* dcWob = (short*)alloc(262144 * 2);
  short* c1bE = (short*)alloc(2 * 1048576 * 2);
  short* c2bE = (short*)alloc(2 * 1048576 * 2);
  short* c1bD = (short*)alloc(1048576 * 2);
  short* c2bD = (short*)alloc(1048576 * 2);
  short* basisdb = (short*)alloc(131072 * 2);
  short* basisib = (short*)alloc(131072 * 2);
  short* Bpadb = (short*)alloc(65536 * 2);
  short* Wtr3b = (short*)alloc(196608 * 2);
  short* p3padb = (short*)alloc(65536 * 2);
  float* p3bpadf = (float*)alloc(128 * 4);
  float* pe = (float*)alloc(524288 * 4);
  long GA = GBL * cDM;
  float* E = (float*)alloc(GA * 4);
  float* X = (float*)alloc(GA * 4);
  float* A = (float*)alloc(GA * 4);
  short* Eb = (short*)alloc(GA * 2);
  short* Xb = (short*)alloc(GA * 2);
  short* Ab = (short*)alloc(GA * 2);
  short* Sb = (short*)alloc(GA * 2);
  short* winb = (short*)alloc(GBL * 128 * 2);
  size_t ubsz = (size_t)GA * 2;
  size_t hdsz = (size_t)RH * cDFF * 2;
  short* UB = (short*)alloc(ubsz > hdsz ? ubsz : hdsz); // Tb / HDb aliased (disjoint in time)
  short* Tb = UB;
  short* HDb = UB;
  float* Fq = (float*)alloc((size_t)BG * 65536 * 4);
  float* Fk = (float*)alloc((size_t)BG * 65536 * 4);
  short* Fqb = (short*)alloc((size_t)BG * 65536 * 2);
  float* QKb = (float*)alloc((size_t)BG * 65536 * 4);
  float* TRD = (float*)alloc(GBL * cCIN * 4);
  float* O1 = (float*)alloc(GBL * cCIN * 4);
  float* O2 = (float*)alloc(GBL * cCIN * 4);

  auto mg = [&](const short* Am, const short* Bm, const float* bias, const float* add,
                const float* peA, float* Cf, short* Cb, int Mm, int Nn, int Kk, int lda, long sA,
                long sB, long sC, int batch, int relu, int Nreal, int ldc, int amode) {
    dim3 g(Nn / 128, Mm / 128, batch);
    mfma_gemm_bf<<<g, 256, 0, stream>>>(Am, Bm, bias, add, peA, Cf, Cb, Mm, Nn, Kk, lda, sA, sB,
                                        sC, relu, Nreal, ldc, amode);
  };
  auto cvt = [&](const float* in, short* out, int n) {
    int g = (n + 255) / 256;
    if (g > 4096) g = 4096;
    cvt_kernel<<<g, 256, 0, stream>>>(in, out, n);
  };
  auto decomp = [&](const float* x, float* sf, short* sb, float* maf, short* mab, long total,
                    int C_) {
    decomp_kernel<<<(int)(total / 256), 256, 0, stream>>>(x, sf, sb, maf, mab, (int)total, C_);
  };
  auto dftT = [&](const short* srcb, float* F) {
    transpose_bf<<<dim3(16, 32, BG), 256, 0, stream>>>(srcb, Tb);
    mg(Tb, basisdb, nullptr, nullptr, nullptr, F, nullptr, cDM, M2, cL, cL, (long)cDM * cL, 0,
       65536, BG, 0, M2, M2, 0);
  };
  auto idft = [&](const short* Fb, short* ob) {
    mg(basisib, Fb, nullptr, nullptr, nullptr, nullptr, ob, cL, cDM, M2, M2, 0, 65536,
       (long)cL * cDM, BG, 0, cDM, cDM, 0);
  };
  auto ffn = [&](const short* inb, const float* addf, float* outf, const short* c1w,
                 const float* c1bias, const short* c2w, const float* c2bias) {
    for (long r = 0; r < GBL; r += RH) {
      mg(inb + r * cDM, c1w, c1bias, nullptr, nullptr, nullptr, HDb, (int)RH, cDFF, cDM, cDM, 0,
         0, 0, 1, 1, cDFF, cDFF, 0);
      mg(HDb, c2w, c2bias, addf + r * cDM, nullptr, outf + r * cDM, nullptr, (int)RH, cDM, cDFF,
         cDFF, 0, 0, 0, 1, 0, cDM, cDM, 0);
    }
  };
  auto trendg = [&](const short* mab) {
    mg(mab, Wtr3b, nullptr, TRD, nullptr, TRD, nullptr, (int)GBL, 128, 1536, 512, 0, 0, 0, 1, 0,
       cCIN, cCIN, 1);
  };
  auto mix = [&](float* F, short* Fb, const float* W, float scale) {
    modemix_kernel<<<dim3(BG, cH), 256, 0, stream>>>(F, W, F, Fb, scale);
  };

  // ---- one-time setup ----
  basis_kernel<<<(M2 * cL) / 256, 256, 0, stream>>>(basisdb, basisib);
  pe_kernel<<<(cL * cDM) / 256, 256, 0, stream>>>(pe);
  prep_kernel<<<768, 256, 0, stream>>>(tok_W, dec_trW, p3W, p3b, Bpadb, Wtr3b, p3padb, p3bpadf);
  cvt(enc_Wq, WqbE, 524288);
  cvt(enc_Wo, WobE, 524288);
  cvt(dsWq, dsWqb, 262144);
  cvt(dsWo, dsWob, 262144);
  cvt(dcWq, dcWqb, 262144);
  cvt(dcWk, dcWkb, 262144);
  cvt(dcWo, dcWob, 262144);
  cvt(enc_c1W, c1bE, 2097152);
  cvt(enc_c2W, c2bE, 2097152);
  cvt(dec_c1W, c1bD, 1048576);
  cvt(dec_c2W, c2bD, 1048576);

  for (int b0 = 0; b0 < cB; b0 += BG) {
    const float* xg = x_enc + (long)b0 * cL * cCIN;

    decomp(xg, nullptr, nullptr, TRD, nullptr, GBL * cCIN, cCIN); // trend_init -> TRD
    winbuild_kernel<<<(int)(GBL * 32 / 256), 256, 0, stream>>>(xg, winb);
    mg(winb, Bpadb, nullptr, nullptr, pe, E, Eb, (int)GBL, cDM, 128, 128, 0, 0, 0, 1, 0, cDM,
       cDM, 0); // embedding

    // ---- encoder ----
    for (int l = 0; l < 2; l++) {
      mg(Eb, WqbE + (long)l * 262144, enc_bq + l * cDM, nullptr, nullptr, nullptr, Xb, (int)GBL,
         cDM, cDM, cDM, 0, 0, 0, 1, 0, cDM, cDM, 0);                       // q -> Xb
      dftT(Xb, Fq);
      mix(Fq, Fqb, fb_enc, 1.0f);
      idft(Fqb, Xb);                                                        // o -> Xb
      mg(Xb, WobE + (long)l * 262144, enc_bo + l * cDM, E, nullptr, A, nullptr, (int)GBL, cDM,
         cDM, cDM, 0, 0, 0, 1, 0, cDM, cDM, 0);                            // x+attn -> A
      decomp(A, X, Xb, nullptr, nullptr, GA, cDM);                         // h -> X,Xb
      ffn(Xb, X, A, c1bE + (long)l * 1048576, enc_c1b + l * cDFF, c2bE + (long)l * 1048576,
          enc_c2b + l * cDM);                                              // h+y -> A
      decomp(A, E, Eb, nullptr, nullptr, GA, cDM);                         // stream -> E,Eb
    }

    // ---- decoder ----
    mg(Eb, dsWqb, dsbq, nullptr, nullptr, nullptr, Xb, (int)GBL, cDM, cDM, cDM, 0, 0, 0, 1, 0,
       cDM, cDM, 0);
    dftT(Xb, Fq);
    mix(Fq, Fqb, fb_dec, 1.0f);
    idft(Fqb, Xb);
    mg(Xb, dsWob, dsbo, E, nullptr, A, nullptr, (int)GBL, cDM, cDM, cDM, 0, 0, 0, 1, 0, cDM, cDM,
       0);                                                                  // x1 -> A
    decomp(A, X, Xb, nullptr, Sb, GA, cDM);                                 // x2 -> X,Xb; ma -> Sb
    trendg(Sb);                                                             // t1
    mg(Xb, dcWqb, dcbq, nullptr, nullptr, nullptr, Ab, (int)GBL, cDM, cDM, cDM, 0, 0, 0, 1, 0,
       cDM, cDM, 0);                                                        // q2 -> Ab
    mg(Eb, dcWkb, dcbk, nullptr, nullptr, nullptr, Sb, (int)GBL, cDM, cDM, cDM, 0, 0, 0, 1, 0,
       cDM, cDM, 0);                                                        // k -> Sb
    dftT(Ab, Fq);
    dftT(Sb, Fk);
    crossqk_kernel<<<dim3(BG, cH), 256, 0, stream>>>(Fq, Fk, QKb);
    crossqkv_kernel<<<dim3(BG, cH), 256, 0, stream>>>(QKb, Fk, Fq);
    mix(Fq, Fqb, fc_w, 1.0f / (float)(cDM * cDM));
    idft(Fqb, Ab);                                                          // o -> Ab
    mg(Ab, dcWob, dcbo, X, nullptr, E, nullptr, (int)GBL, cDM, cDM, cDM, 0, 0, 0, 1, 0, cDM, cDM,
       0);                                                                  // x3 -> E
    decomp(E, A, Ab, nullptr, Sb, GA, cDM);                                 // x4 -> A,Ab; ma->Sb
    trendg(Sb);                                                             // t2
    ffn(Ab, A, E, c1bD, dec_c1b, c2bD, dec_c2b);                            // x4+y -> E
    decomp(E, nullptr, Xb, nullptr, Sb, GA, cDM);                           // x5 -> Xb; ma -> Sb
    trendg(Sb);                                                             // t3

    // ---- final projections ----
    mg(Xb, p3padb, p3bpadf, TRD, nullptr, O1, nullptr, (int)GBL, 128, cDM, cDM, 0, 0, 0, 1, 0,
       cCIN, cCIN, 0);                                                      // trend + x@p3
    gemm_kernel<<<dim3(1, (int)(GBL / 128)), 256, 0, stream>>>(O1, p1W, p1b, O2, (int)GBL, cCIN,
                                                               cCIN);
    p2_kernel<<<dim3(BG, 32), 256, 0, stream>>>(O2, p2W, p2b,
                                                (float*)d_out + (long)b0 * cPRED * cCIN);
  }
}

// Round 8
// 4073.430 us; speedup vs baseline: 11.9699x; 1.0293x over previous
//
#include <hip/hip_runtime.h>
#include <math.h>

namespace {

constexpr int cB = 32, cL = 1024, cCIN = 32, cDM = 512, cDFF = 2048;
constexpr int cH = 8, cE = 64, cM = 64, cPRED = 256;
constexpr int M2 = 2 * cM; // 128

typedef __attribute__((ext_vector_type(8))) short short8v;
typedef __attribute__((ext_vector_type(4))) float float4v;

__device__ inline unsigned short f2bf(float f) {
  unsigned int u = __builtin_bit_cast(unsigned int, f);
  u += 0x7FFFu + ((u >> 16) & 1u); // RNE
  return (unsigned short)(u >> 16);
}

typedef const __attribute__((address_space(1))) unsigned int gu32_t;
typedef __attribute__((address_space(3))) unsigned int lu32_t;
__device__ inline void gld16(const void* g, void* l) {
  __builtin_amdgcn_global_load_lds((gu32_t*)g, (lu32_t*)l, 16, 0, 0);
}

// ================= one-time tables =================
__global__ void basis_kernel(short* __restrict__ basisdb, short* __restrict__ basisib) {
  int idx = blockIdx.x * 256 + threadIdx.x;
  if (idx >= M2 * cL) return;
  int t = idx & (cL - 1);
  int m2 = idx >> 10;
  int m = m2 >> 1;
  float ang = 6.2831853071795864f * (float)((m * t) & (cL - 1)) / (float)cL;
  float cv = cosf(ang), sv = sinf(ang);
  float vd = (m2 & 1) ? -sv : cv;
  basisdb[idx] = (short)f2bf(vd);
  float s = (m == 0) ? ((m2 & 1) ? 0.f : (1.f / (float)cL)) : (2.f / (float)cL);
  basisib[t * M2 + m2] = (short)f2bf(vd * s);
}

__global__ void pe_kernel(float* __restrict__ pe) {
  int idx = blockIdx.x * 256 + threadIdx.x;
  int o = idx & (cDM - 1), t = idx >> 9;
  int i = o >> 1;
  float freq = __expf((float)(2 * i) * (-9.210340371976184f / (float)cDM));
  float ang = freq * (float)t;
  pe[idx] = (o & 1) ? cosf(ang) : sinf(ang);
}

__global__ void cvt_kernel(const float* __restrict__ in, short* __restrict__ out, int n) {
  for (int i = blockIdx.x * 256 + threadIdx.x; i < n; i += gridDim.x * 256)
    out[i] = (short)f2bf(in[i]);
}

// Bpadb[o][j*32+c]=tok_W[o][c][j]; Wtr3b[o][j*512+c]=trW[o][c][j] (o<32); p3padb; p3bpadf
__global__ void prep_kernel(const float* __restrict__ tok_W, const float* __restrict__ trW,
                            const float* __restrict__ p3W, const float* __restrict__ p3b,
                            short* __restrict__ Bpadb, short* __restrict__ Wtr3b,
                            short* __restrict__ p3padb, float* __restrict__ p3bpadf) {
  int idx = blockIdx.x * 256 + threadIdx.x;
  if (idx < 512 * 128) {
    int o = idx >> 7, s = idx & 127, j = s >> 5, c = s & 31;
    Bpadb[idx] = (j < 3) ? (short)f2bf(tok_W[o * 96 + c * 3 + j]) : (short)0;
  }
  if (idx < 128 * 1536) {
    int o = idx / 1536, r = idx % 1536, j = r >> 9, c = r & 511;
    Wtr3b[idx] = (o < 32) ? (short)f2bf(trW[(long)o * 1536 + c * 3 + j]) : (short)0;
  }
  if (idx < 128 * 512) {
    int o = idx >> 9, k = idx & 511;
    p3padb[idx] = (o < 32) ? (short)f2bf(p3W[o * 512 + k]) : (short)0;
  }
  if (idx < 128) p3bpadf[idx] = (idx < 32) ? p3b[idx] : 0.f;
}

// win[row][128] bf16 = [x[t-1,:], x[t,:], x[t+1,:], 0] circular
__global__ void winbuild_kernel(const float* __restrict__ x, short* __restrict__ win) {
  int idx = blockIdx.x * 256 + threadIdx.x; // over rows*32
  int s4 = idx & 31;
  int row = idx >> 5;
  int t = row & (cL - 1), b = row >> 10;
  int j = s4 >> 3, c4 = s4 & 7;
  unsigned int lo = 0, hi = 0;
  if (j < 3) {
    int ts = (t + j + cL - 1) & (cL - 1);
    float4 v = *(const float4*)&x[((long)b * cL + ts) * cCIN + c4 * 4];
    lo = (unsigned int)f2bf(v.x) | ((unsigned int)f2bf(v.y) << 16);
    hi = (unsigned int)f2bf(v.z) | ((unsigned int)f2bf(v.w) << 16);
  }
  *(uint2*)&win[row * 128 + s4 * 4] = make_uint2(lo, hi);
}

// batched bf16 transpose: in [B][1024][512] -> out [B][512][1024]
__global__ __launch_bounds__(256) void transpose_bf(const short* __restrict__ in,
                                                    short* __restrict__ out) {
  __shared__ short tile[32][33];
  int b = blockIdx.z;
  in += (long)b * cL * cDM;
  out += (long)b * cL * cDM;
  int c0 = blockIdx.x * 32, t0 = blockIdx.y * 32;
  int tx = threadIdx.x & 31, ty = threadIdx.x >> 5;
#pragma unroll
  for (int r = 0; r < 32; r += 8) tile[ty + r][tx] = in[(long)(t0 + ty + r) * cDM + c0 + tx];
  __syncthreads();
#pragma unroll
  for (int r = 0; r < 32; r += 8)
    out[(long)(c0 + ty + r) * cL + t0 + tx] = tile[tx][ty + r];
}

// ================= moving-average decomposition (f32 + optional bf16 shadows) =========
__global__ void decomp_kernel(const float* __restrict__ x, float* __restrict__ sf,
                              short* __restrict__ sb, float* __restrict__ maf,
                              short* __restrict__ mab, int total, int C) {
  int idx = blockIdx.x * 256 + threadIdx.x;
  if (idx >= total) return;
  int c = idx % C;
  int t = (idx / C) & (cL - 1);
  long base = (long)(idx / (C * cL)) * cL * C + c;
  float s = 0.f;
#pragma unroll
  for (int j = -12; j <= 12; j++) {
    int tt = t + j;
    tt = tt < 0 ? 0 : (tt >= cL ? cL - 1 : tt);
    s += x[base + (long)tt * C];
  }
  float ma = s * (1.0f / 25.0f);
  float se = x[idx] - ma;
  if (sf) sf[idx] = se;
  if (sb) sb[idx] = (short)f2bf(se);
  if (maf) maf[idx] = ma;
  if (mab) mab[idx] = (short)f2bf(ma);
}

// ================= final time projection =================
__global__ __launch_bounds__(256) void p2_kernel(const float* __restrict__ x,
                                                 const float* __restrict__ W,
                                                 const float* __restrict__ bias,
                                                 float* __restrict__ out) {
  __shared__ float tile[256 * 32];
  int b = blockIdx.x;
  int p0 = blockIdx.y * 8;
  int c = threadIdx.x & 31, pl = threadIdx.x >> 5;
  const float* xb = x + (long)b * cL * cCIN;
  const float* w = W + (long)(p0 + pl) * cL;
  float s = 0.f;
  for (int l0 = 0; l0 < cL; l0 += 256) {
    __syncthreads();
    for (int i = threadIdx.x; i < 256 * 32; i += 256) tile[i] = xb[(long)l0 * 32 + i];
    __syncthreads();
#pragma unroll 8
    for (int l = 0; l < 256; l++) s += tile[l * 32 + c] * w[l0 + l];
  }
  out[((long)b * cPRED + p0 + pl) * cCIN + c] = s + bias[p0 + pl];
}

// ================= per-(h,mode) complex mode mix (+ optional bf16 out) =================
__global__ __launch_bounds__(256) void modemix_kernel(const float* __restrict__ F,
                                                      const float* __restrict__ W,
                                                      float* __restrict__ out,
                                                      short* __restrict__ outb, float scale) {
  int b = blockIdx.x, h = blockIdx.y;
  __shared__ float2 Fs[cE][cM];
  const float* Fb = F + ((long)b * cDM + h * cE) * M2;
  for (int i = threadIdx.x; i < cE * cM; i += 256) {
    int e = i >> 6, x = i & 63;
    Fs[e][x] = ((const float2*)(Fb + (long)e * M2))[x];
  }
  __syncthreads();
  int x = threadIdx.x & 63, og = threadIdx.x >> 6;
  float2 acc[16];
#pragma unroll
  for (int i = 0; i < 16; i++) acc[i] = make_float2(0.f, 0.f);
  for (int e = 0; e < cE; e++) {
    float2 f = Fs[e][x];
#pragma unroll
    for (int i = 0; i < 16; i++) {
      int o = og * 16 + i;
      const float2 w = *(const float2*)(W + ((((long)h * cE + e) * cE + o) * cM + x) * 2);
      acc[i].x += f.x * w.x - f.y * w.y;
      acc[i].y += f.x * w.y + f.y * w.x;
    }
  }
  long ob = ((long)b * cDM + h * cE) * M2;
#pragma unroll
  for (int i = 0; i < 16; i++) {
    int o = og * 16 + i;
    float rx = acc[i].x * scale, ry = acc[i].y * scale;
    ((float2*)(out + ob + (long)o * M2))[x] = make_float2(rx, ry);
    if (outb) {
      unsigned int pk = (unsigned int)f2bf(rx) | ((unsigned int)f2bf(ry) << 16);
      *(unsigned int*)&outb[ob + (long)o * M2 + 2 * x] = pk;
    }
  }
}

// ================= fourier_cross =================
__global__ __launch_bounds__(256) void crossqk_kernel(const float* __restrict__ Fq,
                                                      const float* __restrict__ Fk,
                                                      float* __restrict__ QKb) {
  int b = blockIdx.x, h = blockIdx.y;
  __shared__ float2 Ks[cE][cM];
  const float* kb = Fk + ((long)b * cDM + h * cE) * M2;
  for (int i = threadIdx.x; i < cE * cM; i += 256) {
    int e = i >> 6, y = i & 63;
    Ks[e][y] = ((const float2*)(kb + (long)e * M2))[y];
  }
  __syncthreads();
  int x = threadIdx.x & 63, yg = threadIdx.x >> 6;
  const float* qb = Fq + ((long)b * cDM + h * cE) * M2;
  float2 acc[16];
#pragma unroll
  for (int i = 0; i < 16; i++) acc[i] = make_float2(0.f, 0.f);
  for (int e = 0; e < cE; e++) {
    float2 q = ((const float2*)(qb + (long)e * M2))[x];
#pragma unroll
    for (int i = 0; i < 16; i++) {
      float2 k = Ks[e][yg * 16 + i];
      acc[i].x += q.x * k.x - q.y * k.y;
      acc[i].y += q.x * k.y + q.y * k.x;
    }
  }
  float2* qkb = (float2*)(QKb) + (((long)b * cH + h) * cM * cM);
#pragma unroll
  for (int i = 0; i < 16; i++) {
    int y = yg * 16 + i;
    float a = acc[i].x, bi = acc[i].y;
    float re, im;
    float t2a = 2.f * a;
    if (fabsf(t2a) > 60.f) {
      re = t2a > 0.f ? 1.f : -1.f;
      im = 0.f;
    } else {
      float denom = coshf(t2a) + cosf(2.f * bi);
      re = sinhf(t2a) / denom;
      im = sinf(2.f * bi) / denom;
    }
    qkb[x * cM + y] = make_float2(re, im);
  }
}

__global__ __launch_bounds__(256) void crossqkv_kernel(const float* __restrict__ QKb,
                                                       const float* __restrict__ Fk,
                                                       float* __restrict__ Fq) {
  int b = blockIdx.x, h = blockIdx.y;
  __shared__ float2 qks[cM][cM];
  const float2* qkb = (const float2*)(QKb) + (((long)b * cH + h) * cM * cM);
  for (int i = threadIdx.x; i < cM * cM; i += 256) qks[i >> 6][i & 63] = qkb[i];
  __syncthreads();
  int e = threadIdx.x & 63, xg = threadIdx.x >> 6;
  const float* kb = Fk + ((long)b * cDM + h * cE) * M2;
  float2 acc[16];
#pragma unroll
  for (int i = 0; i < 16; i++) acc[i] = make_float2(0.f, 0.f);
  for (int y = 0; y < cM; y++) {
    float2 k = ((const float2*)(kb + (long)e * M2))[y];
#pragma unroll
    for (int i = 0; i < 16; i++) {
      float2 qk = qks[xg * 16 + i][y];
      acc[i].x += qk.x * k.x - qk.y * k.y;
      acc[i].y += qk.x * k.y + qk.y * k.x;
    }
  }
  float* ob = Fq + ((long)b * cDM + h * cE) * M2;
#pragma unroll
  for (int i = 0; i < 16; i++) {
    int x = xg * 16 + i;
    ((float2*)(ob + (long)e * M2))[x] = acc[i];
  }
}

// ================= f32 shader GEMM (tiny p1 only) =================
constexpr int GBM = 128, GBN = 128, GBK = 16, LPAD = 132;

__global__ __launch_bounds__(256) void gemm_kernel(const float* __restrict__ A,
                                                   const float* __restrict__ B,
                                                   const float* __restrict__ bias,
                                                   float* __restrict__ C, int M, int N, int K) {
  __shared__ float As[GBK][LPAD];
  __shared__ float Bs[GBK][LPAD];
  int n0 = blockIdx.x * GBN, m0 = blockIdx.y * GBM;
  int tid = threadIdx.x;
  int tx = tid & 15, ty = tid >> 4;
  float acc[8][8];
#pragma unroll
  for (int i = 0; i < 8; i++)
#pragma unroll
    for (int j = 0; j < 8; j++) acc[i][j] = 0.f;

  for (int k0 = 0; k0 < K; k0 += GBK) {
#pragma unroll
    for (int p = 0; p < 8; p++) {
      int i = p * 256 + tid;
      int mm = i >> 4, kk = i & 15;
      int gm = m0 + mm;
      As[kk][mm] = (gm < M && k0 + kk < K) ? A[(long)gm * K + k0 + kk] : 0.f;
    }
#pragma unroll
    for (int p = 0; p < 8; p++) {
      int i = p * 256 + tid;
      int nn = i >> 4, kk = i & 15;
      int gn = n0 + nn;
      Bs[kk][nn] = (gn < N && k0 + kk < K) ? B[(long)gn * K + k0 + kk] : 0.f;
    }
    __syncthreads();
#pragma unroll
    for (int kk = 0; kk < GBK; kk++) {
      float a[8], bb[8];
      *(float4*)&a[0] = *(const float4*)&As[kk][ty * 8];
      *(float4*)&a[4] = *(const float4*)&As[kk][ty * 8 + 4];
      *(float4*)&bb[0] = *(const float4*)&Bs[kk][tx * 8];
      *(float4*)&bb[4] = *(const float4*)&Bs[kk][tx * 8 + 4];
#pragma unroll
      for (int i = 0; i < 8; i++)
#pragma unroll
        for (int j = 0; j < 8; j++) acc[i][j] += a[i] * bb[j];
    }
    __syncthreads();
  }

  for (int i = 0; i < 8; i++) {
    int gm = m0 + ty * 8 + i;
    if (gm >= M) break;
    long rowoff = (long)gm * N;
    for (int j = 0; j < 8; j++) {
      int gn = n0 + tx * 8 + j;
      if (gn < N) C[rowoff + gn] = acc[i][j] + (bias ? bias[gn] : 0.f);
    }
  }
}

// ===== bf16 MFMA GEMM: m97 single-buffer structure (32KB LDS -> ~5 blocks/CU TLP) =====
// C = A @ B^T; A [M][lda] bf16, B [N][K] bf16. amode=1: circular t-shift rows (trend conv).
// Bank-conflict-free via source-side XOR pre-swizzle + matching ds_read XOR (G21).
__global__ __launch_bounds__(256) void mfma_gemm_bf(const short* __restrict__ A,
                                                    const short* __restrict__ B,
                                                    const float* __restrict__ bias,
                                                    const float* __restrict__ addend,
                                                    const float* __restrict__ pe,
                                                    float* __restrict__ Cf, short* __restrict__ Cb,
                                                    int M, int N, int K, int lda, long sA, long sB,
                                                    long sC, int relu, int Nreal, int ldc,
                                                    int amode) {
  __shared__ __align__(16) short As[8192];
  __shared__ __align__(16) short Bs[8192];
  // bijective XCD-chunked remap (T1, m204): each XCD gets a contiguous block range
  int nwg = gridDim.x * gridDim.y * gridDim.z;
  int orig = blockIdx.x + gridDim.x * (blockIdx.y + gridDim.y * blockIdx.z);
  int q = nwg >> 3, r = nwg & 7;
  int xcd = orig & 7, ii = orig >> 3;
  int flat = (xcd < r ? xcd * (q + 1) : r * (q + 1) + (xcd - r) * q) + ii;
  int bx = flat % (int)gridDim.x;
  int tmp = flat / (int)gridDim.x;
  int by = tmp % (int)gridDim.y;
  int bz = tmp / (int)gridDim.y;

  int z = bz;
  A += (long)z * sA;
  B += (long)z * sB;
  if (Cf) Cf += (long)z * sC;
  if (Cb) Cb += (long)z * sC;
  const float* Ad = addend ? addend + (long)z * sC : nullptr;
  int n0 = bx * 128, m0 = by * 128;
  int tid = threadIdx.x;
  int lane = tid & 63;
  int w = tid >> 6;
  int wm = w & 1, wn = w >> 1;
  int lr = lane & 15, lg = lane >> 4;
  int lrow = lane >> 3;                      // staging row within 8-row segment
  int scol = ((lane & 7) * 8) ^ (lrow << 3); // swizzled source column (shorts)

  float4v acc[4][4];
#pragma unroll
  for (int i = 0; i < 4; i++)
#pragma unroll
    for (int j = 0; j < 4; j++) acc[i][j] = (float4v){0.f, 0.f, 0.f, 0.f};

  auto stage = [&](int k0) {
#pragma unroll
    for (int j = 0; j < 4; j++) {
      int seg = w * 4 + j;
      int row = seg * 8 + lrow;
      const short* ga;
      if (amode == 0) {
        ga = A + (long)(m0 + row) * lda + k0 + scol;
      } else {
        int r2 = m0 + row;
        int bb = r2 >> 10, t = r2 & 1023;
        int jj = k0 >> 9, c0 = k0 & 511;
        ga = A + ((((long)(bb << 10)) | ((t + jj + 1023) & 1023)) << 9) + c0 + scol;
      }
      gld16(ga, &As[seg * 512]);
      const short* gb = B + (long)(n0 + row) * K + k0 + scol;
      gld16(gb, &Bs[seg * 512]);
    }
  };

  int nk = K >> 6;
  int swr = (lr & 7) << 3; // read-side XOR (shorts)
  for (int t = 0; t < nk; ++t) {
    stage(t << 6);
    asm volatile("s_waitcnt vmcnt(0)" ::: "memory");
    __syncthreads();
#pragma unroll
    for (int ks = 0; ks < 2; ks++) {
      short8v af[4], bfr[4];
#pragma unroll
      for (int mi = 0; mi < 4; mi++)
        af[mi] = *(const short8v*)&As[(wm * 64 + mi * 16 + lr) * 64 + ((ks * 32 + lg * 8) ^ swr)];
#pragma unroll
      for (int ni = 0; ni < 4; ni++)
        bfr[ni] = *(const short8v*)&Bs[(wn * 64 + ni * 16 + lr) * 64 + ((ks * 32 + lg * 8) ^ swr)];
#pragma unroll
      for (int mi = 0; mi < 4; mi++)
#pragma unroll
        for (int ni = 0; ni < 4; ni++)
          acc[mi][ni] =
              __builtin_amdgcn_mfma_f32_16x16x32_bf16(af[mi], bfr[ni], acc[mi][ni], 0, 0, 0);
    }
    __syncthreads();
  }

#pragma unroll
  for (int mi = 0; mi < 4; mi++) {
#pragma unroll
    for (int i = 0; i < 4; i++) {
      int gr = m0 + wm * 64 + mi * 16 + lg * 4 + i;
      long rowoff = (long)gr * ldc;
#pragma unroll
      for (int ni = 0; ni < 4; ni++) {
        int gc = n0 + wn * 64 + ni * 16 + lr;
        if (gc < Nreal) {
          float v = acc[mi][ni][i];
          if (bias) v += bias[gc];
          if (pe) v += pe[((gr & (cL - 1)) << 9) + gc];
          if (Ad) v += Ad[rowoff + gc];
          if (relu) v = fmaxf(v, 0.f);
          if (Cf) Cf[rowoff + gc] = v;
          if (Cb) Cb[rowoff + gc] = (short)f2bf(v);
        }
      }
    }
  }
}

} // namespace

extern "C" void kernel_launch(void* const* d_in, const int* in_sizes, int n_in, void* d_out,
                              int out_size, void* d_ws, size_t ws_size, hipStream_t stream) {
  const float* x_enc = (const float*)d_in[0];
  const float* tok_W = (const float*)d_in[1];
  const float* enc_Wq = (const float*)d_in[2];
  const float* enc_Wo = (const float*)d_in[5];
  const float* enc_bq = (const float*)d_in[6];
  const float* enc_bo = (const float*)d_in[9];
  const float* dsWq = (const float*)d_in[10];
  const float* dsWo = (const float*)d_in[13];
  const float* dsbq = (const float*)d_in[14];
  const float* dsbo = (const float*)d_in[17];
  const float* dcWq = (const float*)d_in[18];
  const float* dcWk = (const float*)d_in[19];
  const float* dcWo = (const float*)d_in[21];
  const float* dcbq = (const float*)d_in[22];
  const float* dcbk = (const float*)d_in[23];
  const float* dcbo = (const float*)d_in[25];
  const float* enc_c1W = (const float*)d_in[26];
  const float* enc_c1b = (const float*)d_in[27];
  const float* enc_c2W = (const float*)d_in[28];
  const float* enc_c2b = (const float*)d_in[29];
  const float* dec_c1W = (const float*)d_in[30];
  const float* dec_c1b = (const float*)d_in[31];
  const float* dec_c2W = (const float*)d_in[32];
  const float* dec_c2b = (const float*)d_in[33];
  const float* dec_trW = (const float*)d_in[34];
  const float* fb_enc = (const float*)d_in[35];
  const float* fb_dec = (const float*)d_in[36];
  const float* fc_w = (const float*)d_in[37];
  const float* p1W = (const float*)d_in[38];
  const float* p1b = (const float*)d_in[39];
  const float* p2W = (const float*)d_in[40];
  const float* p2b = (const float*)d_in[41];
  const float* p3W = (const float*)d_in[42];
  const float* p3b = (const float*)d_in[43];

  // ---- layout sizing (dry-run) ----
  auto layout_bytes = [&](long BG, long RH) -> size_t {
    size_t t = 0;
    auto add = [&](size_t b) { t = (t + b + 255) & ~(size_t)255; };
    add(2 * 262144 * 2); add(2 * 262144 * 2);                 // WqbE WobE
    add(262144 * 2); add(262144 * 2); add(262144 * 2); add(262144 * 2); add(262144 * 2);
    add(2 * 1048576 * 2); add(2 * 1048576 * 2); add(1048576 * 2); add(1048576 * 2);
    add(131072 * 2); add(131072 * 2); add(65536 * 2); add(196608 * 2); add(65536 * 2);
    add(128 * 4); add(524288 * 4);
    long GA = BG * cL * cDM;
    add(GA * 4); add(GA * 4); add(GA * 4);                     // E X A
    add(GA * 2); add(GA * 2); add(GA * 2); add(GA * 2);        // Eb Xb Ab Sb
    add(BG * cL * 128 * 2);                                    // winb
    size_t ub = (size_t)GA * 2;                                // Tb
    size_t hd = (size_t)RH * cDFF * 2;                         // HDb
    add(ub > hd ? ub : hd);                                    // UB (aliased)
    add(BG * 65536 * 4); add(BG * 65536 * 4); add(BG * 65536 * 2); add(BG * 65536 * 4);
    add(BG * cL * cCIN * 4); add(BG * cL * cCIN * 4); add(BG * cL * cCIN * 4);
    return t;
  };
  int BG = cB;
  while (BG > 1 && layout_bytes(BG, 512) > ws_size) BG >>= 1;
  long RH = (long)BG * cL;
  while (RH > 512 && layout_bytes(BG, RH) > ws_size) RH >>= 1;

  long GBL = (long)BG * cL;
  char* base = (char*)d_ws;
  size_t off = 0;
  auto alloc = [&](size_t bytes) -> void* {
    void* p = base + off;
    off = (off + bytes + 255) & ~(size_t)255;
    return p;
  };
  short* WqbE = (short*)alloc(2 * 262144 * 2);
  short* WobE = (short*)alloc(2 * 262144 * 2);
  short* dsWqb = (short*)alloc(262144 * 2);
  short* dsWob = (short*)alloc(262144 * 2);
  short* dcWqb = (short*)alloc(262144 * 2);
  short* dcWkb = (short*)alloc(262144 * 2);
  short* dcWob = (short*)alloc(262144 * 2);
  short* c1bE = (short*)alloc(2 * 1048576 * 2);
  short* c2bE = (short*)alloc(2 * 1048576 * 2);
  short* c1bD = (short*)alloc(1048576 * 2);
  short* c2bD = (short*)alloc(1048576 * 2);
  short* basisdb = (short*)alloc(131072 * 2);
  short* basisib = (short*)alloc(131072 * 2);
  short* Bpadb = (short*)alloc(65536 * 2);
  short* Wtr3b = (short*)alloc(196608 * 2);
  short* p3padb = (short*)alloc(65536 * 2);
  float* p3bpadf = (float*)alloc(128 * 4);
  float* pe = (float*)alloc(524288 * 4);
  long GA = GBL * cDM;
  float* E = (float*)alloc(GA * 4);
  float* X = (float*)alloc(GA * 4);
  float* A = (float*)alloc(GA * 4);
  short* Eb = (short*)alloc(GA * 2);
  short* Xb = (short*)alloc(GA * 2);
  short* Ab = (short*)alloc(GA * 2);
  short* Sb = (short*)alloc(GA * 2);
  short* winb = (short*)alloc(GBL * 128 * 2);
  size_t ubsz = (size_t)GA * 2;
  size_t hdsz = (size_t)RH * cDFF * 2;
  short* UB = (short*)alloc(ubsz > hdsz ? ubsz : hdsz); // Tb / HDb aliased (disjoint in time)
  short* Tb = UB;
  short* HDb = UB;
  float* Fq = (float*)alloc((size_t)BG * 65536 * 4);
  float* Fk = (float*)alloc((size_t)BG * 65536 * 4);
  short* Fqb = (short*)alloc((size_t)BG * 65536 * 2);
  float* QKb = (float*)alloc((size_t)BG * 65536 * 4);
  float* TRD = (float*)alloc(GBL * cCIN * 4);
  float* O1 = (float*)alloc(GBL * cCIN * 4);
  float* O2 = (float*)alloc(GBL * cCIN * 4);

  auto mg = [&](const short* Am, const short* Bm, const float* bias, const float* add,
                const float* peA, float* Cf, short* Cb, int Mm, int Nn, int Kk, int lda, long sA,
                long sB, long sC, int batch, int relu, int Nreal, int ldc, int amode) {
    dim3 g(Nn / 128, Mm / 128, batch);
    mfma_gemm_bf<<<g, 256, 0, stream>>>(Am, Bm, bias, add, peA, Cf, Cb, Mm, Nn, Kk, lda, sA, sB,
                                        sC, relu, Nreal, ldc, amode);
  };
  auto cvt = [&](const float* in, short* out, int n) {
    int g = (n + 255) / 256;
    if (g > 4096) g = 4096;
    cvt_kernel<<<g, 256, 0, stream>>>(in, out, n);
  };
  auto decomp = [&](const float* x, float* sf, short* sb, float* maf, short* mab, long total,
                    int C_) {
    decomp_kernel<<<(int)(total / 256), 256, 0, stream>>>(x, sf, sb, maf, mab, (int)total, C_);
  };
  auto dftT = [&](const short* srcb, float* F) {
    transpose_bf<<<dim3(16, 32, BG), 256, 0, stream>>>(srcb, Tb);
    mg(Tb, basisdb, nullptr, nullptr, nullptr, F, nullptr, cDM, M2, cL, cL, (long)cDM * cL, 0,
       65536, BG, 0, M2, M2, 0);
  };
  auto idft = [&](const short* Fb, short* ob) {
    mg(basisib, Fb, nullptr, nullptr, nullptr, nullptr, ob, cL, cDM, M2, M2, 0, 65536,
       (long)cL * cDM, BG, 0, cDM, cDM, 0);
  };
  auto ffn = [&](const short* inb, const float* addf, float* outf, const short* c1w,
                 const float* c1bias, const short* c2w, const float* c2bias) {
    for (long r = 0; r < GBL; r += RH) {
      mg(inb + r * cDM, c1w, c1bias, nullptr, nullptr, nullptr, HDb, (int)RH, cDFF, cDM, cDM, 0,
         0, 0, 1, 1, cDFF, cDFF, 0);
      mg(HDb, c2w, c2bias, addf + r * cDM, nullptr, outf + r * cDM, nullptr, (int)RH, cDM, cDFF,
         cDFF, 0, 0, 0, 1, 0, cDM, cDM, 0);
    }
  };
  auto trendg = [&](const short* mab) {
    mg(mab, Wtr3b, nullptr, TRD, nullptr, TRD, nullptr, (int)GBL, 128, 1536, 512, 0, 0, 0, 1, 0,
       cCIN, cCIN, 1);
  };
  auto mix = [&](float* F, short* Fb, const float* W, float scale) {
    modemix_kernel<<<dim3(BG, cH), 256, 0, stream>>>(F, W, F, Fb, scale);
  };

  // ---- one-time setup ----
  basis_kernel<<<(M2 * cL) / 256, 256, 0, stream>>>(basisdb, basisib);
  pe_kernel<<<(cL * cDM) / 256, 256, 0, stream>>>(pe);
  prep_kernel<<<768, 256, 0, stream>>>(tok_W, dec_trW, p3W, p3b, Bpadb, Wtr3b, p3padb, p3bpadf);
  cvt(enc_Wq, WqbE, 524288);
  cvt(enc_Wo, WobE, 524288);
  cvt(dsWq, dsWqb, 262144);
  cvt(dsWo, dsWob, 262144);
  cvt(dcWq, dcWqb, 262144);
  cvt(dcWk, dcWkb, 262144);
  cvt(dcWo, dcWob, 262144);
  cvt(enc_c1W, c1bE, 2097152);
  cvt(enc_c2W, c2bE, 2097152);
  cvt(dec_c1W, c1bD, 1048576);
  cvt(dec_c2W, c2bD, 1048576);

  for (int b0 = 0; b0 < cB; b0 += BG) {
    const float* xg = x_enc + (long)b0 * cL * cCIN;

    decomp(xg, nullptr, nullptr, TRD, nullptr, GBL * cCIN, cCIN); // trend_init -> TRD
    winbuild_kernel<<<(int)(GBL * 32 / 256), 256, 0, stream>>>(xg, winb);
    mg(winb, Bpadb, nullptr, nullptr, pe, E, Eb, (int)GBL, cDM, 128, 128, 0, 0, 0, 1, 0, cDM,
       cDM, 0); // embedding

    // ---- encoder ----
    for (int l = 0; l < 2; l++) {
      mg(Eb, WqbE + (long)l * 262144, enc_bq + l * cDM, nullptr, nullptr, nullptr, Xb, (int)GBL,
         cDM, cDM, cDM, 0, 0, 0, 1, 0, cDM, cDM, 0);                       // q -> Xb
      dftT(Xb, Fq);
      mix(Fq, Fqb, fb_enc, 1.0f);
      idft(Fqb, Xb);                                                        // o -> Xb
      mg(Xb, WobE + (long)l * 262144, enc_bo + l * cDM, E, nullptr, A, nullptr, (int)GBL, cDM,
         cDM, cDM, 0, 0, 0, 1, 0, cDM, cDM, 0);                            // x+attn -> A
      decomp(A, X, Xb, nullptr, nullptr, GA, cDM);                         // h -> X,Xb
      ffn(Xb, X, A, c1bE + (long)l * 1048576, enc_c1b + l * cDFF, c2bE + (long)l * 1048576,
          enc_c2b + l * cDM);                                              // h+y -> A
      decomp(A, E, Eb, nullptr, nullptr, GA, cDM);                         // stream -> E,Eb
    }

    // ---- decoder ----
    mg(Eb, dsWqb, dsbq, nullptr, nullptr, nullptr, Xb, (int)GBL, cDM, cDM, cDM, 0, 0, 0, 1, 0,
       cDM, cDM, 0);
    dftT(Xb, Fq);
    mix(Fq, Fqb, fb_dec, 1.0f);
    idft(Fqb, Xb);
    mg(Xb, dsWob, dsbo, E, nullptr, A, nullptr, (int)GBL, cDM, cDM, cDM, 0, 0, 0, 1, 0, cDM, cDM,
       0);                                                                  // x1 -> A
    decomp(A, X, Xb, nullptr, Sb, GA, cDM);                                 // x2 -> X,Xb; ma -> Sb
    trendg(Sb);                                                             // t1
    mg(Xb, dcWqb, dcbq, nullptr, nullptr, nullptr, Ab, (int)GBL, cDM, cDM, cDM, 0, 0, 0, 1, 0,
       cDM, cDM, 0);                                                        // q2 -> Ab
    mg(Eb, dcWkb, dcbk, nullptr, nullptr, nullptr, Sb, (int)GBL, cDM, cDM, cDM, 0, 0, 0, 1, 0,
       cDM, cDM, 0);                                                        // k -> Sb
    dftT(Ab, Fq);
    dftT(Sb, Fk);
    crossqk_kernel<<<dim3(BG, cH), 256, 0, stream>>>(Fq, Fk, QKb);
    crossqkv_kernel<<<dim3(BG, cH), 256, 0, stream>>>(QKb, Fk, Fq);
    mix(Fq, Fqb, fc_w, 1.0f / (float)(cDM * cDM));
    idft(Fqb, Ab);                                                          // o -> Ab
    mg(Ab, dcWob, dcbo, X, nullptr, E, nullptr, (int)GBL, cDM, cDM, cDM, 0, 0, 0, 1, 0, cDM, cDM,
       0);                                                                  // x3 -> E
    decomp(E, A, Ab, nullptr, Sb, GA, cDM);                                 // x4 -> A,Ab; ma->Sb
    trendg(Sb);                                                             // t2
    ffn(Ab, A, E, c1bD, dec_c1b, c2bD, dec_c2b);                            // x4+y -> E
    decomp(E, nullptr, Xb, nullptr, Sb, GA, cDM);                           // x5 -> Xb; ma -> Sb
    trendg(Sb);                                                             // t3

    // ---- final projections ----
    mg(Xb, p3padb, p3bpadf, TRD, nullptr, O1, nullptr, (int)GBL, 128, cDM, cDM, 0, 0, 0, 1, 0,
       cCIN, cCIN, 0);                                                      // trend + x@p3
    gemm_kernel<<<dim3(1, (int)(GBL / 128)), 256, 0, stream>>>(O1, p1W, p1b, O2, (int)GBL, cCIN,
                                                               cCIN);
    p2_kernel<<<dim3(BG, 32), 256, 0, stream>>>(O2, p2W, p2b,
                                                (float*)d_out + (long)b0 * cPRED * cCIN);
  }
}

// Round 9
// 3922.546 us; speedup vs baseline: 12.4303x; 1.0385x over previous
//
#include <hip/hip_runtime.h>
#include <math.h>

namespace {

constexpr int cB = 32, cL = 1024, cCIN = 32, cDM = 512, cDFF = 2048;
constexpr int cH = 8, cE = 64, cM = 64, cPRED = 256;
constexpr int M2 = 2 * cM; // 128

typedef __attribute__((ext_vector_type(8))) short short8v;
typedef __attribute__((ext_vector_type(4))) float float4v;

__device__ inline unsigned short f2bf(float f) {
  unsigned int u = __builtin_bit_cast(unsigned int, f);
  u += 0x7FFFu + ((u >> 16) & 1u); // RNE
  return (unsigned short)(u >> 16);
}

typedef const __attribute__((address_space(1))) unsigned int gu32_t;
typedef __attribute__((address_space(3))) unsigned int lu32_t;
__device__ inline void gld16(const void* g, void* l) {
  __builtin_amdgcn_global_load_lds((gu32_t*)g, (lu32_t*)l, 16, 0, 0);
}

// ================= one-time tables =================
__global__ void basis_kernel(short* __restrict__ basisdb, short* __restrict__ basisib) {
  int idx = blockIdx.x * 256 + threadIdx.x;
  if (idx >= M2 * cL) return;
  int t = idx & (cL - 1);
  int m2 = idx >> 10;
  int m = m2 >> 1;
  float ang = 6.2831853071795864f * (float)((m * t) & (cL - 1)) / (float)cL;
  float cv = cosf(ang), sv = sinf(ang);
  float vd = (m2 & 1) ? -sv : cv;
  basisdb[idx] = (short)f2bf(vd);
  float s = (m == 0) ? ((m2 & 1) ? 0.f : (1.f / (float)cL)) : (2.f / (float)cL);
  basisib[t * M2 + m2] = (short)f2bf(vd * s);
}

__global__ void pe_kernel(float* __restrict__ pe) {
  int idx = blockIdx.x * 256 + threadIdx.x;
  int o = idx & (cDM - 1), t = idx >> 9;
  int i = o >> 1;
  float freq = __expf((float)(2 * i) * (-9.210340371976184f / (float)cDM));
  float ang = freq * (float)t;
  pe[idx] = (o & 1) ? cosf(ang) : sinf(ang);
}

__global__ void cvt_kernel(const float* __restrict__ in, short* __restrict__ out, int n) {
  for (int i = blockIdx.x * 256 + threadIdx.x; i < n; i += gridDim.x * 256)
    out[i] = (short)f2bf(in[i]);
}

// Bpadb[o][j*32+c]=tok_W[o][c][j]; Wtr3b[o][j*512+c]=trW[o][c][j] (o<32); p3padb; p3bpadf
__global__ void prep_kernel(const float* __restrict__ tok_W, const float* __restrict__ trW,
                            const float* __restrict__ p3W, const float* __restrict__ p3b,
                            short* __restrict__ Bpadb, short* __restrict__ Wtr3b,
                            short* __restrict__ p3padb, float* __restrict__ p3bpadf) {
  int idx = blockIdx.x * 256 + threadIdx.x;
  if (idx < 512 * 128) {
    int o = idx >> 7, s = idx & 127, j = s >> 5, c = s & 31;
    Bpadb[idx] = (j < 3) ? (short)f2bf(tok_W[o * 96 + c * 3 + j]) : (short)0;
  }
  if (idx < 128 * 1536) {
    int o = idx / 1536, r = idx % 1536, j = r >> 9, c = r & 511;
    Wtr3b[idx] = (o < 32) ? (short)f2bf(trW[(long)o * 1536 + c * 3 + j]) : (short)0;
  }
  if (idx < 128 * 512) {
    int o = idx >> 9, k = idx & 511;
    p3padb[idx] = (o < 32) ? (short)f2bf(p3W[o * 512 + k]) : (short)0;
  }
  if (idx < 128) p3bpadf[idx] = (idx < 32) ? p3b[idx] : 0.f;
}

// win[row][128] bf16 = [x[t-1,:], x[t,:], x[t+1,:], 0] circular
__global__ void winbuild_kernel(const float* __restrict__ x, short* __restrict__ win) {
  int idx = blockIdx.x * 256 + threadIdx.x; // over rows*32
  int s4 = idx & 31;
  int row = idx >> 5;
  int t = row & (cL - 1), b = row >> 10;
  int j = s4 >> 3, c4 = s4 & 7;
  unsigned int lo = 0, hi = 0;
  if (j < 3) {
    int ts = (t + j + cL - 1) & (cL - 1);
    float4 v = *(const float4*)&x[((long)b * cL + ts) * cCIN + c4 * 4];
    lo = (unsigned int)f2bf(v.x) | ((unsigned int)f2bf(v.y) << 16);
    hi = (unsigned int)f2bf(v.z) | ((unsigned int)f2bf(v.w) << 16);
  }
  *(uint2*)&win[row * 128 + s4 * 4] = make_uint2(lo, hi);
}

// batched bf16 transpose: in [B][1024][512] -> out [B][512][1024]
__global__ __launch_bounds__(256) void transpose_bf(const short* __restrict__ in,
                                                    short* __restrict__ out) {
  __shared__ short tile[32][33];
  int b = blockIdx.z;
  in += (long)b * cL * cDM;
  out += (long)b * cL * cDM;
  int c0 = blockIdx.x * 32, t0 = blockIdx.y * 32;
  int tx = threadIdx.x & 31, ty = threadIdx.x >> 5;
#pragma unroll
  for (int r = 0; r < 32; r += 8) tile[ty + r][tx] = in[(long)(t0 + ty + r) * cDM + c0 + tx];
  __syncthreads();
#pragma unroll
  for (int r = 0; r < 32; r += 8)
    out[(long)(c0 + ty + r) * cL + t0 + tx] = tile[tx][ty + r];
}

// ================= moving-average decomposition (f32 + optional bf16 shadows) =========
__global__ void decomp_kernel(const float* __restrict__ x, float* __restrict__ sf,
                              short* __restrict__ sb, float* __restrict__ maf,
                              short* __restrict__ mab, int total, int C) {
  int idx = blockIdx.x * 256 + threadIdx.x;
  if (idx >= total) return;
  int c = idx % C;
  int t = (idx / C) & (cL - 1);
  long base = (long)(idx / (C * cL)) * cL * C + c;
  float s = 0.f;
#pragma unroll
  for (int j = -12; j <= 12; j++) {
    int tt = t + j;
    tt = tt < 0 ? 0 : (tt >= cL ? cL - 1 : tt);
    s += x[base + (long)tt * C];
  }
  float ma = s * (1.0f / 25.0f);
  float se = x[idx] - ma;
  if (sf) sf[idx] = se;
  if (sb) sb[idx] = (short)f2bf(se);
  if (maf) maf[idx] = ma;
  if (mab) mab[idx] = (short)f2bf(ma);
}

// ================= final time projection =================
__global__ __launch_bounds__(256) void p2_kernel(const float* __restrict__ x,
                                                 const float* __restrict__ W,
                                                 const float* __restrict__ bias,
                                                 float* __restrict__ out) {
  __shared__ float tile[256 * 32];
  int b = blockIdx.x;
  int p0 = blockIdx.y * 8;
  int c = threadIdx.x & 31, pl = threadIdx.x >> 5;
  const float* xb = x + (long)b * cL * cCIN;
  const float* w = W + (long)(p0 + pl) * cL;
  float s = 0.f;
  for (int l0 = 0; l0 < cL; l0 += 256) {
    __syncthreads();
    for (int i = threadIdx.x; i < 256 * 32; i += 256) tile[i] = xb[(long)l0 * 32 + i];
    __syncthreads();
#pragma unroll 8
    for (int l = 0; l < 256; l++) s += tile[l * 32 + c] * w[l0 + l];
  }
  out[((long)b * cPRED + p0 + pl) * cCIN + c] = s + bias[p0 + pl];
}

// ====== per-(h,mode) complex mode mix; output bf16 TRANSPOSED [b][m2][dm] for NT chain =====
__global__ __launch_bounds__(256) void modemix_t_kernel(const float* __restrict__ F,
                                                        const float* __restrict__ W,
                                                        short* __restrict__ Gt, float scale) {
  int b = blockIdx.x, h = blockIdx.y;
  __shared__ float2 Fs[cE][cM];
  __shared__ short ot[128][72];
  const float* Fb = F + ((long)b * cDM + h * cE) * M2;
  for (int i = threadIdx.x; i < cE * cM; i += 256) {
    int e = i >> 6, x = i & 63;
    Fs[e][x] = ((const float2*)(Fb + (long)e * M2))[x];
  }
  __syncthreads();
  int x = threadIdx.x & 63, og = threadIdx.x >> 6;
  float2 acc[16];
#pragma unroll
  for (int i = 0; i < 16; i++) acc[i] = make_float2(0.f, 0.f);
  for (int e = 0; e < cE; e++) {
    float2 f = Fs[e][x];
#pragma unroll
    for (int i = 0; i < 16; i++) {
      int o = og * 16 + i;
      const float2 w = *(const float2*)(W + ((((long)h * cE + e) * cE + o) * cM + x) * 2);
      acc[i].x += f.x * w.x - f.y * w.y;
      acc[i].y += f.x * w.y + f.y * w.x;
    }
  }
#pragma unroll
  for (int i = 0; i < 16; i++) {
    int o = og * 16 + i;
    ot[2 * x][o] = (short)f2bf(acc[i].x * scale);
    ot[2 * x + 1][o] = (short)f2bf(acc[i].y * scale);
  }
  __syncthreads();
  short* gb = Gt + (long)b * (M2 * cDM) + h * cE;
  for (int u = threadIdx.x; u < 1024; u += 256) {
    int row = u >> 3, seg = u & 7;
    *(uint4*)&gb[(long)row * cDM + seg * 8] = *(const uint4*)&ot[row][seg * 8];
  }
}

// ================= fourier_cross =================
__global__ __launch_bounds__(256) void crossqk_kernel(const float* __restrict__ Fq,
                                                      const float* __restrict__ Fk,
                                                      float* __restrict__ QKb) {
  int b = blockIdx.x, h = blockIdx.y;
  __shared__ float2 Ks[cE][cM];
  const float* kb = Fk + ((long)b * cDM + h * cE) * M2;
  for (int i = threadIdx.x; i < cE * cM; i += 256) {
    int e = i >> 6, y = i & 63;
    Ks[e][y] = ((const float2*)(kb + (long)e * M2))[y];
  }
  __syncthreads();
  int x = threadIdx.x & 63, yg = threadIdx.x >> 6;
  const float* qb = Fq + ((long)b * cDM + h * cE) * M2;
  float2 acc[16];
#pragma unroll
  for (int i = 0; i < 16; i++) acc[i] = make_float2(0.f, 0.f);
  for (int e = 0; e < cE; e++) {
    float2 q = ((const float2*)(qb + (long)e * M2))[x];
#pragma unroll
    for (int i = 0; i < 16; i++) {
      float2 k = Ks[e][yg * 16 + i];
      acc[i].x += q.x * k.x - q.y * k.y;
      acc[i].y += q.x * k.y + q.y * k.x;
    }
  }
  float2* qkb = (float2*)(QKb) + (((long)b * cH + h) * cM * cM);
#pragma unroll
  for (int i = 0; i < 16; i++) {
    int y = yg * 16 + i;
    float a = acc[i].x, bi = acc[i].y;
    float re, im;
    float t2a = 2.f * a;
    if (fabsf(t2a) > 60.f) {
      re = t2a > 0.f ? 1.f : -1.f;
      im = 0.f;
    } else {
      float denom = coshf(t2a) + cosf(2.f * bi);
      re = sinhf(t2a) / denom;
      im = sinf(2.f * bi) / denom;
    }
    qkb[x * cM + y] = make_float2(re, im);
  }
}

__global__ __launch_bounds__(256) void crossqkv_kernel(const float* __restrict__ QKb,
                                                       const float* __restrict__ Fk,
                                                       float* __restrict__ Fq) {
  int b = blockIdx.x, h = blockIdx.y;
  __shared__ float2 qks[cM][cM];
  const float2* qkb = (const float2*)(QKb) + (((long)b * cH + h) * cM * cM);
  for (int i = threadIdx.x; i < cM * cM; i += 256) qks[i >> 6][i & 63] = qkb[i];
  __syncthreads();
  int e = threadIdx.x & 63, xg = threadIdx.x >> 6;
  const float* kb = Fk + ((long)b * cDM + h * cE) * M2;
  float2 acc[16];
#pragma unroll
  for (int i = 0; i < 16; i++) acc[i] = make_float2(0.f, 0.f);
  for (int y = 0; y < cM; y++) {
    float2 k = ((const float2*)(kb + (long)e * M2))[y];
#pragma unroll
    for (int i = 0; i < 16; i++) {
      float2 qk = qks[xg * 16 + i][y];
      acc[i].x += qk.x * k.x - qk.y * k.y;
      acc[i].y += qk.x * k.y + qk.y * k.x;
    }
  }
  float* ob = Fq + ((long)b * cDM + h * cE) * M2;
#pragma unroll
  for (int i = 0; i < 16; i++) {
    int x = xg * 16 + i;
    ((float2*)(ob + (long)e * M2))[x] = acc[i];
  }
}

// ================= f32 shader GEMM (tiny p1 only) =================
constexpr int GBM = 128, GBN = 128, GBK = 16, LPAD = 132;

__global__ __launch_bounds__(256) void gemm_kernel(const float* __restrict__ A,
                                                   const float* __restrict__ B,
                                                   const float* __restrict__ bias,
                                                   float* __restrict__ C, int M, int N, int K) {
  __shared__ float As[GBK][LPAD];
  __shared__ float Bs[GBK][LPAD];
  int n0 = blockIdx.x * GBN, m0 = blockIdx.y * GBM;
  int tid = threadIdx.x;
  int tx = tid & 15, ty = tid >> 4;
  float acc[8][8];
#pragma unroll
  for (int i = 0; i < 8; i++)
#pragma unroll
    for (int j = 0; j < 8; j++) acc[i][j] = 0.f;

  for (int k0 = 0; k0 < K; k0 += GBK) {
#pragma unroll
    for (int p = 0; p < 8; p++) {
      int i = p * 256 + tid;
      int mm = i >> 4, kk = i & 15;
      int gm = m0 + mm;
      As[kk][mm] = (gm < M && k0 + kk < K) ? A[(long)gm * K + k0 + kk] : 0.f;
    }
#pragma unroll
    for (int p = 0; p < 8; p++) {
      int i = p * 256 + tid;
      int nn = i >> 4, kk = i & 15;
      int gn = n0 + nn;
      Bs[kk][nn] = (gn < N && k0 + kk < K) ? B[(long)gn * K + k0 + kk] : 0.f;
    }
    __syncthreads();
#pragma unroll
    for (int kk = 0; kk < GBK; kk++) {
      float a[8], bb[8];
      *(float4*)&a[0] = *(const float4*)&As[kk][ty * 8];
      *(float4*)&a[4] = *(const float4*)&As[kk][ty * 8 + 4];
      *(float4*)&bb[0] = *(const float4*)&Bs[kk][tx * 8];
      *(float4*)&bb[4] = *(const float4*)&Bs[kk][tx * 8 + 4];
#pragma unroll
      for (int i = 0; i < 8; i++)
#pragma unroll
        for (int j = 0; j < 8; j++) acc[i][j] += a[i] * bb[j];
    }
    __syncthreads();
  }

  for (int i = 0; i < 8; i++) {
    int gm = m0 + ty * 8 + i;
    if (gm >= M) break;
    long rowoff = (long)gm * N;
    for (int j = 0; j < 8; j++) {
      int gn = n0 + tx * 8 + j;
      if (gn < N) C[rowoff + gn] = acc[i][j] + (bias ? bias[gn] : 0.f);
    }
  }
}

// ===== bf16 MFMA GEMM (m97 single-buffer, swizzled, XCD-chunked) =====
// C = A @ B^T. amode=1: circular t-shift rows (trend conv). m0b: += 1024*m0b[gr] at gc==0
// (DFT mode-0 bias injection).
__global__ __launch_bounds__(256) void mfma_gemm_bf(const short* __restrict__ A,
                                                    const short* __restrict__ B,
                                                    const float* __restrict__ bias,
                                                    const float* __restrict__ addend,
                                                    const float* __restrict__ pe,
                                                    const float* __restrict__ m0b,
                                                    float* __restrict__ Cf, short* __restrict__ Cb,
                                                    int M, int N, int K, int lda, long sA, long sB,
                                                    long sC, int relu, int Nreal, int ldc,
                                                    int amode) {
  __shared__ __align__(16) short As[8192];
  __shared__ __align__(16) short Bs[8192];
  int nwg = gridDim.x * gridDim.y * gridDim.z;
  int orig = blockIdx.x + gridDim.x * (blockIdx.y + gridDim.y * blockIdx.z);
  int q = nwg >> 3, r = nwg & 7;
  int xcd = orig & 7, ii = orig >> 3;
  int flat = (xcd < r ? xcd * (q + 1) : r * (q + 1) + (xcd - r) * q) + ii;
  int bx = flat % (int)gridDim.x;
  int tmp = flat / (int)gridDim.x;
  int by = tmp % (int)gridDim.y;
  int bz = tmp / (int)gridDim.y;

  int z = bz;
  A += (long)z * sA;
  B += (long)z * sB;
  if (Cf) Cf += (long)z * sC;
  if (Cb) Cb += (long)z * sC;
  const float* Ad = addend ? addend + (long)z * sC : nullptr;
  int n0 = bx * 128, m0 = by * 128;
  int tid = threadIdx.x;
  int lane = tid & 63;
  int w = tid >> 6;
  int wm = w & 1, wn = w >> 1;
  int lr = lane & 15, lg = lane >> 4;
  int lrow = lane >> 3;
  int scol = ((lane & 7) * 8) ^ (lrow << 3);

  float4v acc[4][4];
#pragma unroll
  for (int i = 0; i < 4; i++)
#pragma unroll
    for (int j = 0; j < 4; j++) acc[i][j] = (float4v){0.f, 0.f, 0.f, 0.f};

  auto stage = [&](int k0) {
#pragma unroll
    for (int j = 0; j < 4; j++) {
      int seg = w * 4 + j;
      int row = seg * 8 + lrow;
      const short* ga;
      if (amode == 0) {
        ga = A + (long)(m0 + row) * lda + k0 + scol;
      } else {
        int r2 = m0 + row;
        int bb = r2 >> 10, t = r2 & 1023;
        int jj = k0 >> 9, c0 = k0 & 511;
        ga = A + ((((long)(bb << 10)) | ((t + jj + 1023) & 1023)) << 9) + c0 + scol;
      }
      gld16(ga, &As[seg * 512]);
      const short* gb = B + (long)(n0 + row) * K + k0 + scol;
      gld16(gb, &Bs[seg * 512]);
    }
  };

  int nk = K >> 6;
  int swr = (lr & 7) << 3;
  for (int t = 0; t < nk; ++t) {
    stage(t << 6);
    asm volatile("s_waitcnt vmcnt(0)" ::: "memory");
    __syncthreads();
#pragma unroll
    for (int ks = 0; ks < 2; ks++) {
      short8v af[4], bfr[4];
#pragma unroll
      for (int mi = 0; mi < 4; mi++)
        af[mi] = *(const short8v*)&As[(wm * 64 + mi * 16 + lr) * 64 + ((ks * 32 + lg * 8) ^ swr)];
#pragma unroll
      for (int ni = 0; ni < 4; ni++)
        bfr[ni] = *(const short8v*)&Bs[(wn * 64 + ni * 16 + lr) * 64 + ((ks * 32 + lg * 8) ^ swr)];
#pragma unroll
      for (int mi = 0; mi < 4; mi++)
#pragma unroll
        for (int ni = 0; ni < 4; ni++)
          acc[mi][ni] =
              __builtin_amdgcn_mfma_f32_16x16x32_bf16(af[mi], bfr[ni], acc[mi][ni], 0, 0, 0);
    }
    __syncthreads();
  }

#pragma unroll
  for (int mi = 0; mi < 4; mi++) {
#pragma unroll
    for (int i = 0; i < 4; i++) {
      int gr = m0 + wm * 64 + mi * 16 + lg * 4 + i;
      long rowoff = (long)gr * ldc;
#pragma unroll
      for (int ni = 0; ni < 4; ni++) {
        int gc = n0 + wn * 64 + ni * 16 + lr;
        if (gc < Nreal) {
          float v = acc[mi][ni][i];
          if (bias) v += bias[gc];
          if (pe) v += pe[((gr & (cL - 1)) << 9) + gc];
          if (m0b && gc == 0) v += 1024.f * m0b[gr];
          if (Ad) v += Ad[rowoff + gc];
          if (relu) v = fmaxf(v, 0.f);
          if (Cf) Cf[rowoff + gc] = v;
          if (Cb) Cb[rowoff + gc] = (short)f2bf(v);
        }
      }
    }
  }
}

} // namespace

extern "C" void kernel_launch(void* const* d_in, const int* in_sizes, int n_in, void* d_out,
                              int out_size, void* d_ws, size_t ws_size, hipStream_t stream) {
  const float* x_enc = (const float*)d_in[0];
  const float* tok_W = (const float*)d_in[1];
  const float* enc_Wq = (const float*)d_in[2];
  const float* enc_Wo = (const float*)d_in[5];
  const float* enc_bq = (const float*)d_in[6];
  const float* enc_bo = (const float*)d_in[9];
  const float* dsWq = (const float*)d_in[10];
  const float* dsWo = (const float*)d_in[13];
  const float* dsbq = (const float*)d_in[14];
  const float* dsbo = (const float*)d_in[17];
  const float* dcWq = (const float*)d_in[18];
  const float* dcWk = (const float*)d_in[19];
  const float* dcWo = (const float*)d_in[21];
  const float* dcbq = (const float*)d_in[22];
  const float* dcbk = (const float*)d_in[23];
  const float* dcbo = (const float*)d_in[25];
  const float* enc_c1W = (const float*)d_in[26];
  const float* enc_c1b = (const float*)d_in[27];
  const float* enc_c2W = (const float*)d_in[28];
  const float* enc_c2b = (const float*)d_in[29];
  const float* dec_c1W = (const float*)d_in[30];
  const float* dec_c1b = (const float*)d_in[31];
  const float* dec_c2W = (const float*)d_in[32];
  const float* dec_c2b = (const float*)d_in[33];
  const float* dec_trW = (const float*)d_in[34];
  const float* fb_enc = (const float*)d_in[35];
  const float* fb_dec = (const float*)d_in[36];
  const float* fc_w = (const float*)d_in[37];
  const float* p1W = (const float*)d_in[38];
  const float* p1b = (const float*)d_in[39];
  const float* p2W = (const float*)d_in[40];
  const float* p2b = (const float*)d_in[41];
  const float* p3W = (const float*)d_in[42];
  const float* p3b = (const float*)d_in[43];

  // ---- layout sizing (dry-run) ----
  auto layout_bytes = [&](long BG, long RH) -> size_t {
    size_t t = 0;
    auto add = [&](size_t b) { t = (t + b + 255) & ~(size_t)255; };
    add(2 * 262144 * 2); add(2 * 262144 * 2);
    add(262144 * 2); add(262144 * 2); add(262144 * 2); add(262144 * 2); add(262144 * 2);
    add(2 * 1048576 * 2); add(2 * 1048576 * 2); add(1048576 * 2); add(1048576 * 2);
    add(131072 * 2); add(131072 * 2); add(65536 * 2); add(196608 * 2); add(65536 * 2);
    add(128 * 4); add(524288 * 4);
    long GA = BG * cL * cDM;
    add(GA * 4); add(GA * 4); add(GA * 4);
    add(GA * 2); add(GA * 2); add(GA * 2); add(GA * 2);
    add(BG * cL * 128 * 2);
    size_t ub = (size_t)GA * 2;
    size_t hd = (size_t)RH * cDFF * 2;
    add(ub > hd ? ub : hd);
    add(BG * 65536 * 4); add(BG * 65536 * 4); add(BG * 65536 * 4);            // Fq Fk QKb
    add(BG * 65536 * 2); add(BG * 65536 * 2); add(BG * 65536 * 2); add(BG * 65536 * 2); // FEb FXb Gtb Hb
    add(BG * cL * cCIN * 4); add(BG * cL * cCIN * 4); add(BG * cL * cCIN * 4);
    return t;
  };
  int BG = cB;
  while (BG > 1 && layout_bytes(BG, 512) > ws_size) BG >>= 1;
  long RH = (long)BG * cL;
  while (RH > 512 && layout_bytes(BG, RH) > ws_size) RH >>= 1;

  long GBL = (long)BG * cL;
  char* base = (char*)d_ws;
  size_t off = 0;
  auto alloc = [&](size_t bytes) -> void* {
    void* p = base + off;
    off = (off + bytes + 255) & ~(size_t)255;
    return p;
  };
  short* WqbE = (short*)alloc(2 * 262144 * 2);
  short* WobE = (short*)alloc(2 * 262144 * 2);
  short* dsWqb = (short*)alloc(262144 * 2);
  short* dsWob = (short*)alloc(262144 * 2);
  short* dcWqb = (short*)alloc(262144 * 2);
  short* dcWkb = (short*)alloc(262144 * 2);
  short* dcWob = (short*)alloc(262144 * 2);
  short* c1bE = (short*)alloc(2 * 1048576 * 2);
  short* c2bE = (short*)alloc(2 * 1048576 * 2);
  short* c1bD = (short*)alloc(1048576 * 2);
  short* c2bD = (short*)alloc(1048576 * 2);
  short* basisdb = (short*)alloc(131072 * 2);
  short* basisib = (short*)alloc(131072 * 2);
  short* Bpadb = (short*)alloc(65536 * 2);
  short* Wtr3b = (short*)alloc(196608 * 2);
  short* p3padb = (short*)alloc(65536 * 2);
  float* p3bpadf = (float*)alloc(128 * 4);
  float* pe = (float*)alloc(524288 * 4);
  long GA = GBL * cDM;
  float* E = (float*)alloc(GA * 4);
  float* X = (float*)alloc(GA * 4);
  float* A = (float*)alloc(GA * 4);
  short* Eb = (short*)alloc(GA * 2);
  short* Xb = (short*)alloc(GA * 2);
  short* Ab = (short*)alloc(GA * 2);
  short* Sb = (short*)alloc(GA * 2);
  short* winb = (short*)alloc(GBL * 128 * 2);
  size_t ubsz = (size_t)GA * 2;
  size_t hdsz = (size_t)RH * cDFF * 2;
  short* UB = (short*)alloc(ubsz > hdsz ? ubsz : hdsz);
  short* Tb = UB;
  short* HDb = UB;
  float* Fq = (float*)alloc((size_t)BG * 65536 * 4);
  float* Fk = (float*)alloc((size_t)BG * 65536 * 4);
  float* QKb = (float*)alloc((size_t)BG * 65536 * 4);
  short* FEb = (short*)alloc((size_t)BG * 65536 * 2); // modes of stream  [b][128][512]
  short* FXb = (short*)alloc((size_t)BG * 65536 * 2); // modes of X2      [b][128][512]
  short* Gtb = (short*)alloc((size_t)BG * 65536 * 2); // mixed modes bf16 [b][128][512]
  short* Hb = (short*)alloc((size_t)BG * 65536 * 2);  // Wo@mixed bf16    [b][512][128]
  float* TRD = (float*)alloc(GBL * cCIN * 4);
  float* O1 = (float*)alloc(GBL * cCIN * 4);
  float* O2 = (float*)alloc(GBL * cCIN * 4);

  auto mg = [&](const short* Am, const short* Bm, const float* bias, const float* add,
                const float* peA, const float* m0b, float* Cf, short* Cb, int Mm, int Nn, int Kk,
                int lda, long sA, long sB, long sC, int batch, int relu, int Nreal, int ldc,
                int amode) {
    dim3 g(Nn / 128, Mm / 128, batch);
    mfma_gemm_bf<<<g, 256, 0, stream>>>(Am, Bm, bias, add, peA, m0b, Cf, Cb, Mm, Nn, Kk, lda, sA,
                                        sB, sC, relu, Nreal, ldc, amode);
  };
  auto cvt = [&](const float* in, short* out, int n) {
    int g = (n + 255) / 256;
    if (g > 4096) g = 4096;
    cvt_kernel<<<g, 256, 0, stream>>>(in, out, n);
  };
  auto decomp = [&](const float* x, float* sf, short* sb, float* maf, short* mab, long total,
                    int C_) {
    decomp_kernel<<<(int)(total / 256), 256, 0, stream>>>(x, sf, sb, maf, mab, (int)total, C_);
  };
  // dft: transpose src bf16 -> Tb [b][512][1024]; F[b][m2][dm] bf16 = basisd @ Tb^T
  auto dft = [&](const short* srcb, short* Fout) {
    transpose_bf<<<dim3(16, 32, BG), 256, 0, stream>>>(srcb, Tb);
    mg(basisdb, Tb, nullptr, nullptr, nullptr, nullptr, nullptr, Fout, M2, cDM, cL, cL, 0,
       (long)cDM * cL, 65536, BG, 0, cDM, cDM, 0);
  };
  // mode-space projection: C[b][512][128] = W @ F_b^T (+1024*b at m2=0)
  auto modeproj = [&](const short* Wb, const short* Fin, const float* m0b, float* Cf, short* Cb) {
    mg(Wb, Fin, nullptr, nullptr, nullptr, m0b, Cf, Cb, cDM, M2, cDM, cDM, 0, 65536, 65536, BG, 0,
       M2, M2, 0);
  };
  // idft: out[b][1024][512] f32 = basisi @ H_b^T (+bias +addend)
  auto idft = [&](const short* Hin, const float* bias, const float* add, float* Cf) {
    mg(basisib, Hin, bias, add, nullptr, nullptr, Cf, nullptr, cL, cDM, M2, M2, 0, 65536,
       (long)cL * cDM, BG, 0, cDM, cDM, 0);
  };
  auto ffn = [&](const short* inb, const float* addf, float* outf, const short* c1w,
                 const float* c1bias, const short* c2w, const float* c2bias) {
    for (long r = 0; r < GBL; r += RH) {
      mg(inb + r * cDM, c1w, c1bias, nullptr, nullptr, nullptr, nullptr, HDb, (int)RH, cDFF, cDM,
         cDM, 0, 0, 0, 1, 1, cDFF, cDFF, 0);
      mg(HDb, c2w, c2bias, addf + r * cDM, nullptr, nullptr, outf + r * cDM, nullptr, (int)RH,
         cDM, cDFF, cDFF, 0, 0, 0, 1, 0, cDM, cDM, 0);
    }
  };
  auto trendg = [&](const short* mab) {
    mg(mab, Wtr3b, nullptr, TRD, nullptr, nullptr, TRD, nullptr, (int)GBL, 128, 1536, 512, 0, 0,
       0, 1, 0, cCIN, cCIN, 1);
  };
  auto mixt = [&](const float* F, const float* W, float scale) {
    modemix_t_kernel<<<dim3(BG, cH), 256, 0, stream>>>(F, W, Gtb, scale);
  };

  // ---- one-time setup ----
  basis_kernel<<<(M2 * cL) / 256, 256, 0, stream>>>(basisdb, basisib);
  pe_kernel<<<(cL * cDM) / 256, 256, 0, stream>>>(pe);
  prep_kernel<<<768, 256, 0, stream>>>(tok_W, dec_trW, p3W, p3b, Bpadb, Wtr3b, p3padb, p3bpadf);
  cvt(enc_Wq, WqbE, 524288);
  cvt(enc_Wo, WobE, 524288);
  cvt(dsWq, dsWqb, 262144);
  cvt(dsWo, dsWob, 262144);
  cvt(dcWq, dcWqb, 262144);
  cvt(dcWk, dcWkb, 262144);
  cvt(dcWo, dcWob, 262144);
  cvt(enc_c1W, c1bE, 2097152);
  cvt(enc_c2W, c2bE, 2097152);
  cvt(dec_c1W, c1bD, 1048576);
  cvt(dec_c2W, c2bD, 1048576);

  for (int b0 = 0; b0 < cB; b0 += BG) {
    const float* xg = x_enc + (long)b0 * cL * cCIN;

    decomp(xg, nullptr, nullptr, TRD, nullptr, GBL * cCIN, cCIN); // trend_init -> TRD
    winbuild_kernel<<<(int)(GBL * 32 / 256), 256, 0, stream>>>(xg, winb);
    mg(winb, Bpadb, nullptr, nullptr, pe, nullptr, E, Eb, (int)GBL, cDM, 128, 128, 0, 0, 0, 1, 0,
       cDM, cDM, 0); // embedding

    // ---- encoder ----
    for (int l = 0; l < 2; l++) {
      dft(Eb, FEb);                                                // modes of stream
      modeproj(WqbE + (long)l * 262144, FEb, enc_bq + l * cDM, Fq, nullptr); // q modes
      mixt(Fq, fb_enc, 1.0f);                                      // mixed -> Gtb (bf16-T)
      modeproj(WobE + (long)l * 262144, Gtb, nullptr, nullptr, Hb);          // Wo @ mixed
      idft(Hb, enc_bo + l * cDM, E, A);                            // x + attn -> A
      decomp(A, X, Xb, nullptr, nullptr, GA, cDM);                 // h -> X,Xb
      ffn(Xb, X, A, c1bE + (long)l * 1048576, enc_c1b + l * cDFF, c2bE + (long)l * 1048576,
          enc_c2b + l * cDM);                                      // h+y -> A
      decomp(A, E, Eb, nullptr, nullptr, GA, cDM);                 // stream -> E,Eb
    }

    // ---- decoder ----
    dft(Eb, FEb);                                                  // modes of enc-out (shared!)
    modeproj(dsWqb, FEb, dsbq, Fq, nullptr);
    mixt(Fq, fb_dec, 1.0f);
    modeproj(dsWob, Gtb, nullptr, nullptr, Hb);
    idft(Hb, dsbo, E, A);                                          // x1 -> A
    decomp(A, X, Xb, nullptr, Sb, GA, cDM);                        // x2 -> X,Xb; ma -> Sb
    trendg(Sb);                                                    // t1

    dft(Xb, FXb);                                                  // modes of x2
    modeproj(dcWqb, FXb, dcbq, Fq, nullptr);                       // xq
    modeproj(dcWkb, FEb, dcbk, Fk, nullptr);                       // xk (reuses FEb!)
    crossqk_kernel<<<dim3(BG, cH), 256, 0, stream>>>(Fq, Fk, QKb);
    crossqkv_kernel<<<dim3(BG, cH), 256, 0, stream>>>(QKb, Fk, Fq);
    mixt(Fq, fc_w, 1.0f / (float)(cDM * cDM));
    modeproj(dcWob, Gtb, nullptr, nullptr, Hb);
    idft(Hb, dcbo, X, E);                                          // x3 -> E
    decomp(E, A, Ab, nullptr, Sb, GA, cDM);                        // x4 -> A,Ab; ma -> Sb
    trendg(Sb);                                                    // t2
    ffn(Ab, A, E, c1bD, dec_c1b, c2bD, dec_c2b);                   // x4+y -> E
    decomp(E, nullptr, Xb, nullptr, Sb, GA, cDM);                  // x5 -> Xb; ma -> Sb
    trendg(Sb);                                                    // t3

    // ---- final projections ----
    mg(Xb, p3padb, p3bpadf, TRD, nullptr, nullptr, O1, nullptr, (int)GBL, 128, cDM, cDM, 0, 0, 0,
       1, 0, cCIN, cCIN, 0);                                       // trend + x@p3
    gemm_kernel<<<dim3(1, (int)(GBL / 128)), 256, 0, stream>>>(O1, p1W, p1b, O2, (int)GBL, cCIN,
                                                               cCIN);
    p2_kernel<<<dim3(BG, 32), 256, 0, stream>>>(O2, p2W, p2b,
                                                (float*)d_out + (long)b0 * cPRED * cCIN);
  }
}

// Round 10
// 3747.490 us; speedup vs baseline: 13.0110x; 1.0467x over previous
//
#include <hip/hip_runtime.h>
#include <math.h>

namespace {

constexpr int cB = 32, cL = 1024, cCIN = 32, cDM = 512, cDFF = 2048;
constexpr int cH = 8, cE = 64, cM = 64, cPRED = 256;
constexpr int M2 = 2 * cM; // 128

typedef __attribute__((ext_vector_type(8))) short short8v;
typedef __attribute__((ext_vector_type(4))) float float4v;

__device__ inline unsigned short f2bf(float f) {
  unsigned int u = __builtin_bit_cast(unsigned int, f);
  u += 0x7FFFu + ((u >> 16) & 1u); // RNE
  return (unsigned short)(u >> 16);
}

typedef const __attribute__((address_space(1))) unsigned int gu32_t;
typedef __attribute__((address_space(3))) unsigned int lu32_t;
__device__ inline void gld16(const void* g, void* l) {
  __builtin_amdgcn_global_load_lds((gu32_t*)g, (lu32_t*)l, 16, 0, 0);
}

// ================= one-time tables =================
__global__ void basis_kernel(short* __restrict__ basisdb, short* __restrict__ basisib) {
  int idx = blockIdx.x * 256 + threadIdx.x;
  if (idx >= M2 * cL) return;
  int t = idx & (cL - 1);
  int m2 = idx >> 10;
  int m = m2 >> 1;
  float ang = 6.2831853071795864f * (float)((m * t) & (cL - 1)) / (float)cL;
  float cv = cosf(ang), sv = sinf(ang);
  float vd = (m2 & 1) ? -sv : cv;
  basisdb[idx] = (short)f2bf(vd);
  float s = (m == 0) ? ((m2 & 1) ? 0.f : (1.f / (float)cL)) : (2.f / (float)cL);
  basisib[t * M2 + m2] = (short)f2bf(vd * s);
}

__global__ void pe_kernel(float* __restrict__ pe) {
  int idx = blockIdx.x * 256 + threadIdx.x;
  int o = idx & (cDM - 1), t = idx >> 9;
  int i = o >> 1;
  float freq = __expf((float)(2 * i) * (-9.210340371976184f / (float)cDM));
  float ang = freq * (float)t;
  pe[idx] = (o & 1) ? cosf(ang) : sinf(ang);
}

__global__ void cvt_kernel(const float* __restrict__ in, short* __restrict__ out, int n) {
  for (int i = blockIdx.x * 256 + threadIdx.x; i < n; i += gridDim.x * 256)
    out[i] = (short)f2bf(in[i]);
}

// Bpadb[o][j*32+c]=tok_W[o][c][j]; Wtr3b[o][j*512+c]=trW[o][c][j] (o<32); p3padb; p3bpadf
__global__ void prep_kernel(const float* __restrict__ tok_W, const float* __restrict__ trW,
                            const float* __restrict__ p3W, const float* __restrict__ p3b,
                            short* __restrict__ Bpadb, short* __restrict__ Wtr3b,
                            short* __restrict__ p3padb, float* __restrict__ p3bpadf) {
  int idx = blockIdx.x * 256 + threadIdx.x;
  if (idx < 512 * 128) {
    int o = idx >> 7, s = idx & 127, j = s >> 5, c = s & 31;
    Bpadb[idx] = (j < 3) ? (short)f2bf(tok_W[o * 96 + c * 3 + j]) : (short)0;
  }
  if (idx < 128 * 1536) {
    int o = idx / 1536, r = idx % 1536, j = r >> 9, c = r & 511;
    Wtr3b[idx] = (o < 32) ? (short)f2bf(trW[(long)o * 1536 + c * 3 + j]) : (short)0;
  }
  if (idx < 128 * 512) {
    int o = idx >> 9, k = idx & 511;
    p3padb[idx] = (o < 32) ? (short)f2bf(p3W[o * 512 + k]) : (short)0;
  }
  if (idx < 128) p3bpadf[idx] = (idx < 32) ? p3b[idx] : 0.f;
}

// win[row][128] bf16 = [x[t-1,:], x[t,:], x[t+1,:], 0] circular
__global__ void winbuild_kernel(const float* __restrict__ x, short* __restrict__ win) {
  int idx = blockIdx.x * 256 + threadIdx.x;
  int s4 = idx & 31;
  int row = idx >> 5;
  int t = row & (cL - 1), b = row >> 10;
  int j = s4 >> 3, c4 = s4 & 7;
  unsigned int lo = 0, hi = 0;
  if (j < 3) {
    int ts = (t + j + cL - 1) & (cL - 1);
    float4 v = *(const float4*)&x[((long)b * cL + ts) * cCIN + c4 * 4];
    lo = (unsigned int)f2bf(v.x) | ((unsigned int)f2bf(v.y) << 16);
    hi = (unsigned int)f2bf(v.z) | ((unsigned int)f2bf(v.w) << 16);
  }
  *(uint2*)&win[row * 128 + s4 * 4] = make_uint2(lo, hi);
}

// batched bf16 transpose: in [B][1024][512] -> out [B][512][1024]
__global__ __launch_bounds__(256) void transpose_bf(const short* __restrict__ in,
                                                    short* __restrict__ out) {
  __shared__ short tile[32][33];
  int b = blockIdx.z;
  in += (long)b * cL * cDM;
  out += (long)b * cL * cDM;
  int c0 = blockIdx.x * 32, t0 = blockIdx.y * 32;
  int tx = threadIdx.x & 31, ty = threadIdx.x >> 5;
#pragma unroll
  for (int r = 0; r < 32; r += 8) tile[ty + r][tx] = in[(long)(t0 + ty + r) * cDM + c0 + tx];
  __syncthreads();
#pragma unroll
  for (int r = 0; r < 32; r += 8)
    out[(long)(c0 + ty + r) * cL + t0 + tx] = tile[tx][ty + r];
}

// ============ moving-average decomposition, sliding-window (8 t per thread) ============
__global__ void decomp_kernel(const float* __restrict__ x, float* __restrict__ sf,
                              short* __restrict__ sb, float* __restrict__ maf,
                              short* __restrict__ mab, int n8, int C) {
  int idx = blockIdx.x * 256 + threadIdx.x;
  if (idx >= n8) return;
  int c = idx % C;
  int u = idx / C;
  int t0 = (u & 127) * 8;
  int b = u >> 7;
  long base = (long)b * cL * C + c;
  float s = 0.f;
#pragma unroll
  for (int j = -12; j <= 12; j++) {
    int tt = t0 + j;
    tt = tt < 0 ? 0 : (tt >= cL ? cL - 1 : tt);
    s += x[base + (long)tt * C];
  }
#pragma unroll
  for (int k = 0; k < 8; k++) {
    int t = t0 + k;
    long e = base + (long)t * C;
    float ma = s * (1.0f / 25.0f);
    float se = x[e] - ma;
    if (sf) sf[e] = se;
    if (sb) sb[e] = (short)f2bf(se);
    if (maf) maf[e] = ma;
    if (mab) mab[e] = (short)f2bf(ma);
    int ta = t + 13;
    ta = ta >= cL ? cL - 1 : ta;
    int td = t - 12;
    td = td < 0 ? 0 : td;
    s += x[base + (long)ta * C] - x[base + (long)td * C];
  }
}

// ================= final time projection =================
__global__ __launch_bounds__(256) void p2_kernel(const float* __restrict__ x,
                                                 const float* __restrict__ W,
                                                 const float* __restrict__ bias,
                                                 float* __restrict__ out) {
  __shared__ float tile[256 * 32];
  int b = blockIdx.x;
  int p0 = blockIdx.y * 8;
  int c = threadIdx.x & 31, pl = threadIdx.x >> 5;
  const float* xb = x + (long)b * cL * cCIN;
  const float* w = W + (long)(p0 + pl) * cL;
  float s = 0.f;
  for (int l0 = 0; l0 < cL; l0 += 256) {
    __syncthreads();
    for (int i = threadIdx.x; i < 256 * 32; i += 256) tile[i] = xb[(long)l0 * 32 + i];
    __syncthreads();
#pragma unroll 8
    for (int l = 0; l < 256; l++) s += tile[l * 32 + c] * w[l0 + l];
  }
  out[((long)b * cPRED + p0 + pl) * cCIN + c] = s + bias[p0 + pl];
}

// ====== per-(h,mode) complex mode mix; output bf16 TRANSPOSED [b][m2][dm] for NT chain =====
__global__ __launch_bounds__(256) void modemix_t_kernel(const float* __restrict__ F,
                                                        const float* __restrict__ W,
                                                        short* __restrict__ Gt, float scale) {
  int b = blockIdx.x, h = blockIdx.y;
  __shared__ float2 Fs[cE][cM];
  __shared__ short ot[128][72];
  const float* Fb = F + ((long)b * cDM + h * cE) * M2;
  for (int i = threadIdx.x; i < cE * cM; i += 256) {
    int e = i >> 6, x = i & 63;
    Fs[e][x] = ((const float2*)(Fb + (long)e * M2))[x];
  }
  __syncthreads();
  int x = threadIdx.x & 63, og = threadIdx.x >> 6;
  float2 acc[16];
#pragma unroll
  for (int i = 0; i < 16; i++) acc[i] = make_float2(0.f, 0.f);
  for (int e = 0; e < cE; e++) {
    float2 f = Fs[e][x];
#pragma unroll
    for (int i = 0; i < 16; i++) {
      int o = og * 16 + i;
      const float2 w = *(const float2*)(W + ((((long)h * cE + e) * cE + o) * cM + x) * 2);
      acc[i].x += f.x * w.x - f.y * w.y;
      acc[i].y += f.x * w.y + f.y * w.x;
    }
  }
#pragma unroll
  for (int i = 0; i < 16; i++) {
    int o = og * 16 + i;
    ot[2 * x][o] = (short)f2bf(acc[i].x * scale);
    ot[2 * x + 1][o] = (short)f2bf(acc[i].y * scale);
  }
  __syncthreads();
  short* gb = Gt + (long)b * (M2 * cDM) + h * cE;
  for (int u = threadIdx.x; u < 1024; u += 256) {
    int row = u >> 3, seg = u & 7;
    *(uint4*)&gb[(long)row * cDM + seg * 8] = *(const uint4*)&ot[row][seg * 8];
  }
}

// ====== fused cross attention: qk=tanh(q^T k), qkv=qk k, mix, transposed bf16 out ======
__global__ __launch_bounds__(256) void fused_cross_kernel(const float* __restrict__ Fq,
                                                          const float* __restrict__ Fk,
                                                          const float* __restrict__ W,
                                                          short* __restrict__ Gt, float scale) {
  __shared__ __align__(16) char smem[65536];
  float2(*Ks)[cM] = (float2(*)[cM])smem;              // [e][y] ; later qkv[e][x]
  float2(*qks)[cM] = (float2(*)[cM])(smem + 32768);   // [x][y] ; later ot region
  int b = blockIdx.x, h = blockIdx.y;
  const float* kb = Fk + ((long)b * cDM + h * cE) * M2;
  for (int i = threadIdx.x; i < cE * cM; i += 256) {
    int e = i >> 6, y = i & 63;
    Ks[e][y] = ((const float2*)(kb + (long)e * M2))[y];
  }
  __syncthreads();
  // phase 1: qk[x][y] = tanh(sum_e q[e][x] * k[e][y])
  {
    int x = threadIdx.x & 63, yg = threadIdx.x >> 6;
    const float* qb = Fq + ((long)b * cDM + h * cE) * M2;
    float2 acc[16];
#pragma unroll
    for (int i = 0; i < 16; i++) acc[i] = make_float2(0.f, 0.f);
    for (int e = 0; e < cE; e++) {
      float2 q = ((const float2*)(qb + (long)e * M2))[x];
#pragma unroll
      for (int i = 0; i < 16; i++) {
        float2 k = Ks[e][yg * 16 + i];
        acc[i].x += q.x * k.x - q.y * k.y;
        acc[i].y += q.x * k.y + q.y * k.x;
      }
    }
#pragma unroll
    for (int i = 0; i < 16; i++) {
      int y = yg * 16 + i;
      float a = acc[i].x, bi = acc[i].y;
      float re, im;
      float t2a = 2.f * a;
      if (fabsf(t2a) > 60.f) {
        re = t2a > 0.f ? 1.f : -1.f;
        im = 0.f;
      } else {
        float denom = coshf(t2a) + cosf(2.f * bi);
        re = sinhf(t2a) / denom;
        im = sinf(2.f * bi) / denom;
      }
      qks[x][y] = make_float2(re, im);
    }
  }
  __syncthreads();
  // phase 2: qkv[e][x] = sum_y qk[x][y] * k[e][y]  (registers)
  int e = threadIdx.x & 63, xg = threadIdx.x >> 6;
  float2 a2[16];
#pragma unroll
  for (int i = 0; i < 16; i++) a2[i] = make_float2(0.f, 0.f);
  for (int y = 0; y < cM; y++) {
    float2 k = Ks[e][y];
#pragma unroll
    for (int i = 0; i < 16; i++) {
      float2 qk = qks[xg * 16 + i][y];
      a2[i].x += qk.x * k.x - qk.y * k.y;
      a2[i].y += qk.x * k.y + qk.y * k.x;
    }
  }
  __syncthreads(); // all Ks/qks reads done
#pragma unroll
  for (int i = 0; i < 16; i++) Ks[e][xg * 16 + i] = a2[i]; // qkv -> Ks region
  __syncthreads();
  // phase 3: mix om[o][x] = sum_e qkv[e][x] * wc[h][e][o][x]; transposed bf16 store
  {
    int x = threadIdx.x & 63, og = threadIdx.x >> 6;
    float2 m[16];
#pragma unroll
    for (int i = 0; i < 16; i++) m[i] = make_float2(0.f, 0.f);
    for (int ee = 0; ee < cE; ee++) {
      float2 f = Ks[ee][x];
#pragma unroll
      for (int i = 0; i < 16; i++) {
        int o = og * 16 + i;
        const float2 w = *(const float2*)(W + ((((long)h * cE + ee) * cE + o) * cM + x) * 2);
        m[i].x += f.x * w.x - f.y * w.y;
        m[i].y += f.x * w.y + f.y * w.x;
      }
    }
    short(*ot)[72] = (short(*)[72])(smem + 32768);
#pragma unroll
    for (int i = 0; i < 16; i++) {
      int o = og * 16 + i;
      ot[2 * x][o] = (short)f2bf(m[i].x * scale);
      ot[2 * x + 1][o] = (short)f2bf(m[i].y * scale);
    }
    __syncthreads();
    short* gb = Gt + (long)b * (M2 * cDM) + h * cE;
    for (int u = threadIdx.x; u < 1024; u += 256) {
      int row = u >> 3, seg = u & 7;
      *(uint4*)&gb[(long)row * cDM + seg * 8] = *(const uint4*)&((short(*)[72])(smem + 32768))[row][seg * 8];
    }
  }
}

// ================= f32 shader GEMM (tiny p1 only) =================
constexpr int GBM = 128, GBN = 128, GBK = 16, LPAD = 132;

__global__ __launch_bounds__(256) void gemm_kernel(const float* __restrict__ A,
                                                   const float* __restrict__ B,
                                                   const float* __restrict__ bias,
                                                   float* __restrict__ C, int M, int N, int K) {
  __shared__ float As[GBK][LPAD];
  __shared__ float Bs[GBK][LPAD];
  int n0 = blockIdx.x * GBN, m0 = blockIdx.y * GBM;
  int tid = threadIdx.x;
  int tx = tid & 15, ty = tid >> 4;
  float acc[8][8];
#pragma unroll
  for (int i = 0; i < 8; i++)
#pragma unroll
    for (int j = 0; j < 8; j++) acc[i][j] = 0.f;

  for (int k0 = 0; k0 < K; k0 += GBK) {
#pragma unroll
    for (int p = 0; p < 8; p++) {
      int i = p * 256 + tid;
      int mm = i >> 4, kk = i & 15;
      int gm = m0 + mm;
      As[kk][mm] = (gm < M && k0 + kk < K) ? A[(long)gm * K + k0 + kk] : 0.f;
    }
#pragma unroll
    for (int p = 0; p < 8; p++) {
      int i = p * 256 + tid;
      int nn = i >> 4, kk = i & 15;
      int gn = n0 + nn;
      Bs[kk][nn] = (gn < N && k0 + kk < K) ? B[(long)gn * K + k0 + kk] : 0.f;
    }
    __syncthreads();
#pragma unroll
    for (int kk = 0; kk < GBK; kk++) {
      float a[8], bb[8];
      *(float4*)&a[0] = *(const float4*)&As[kk][ty * 8];
      *(float4*)&a[4] = *(const float4*)&As[kk][ty * 8 + 4];
      *(float4*)&bb[0] = *(const float4*)&Bs[kk][tx * 8];
      *(float4*)&bb[4] = *(const float4*)&Bs[kk][tx * 8 + 4];
#pragma unroll
      for (int i = 0; i < 8; i++)
#pragma unroll
        for (int j = 0; j < 8; j++) acc[i][j] += a[i] * bb[j];
    }
    __syncthreads();
  }

  for (int i = 0; i < 8; i++) {
    int gm = m0 + ty * 8 + i;
    if (gm >= M) break;
    long rowoff = (long)gm * N;
    for (int j = 0; j < 8; j++) {
      int gn = n0 + tx * 8 + j;
      if (gn < N) C[rowoff + gn] = acc[i][j] + (bias ? bias[gn] : 0.f);
    }
  }
}

// ===== bf16 MFMA GEMM (m97 single-buffer, swizzled, XCD-chunked) =====
// C = A @ B^T. amode=1: circular t-shift rows (trend conv). m0b: += 1024*m0b[gr] at gc==0.
// zsplit>0: blocks with bz>=zsplit use (A2,B2,m0b2,Cf2) with z=bz-zsplit (merged dual GEMM).
__global__ __launch_bounds__(256) void mfma_gemm_bf(
    const short* __restrict__ A, const short* __restrict__ B, const float* __restrict__ bias,
    const float* __restrict__ addend, const float* __restrict__ pe, const float* __restrict__ m0b,
    float* __restrict__ Cf, short* __restrict__ Cb, int M, int N, int K, int lda, long sA, long sB,
    long sC, int relu, int Nreal, int ldc, int amode, const short* __restrict__ A2,
    const short* __restrict__ B2, const float* __restrict__ m0b2, float* __restrict__ Cf2,
    int zsplit) {
  __shared__ __align__(16) short As[8192];
  __shared__ __align__(16) short Bs[8192];
  int nwg = gridDim.x * gridDim.y * gridDim.z;
  int orig = blockIdx.x + gridDim.x * (blockIdx.y + gridDim.y * blockIdx.z);
  int q = nwg >> 3, r = nwg & 7;
  int xcd = orig & 7, ii = orig >> 3;
  int flat = (xcd < r ? xcd * (q + 1) : r * (q + 1) + (xcd - r) * q) + ii;
  int bx = flat % (int)gridDim.x;
  int tmp = flat / (int)gridDim.x;
  int by = tmp % (int)gridDim.y;
  int bz = tmp / (int)gridDim.y;

  int z = bz;
  if (zsplit > 0 && bz >= zsplit) {
    A = A2;
    B = B2;
    m0b = m0b2;
    Cf = Cf2;
    z = bz - zsplit;
  }
  A += (long)z * sA;
  B += (long)z * sB;
  if (Cf) Cf += (long)z * sC;
  if (Cb) Cb += (long)z * sC;
  const float* Ad = addend ? addend + (long)z * sC : nullptr;
  int n0 = bx * 128, m0 = by * 128;
  int tid = threadIdx.x;
  int lane = tid & 63;
  int w = tid >> 6;
  int wm = w & 1, wn = w >> 1;
  int lr = lane & 15, lg = lane >> 4;
  int lrow = lane >> 3;
  int scol = ((lane & 7) * 8) ^ (lrow << 3);

  float4v acc[4][4];
#pragma unroll
  for (int i = 0; i < 4; i++)
#pragma unroll
    for (int j = 0; j < 4; j++) acc[i][j] = (float4v){0.f, 0.f, 0.f, 0.f};

  auto stage = [&](int k0) {
#pragma unroll
    for (int j = 0; j < 4; j++) {
      int seg = w * 4 + j;
      int row = seg * 8 + lrow;
      const short* ga;
      if (amode == 0) {
        ga = A + (long)(m0 + row) * lda + k0 + scol;
      } else {
        int r2 = m0 + row;
        int bb = r2 >> 10, t = r2 & 1023;
        int jj = k0 >> 9, c0 = k0 & 511;
        ga = A + ((((long)(bb << 10)) | ((t + jj + 1023) & 1023)) << 9) + c0 + scol;
      }
      gld16(ga, &As[seg * 512]);
      const short* gb = B + (long)(n0 + row) * K + k0 + scol;
      gld16(gb, &Bs[seg * 512]);
    }
  };

  int nk = K >> 6;
  int swr = (lr & 7) << 3;
  for (int t = 0; t < nk; ++t) {
    stage(t << 6);
    asm volatile("s_waitcnt vmcnt(0)" ::: "memory");
    __syncthreads();
#pragma unroll
    for (int ks = 0; ks < 2; ks++) {
      short8v af[4], bfr[4];
#pragma unroll
      for (int mi = 0; mi < 4; mi++)
        af[mi] = *(const short8v*)&As[(wm * 64 + mi * 16 + lr) * 64 + ((ks * 32 + lg * 8) ^ swr)];
#pragma unroll
      for (int ni = 0; ni < 4; ni++)
        bfr[ni] = *(const short8v*)&Bs[(wn * 64 + ni * 16 + lr) * 64 + ((ks * 32 + lg * 8) ^ swr)];
#pragma unroll
      for (int mi = 0; mi < 4; mi++)
#pragma unroll
        for (int ni = 0; ni < 4; ni++)
          acc[mi][ni] =
              __builtin_amdgcn_mfma_f32_16x16x32_bf16(af[mi], bfr[ni], acc[mi][ni], 0, 0, 0);
    }
    __syncthreads();
  }

#pragma unroll
  for (int mi = 0; mi < 4; mi++) {
#pragma unroll
    for (int i = 0; i < 4; i++) {
      int gr = m0 + wm * 64 + mi * 16 + lg * 4 + i;
      long rowoff = (long)gr * ldc;
#pragma unroll
      for (int ni = 0; ni < 4; ni++) {
        int gc = n0 + wn * 64 + ni * 16 + lr;
        if (gc < Nreal) {
          float v = acc[mi][ni][i];
          if (bias) v += bias[gc];
          if (pe) v += pe[((gr & (cL - 1)) << 9) + gc];
          if (m0b && gc == 0) v += 1024.f * m0b[gr];
          if (Ad) v += Ad[rowoff + gc];
          if (relu) v = fmaxf(v, 0.f);
          if (Cf) Cf[rowoff + gc] = v;
          if (Cb) Cb[rowoff + gc] = (short)f2bf(v);
        }
      }
    }
  }
}

} // namespace

extern "C" void kernel_launch(void* const* d_in, const int* in_sizes, int n_in, void* d_out,
                              int out_size, void* d_ws, size_t ws_size, hipStream_t stream) {
  const float* x_enc = (const float*)d_in[0];
  const float* tok_W = (const float*)d_in[1];
  const float* enc_Wq = (const float*)d_in[2];
  const float* enc_Wo = (const float*)d_in[5];
  const float* enc_bq = (const float*)d_in[6];
  const float* enc_bo = (const float*)d_in[9];
  const float* dsWq = (const float*)d_in[10];
  const float* dsWo = (const float*)d_in[13];
  const float* dsbq = (const float*)d_in[14];
  const float* dsbo = (const float*)d_in[17];
  const float* dcWq = (const float*)d_in[18];
  const float* dcWk = (const float*)d_in[19];
  const float* dcWo = (const float*)d_in[21];
  const float* dcbq = (const float*)d_in[22];
  const float* dcbk = (const float*)d_in[23];
  const float* dcbo = (const float*)d_in[25];
  const float* enc_c1W = (const float*)d_in[26];
  const float* enc_c1b = (const float*)d_in[27];
  const float* enc_c2W = (const float*)d_in[28];
  const float* enc_c2b = (const float*)d_in[29];
  const float* dec_c1W = (const float*)d_in[30];
  const float* dec_c1b = (const float*)d_in[31];
  const float* dec_c2W = (const float*)d_in[32];
  const float* dec_c2b = (const float*)d_in[33];
  const float* dec_trW = (const float*)d_in[34];
  const float* fb_enc = (const float*)d_in[35];
  const float* fb_dec = (const float*)d_in[36];
  const float* fc_w = (const float*)d_in[37];
  const float* p1W = (const float*)d_in[38];
  const float* p1b = (const float*)d_in[39];
  const float* p2W = (const float*)d_in[40];
  const float* p2b = (const float*)d_in[41];
  const float* p3W = (const float*)d_in[42];
  const float* p3b = (const float*)d_in[43];

  // ---- layout sizing (dry-run) ----
  auto layout_bytes = [&](long BG, long RH) -> size_t {
    size_t t = 0;
    auto add = [&](size_t b) { t = (t + b + 255) & ~(size_t)255; };
    add(2 * 262144 * 2); add(2 * 262144 * 2);
    add(262144 * 2); add(262144 * 2); add(262144 * 2); add(262144 * 2); add(262144 * 2);
    add(2 * 1048576 * 2); add(2 * 1048576 * 2); add(1048576 * 2); add(1048576 * 2);
    add(131072 * 2); add(131072 * 2); add(65536 * 2); add(196608 * 2); add(65536 * 2);
    add(128 * 4); add(524288 * 4);
    long GA = BG * cL * cDM;
    add(GA * 4); add(GA * 4); add(GA * 4);
    add(GA * 2); add(GA * 2); add(GA * 2); add(GA * 2);
    add(BG * cL * 128 * 2);
    size_t ub = (size_t)GA * 2;
    size_t hd = (size_t)RH * cDFF * 2;
    add(ub > hd ? ub : hd);
    add(BG * 65536 * 4); add(BG * 65536 * 4);                                  // Fq Fk
    add(BG * 65536 * 2); add(BG * 65536 * 2); add(BG * 65536 * 2); add(BG * 65536 * 2);
    add(BG * cL * cCIN * 4); add(BG * cL * cCIN * 4); add(BG * cL * cCIN * 4);
    return t;
  };
  int BG = cB;
  while (BG > 1 && layout_bytes(BG, 512) > ws_size) BG >>= 1;
  long RH = (long)BG * cL;
  while (RH > 512 && layout_bytes(BG, RH) > ws_size) RH >>= 1;

  long GBL = (long)BG * cL;
  char* base = (char*)d_ws;
  size_t off = 0;
  auto alloc = [&](size_t bytes) -> void* {
    void* p = base + off;
    off = (off + bytes + 255) & ~(size_t)255;
    return p;
  };
  short* WqbE = (short*)alloc(2 * 262144 * 2);
  short* WobE = (short*)alloc(2 * 262144 * 2);
  short* dsWqb = (short*)alloc(262144 * 2);
  short* dsWob = (short*)alloc(262144 * 2);
  short* dcWqb = (short*)alloc(262144 * 2);
  short* dcWkb = (short*)alloc(262144 * 2);
  short* dcWob = (short*)alloc(262144 * 2);
  short* c1bE = (short*)alloc(2 * 1048576 * 2);
  short* c2bE = (short*)alloc(2 * 1048576 * 2);
  short* c1bD = (short*)alloc(1048576 * 2);
  short* c2bD = (short*)alloc(1048576 * 2);
  short* basisdb = (short*)alloc(131072 * 2);
  short* basisib = (short*)alloc(131072 * 2);
  short* Bpadb = (short*)alloc(65536 * 2);
  short* Wtr3b = (short*)alloc(196608 * 2);
  short* p3padb = (short*)alloc(65536 * 2);
  float* p3bpadf = (float*)alloc(128 * 4);
  float* pe = (float*)alloc(524288 * 4);
  long GA = GBL * cDM;
  float* E = (float*)alloc(GA * 4);
  float* X = (float*)alloc(GA * 4);
  float* A = (float*)alloc(GA * 4);
  short* Eb = (short*)alloc(GA * 2);
  short* Xb = (short*)alloc(GA * 2);
  short* Ab = (short*)alloc(GA * 2);
  short* Sb = (short*)alloc(GA * 2);
  short* winb = (short*)alloc(GBL * 128 * 2);
  size_t ubsz = (size_t)GA * 2;
  size_t hdsz = (size_t)RH * cDFF * 2;
  short* UB = (short*)alloc(ubsz > hdsz ? ubsz : hdsz);
  short* Tb = UB;
  short* HDb = UB;
  float* Fq = (float*)alloc((size_t)BG * 65536 * 4);
  float* Fk = (float*)alloc((size_t)BG * 65536 * 4);
  short* FEb = (short*)alloc((size_t)BG * 65536 * 2);
  short* FXb = (short*)alloc((size_t)BG * 65536 * 2);
  short* Gtb = (short*)alloc((size_t)BG * 65536 * 2);
  short* Hb = (short*)alloc((size_t)BG * 65536 * 2);
  float* TRD = (float*)alloc(GBL * cCIN * 4);
  float* O1 = (float*)alloc(GBL * cCIN * 4);
  float* O2 = (float*)alloc(GBL * cCIN * 4);

  auto mg = [&](const short* Am, const short* Bm, const float* bias, const float* add,
                const float* peA, const float* m0b, float* Cf, short* Cb, int Mm, int Nn, int Kk,
                int lda, long sA, long sB, long sC, int batch, int relu, int Nreal, int ldc,
                int amode) {
    dim3 g(Nn / 128, Mm / 128, batch);
    mfma_gemm_bf<<<g, 256, 0, stream>>>(Am, Bm, bias, add, peA, m0b, Cf, Cb, Mm, Nn, Kk, lda, sA,
                                        sB, sC, relu, Nreal, ldc, amode, nullptr, nullptr,
                                        nullptr, nullptr, 0);
  };
  auto cvt = [&](const float* in, short* out, int n) {
    int g = (n + 255) / 256;
    if (g > 4096) g = 4096;
    cvt_kernel<<<g, 256, 0, stream>>>(in, out, n);
  };
  auto decomp = [&](const float* x, float* sf, short* sb, float* maf, short* mab, long total,
                    int C_) {
    int n8 = (int)(total / 8);
    decomp_kernel<<<(n8 + 255) / 256, 256, 0, stream>>>(x, sf, sb, maf, mab, n8, C_);
  };
  auto dft = [&](const short* srcb, short* Fout) {
    transpose_bf<<<dim3(16, 32, BG), 256, 0, stream>>>(srcb, Tb);
    mg(basisdb, Tb, nullptr, nullptr, nullptr, nullptr, nullptr, Fout, M2, cDM, cL, cL, 0,
       (long)cDM * cL, 65536, BG, 0, cDM, cDM, 0);
  };
  auto modeproj = [&](const short* Wb, const short* Fin, const float* m0b, float* Cf, short* Cb) {
    mg(Wb, Fin, nullptr, nullptr, nullptr, m0b, Cf, Cb, cDM, M2, cDM, cDM, 0, 65536, 65536, BG, 0,
       M2, M2, 0);
  };
  // merged q/k mode projections (one dispatch, z in [0, 2*BG))
  auto modeproj2 = [&](const short* Wa, const short* Fa, const float* ba, float* Ca,
                       const short* Wb2, const short* Fb2, const float* bb2, float* Cb2) {
    dim3 g(1, cDM / 128, 2 * BG);
    mfma_gemm_bf<<<g, 256, 0, stream>>>(Wa, Fa, nullptr, nullptr, nullptr, ba, Ca, nullptr, cDM,
                                        M2, cDM, cDM, 0, 65536, 65536, 0, M2, M2, 0, Wb2, Fb2,
                                        bb2, Cb2, BG);
  };
  auto idft = [&](const short* Hin, const float* bias, const float* add, float* Cf) {
    mg(basisib, Hin, bias, add, nullptr, nullptr, Cf, nullptr, cL, cDM, M2, M2, 0, 65536,
       (long)cL * cDM, BG, 0, cDM, cDM, 0);
  };
  auto ffn = [&](const short* inb, const float* addf, float* outf, const short* c1w,
                 const float* c1bias, const short* c2w, const float* c2bias) {
    for (long r = 0; r < GBL; r += RH) {
      mg(inb + r * cDM, c1w, c1bias, nullptr, nullptr, nullptr, nullptr, HDb, (int)RH, cDFF, cDM,
         cDM, 0, 0, 0, 1, 1, cDFF, cDFF, 0);
      mg(HDb, c2w, c2bias, addf + r * cDM, nullptr, nullptr, outf + r * cDM, nullptr, (int)RH,
         cDM, cDFF, cDFF, 0, 0, 0, 1, 0, cDM, cDM, 0);
    }
  };
  auto trendg = [&](const short* mab) {
    mg(mab, Wtr3b, nullptr, TRD, nullptr, nullptr, TRD, nullptr, (int)GBL, 128, 1536, 512, 0, 0,
       0, 1, 0, cCIN, cCIN, 1);
  };
  auto mixt = [&](const float* F, const float* W, float scale) {
    modemix_t_kernel<<<dim3(BG, cH), 256, 0, stream>>>(F, W, Gtb, scale);
  };

  // ---- one-time setup ----
  basis_kernel<<<(M2 * cL) / 256, 256, 0, stream>>>(basisdb, basisib);
  pe_kernel<<<(cL * cDM) / 256, 256, 0, stream>>>(pe);
  prep_kernel<<<768, 256, 0, stream>>>(tok_W, dec_trW, p3W, p3b, Bpadb, Wtr3b, p3padb, p3bpadf);
  cvt(enc_Wq, WqbE, 524288);
  cvt(enc_Wo, WobE, 524288);
  cvt(dsWq, dsWqb, 262144);
  cvt(dsWo, dsWob, 262144);
  cvt(dcWq, dcWqb, 262144);
  cvt(dcWk, dcWkb, 262144);
  cvt(dcWo, dcWob, 262144);
  cvt(enc_c1W, c1bE, 2097152);
  cvt(enc_c2W, c2bE, 2097152);
  cvt(dec_c1W, c1bD, 1048576);
  cvt(dec_c2W, c2bD, 1048576);

  for (int b0 = 0; b0 < cB; b0 += BG) {
    const float* xg = x_enc + (long)b0 * cL * cCIN;

    decomp(xg, nullptr, nullptr, TRD, nullptr, GBL * cCIN, cCIN); // trend_init -> TRD
    winbuild_kernel<<<(int)(GBL * 32 / 256), 256, 0, stream>>>(xg, winb);
    mg(winb, Bpadb, nullptr, nullptr, pe, nullptr, E, Eb, (int)GBL, cDM, 128, 128, 0, 0, 0, 1, 0,
       cDM, cDM, 0); // embedding

    // ---- encoder ----
    for (int l = 0; l < 2; l++) {
      dft(Eb, FEb);
      modeproj(WqbE + (long)l * 262144, FEb, enc_bq + l * cDM, Fq, nullptr);
      mixt(Fq, fb_enc, 1.0f);
      modeproj(WobE + (long)l * 262144, Gtb, nullptr, nullptr, Hb);
      idft(Hb, enc_bo + l * cDM, E, A);
      decomp(A, X, Xb, nullptr, nullptr, GA, cDM);
      ffn(Xb, X, A, c1bE + (long)l * 1048576, enc_c1b + l * cDFF, c2bE + (long)l * 1048576,
          enc_c2b + l * cDM);
      decomp(A, E, Eb, nullptr, nullptr, GA, cDM);
    }

    // ---- decoder ----
    dft(Eb, FEb);
    modeproj(dsWqb, FEb, dsbq, Fq, nullptr);
    mixt(Fq, fb_dec, 1.0f);
    modeproj(dsWob, Gtb, nullptr, nullptr, Hb);
    idft(Hb, dsbo, E, A);                                          // x1 -> A
    decomp(A, X, Xb, nullptr, Sb, GA, cDM);                        // x2 -> X,Xb; ma -> Sb
    trendg(Sb);                                                    // t1

    dft(Xb, FXb);
    modeproj2(dcWqb, FXb, dcbq, Fq, dcWkb, FEb, dcbk, Fk);         // xq + xk, one dispatch
    fused_cross_kernel<<<dim3(BG, cH), 256, 0, stream>>>(Fq, Fk, fc_w, Gtb,
                                                         1.0f / (float)(cDM * cDM));
    modeproj(dcWob, Gtb, nullptr, nullptr, Hb);
    idft(Hb, dcbo, X, E);                                          // x3 -> E
    decomp(E, A, Ab, nullptr, Sb, GA, cDM);                        // x4 -> A,Ab; ma -> Sb
    trendg(Sb);                                                    // t2
    ffn(Ab, A, E, c1bD, dec_c1b, c2bD, dec_c2b);                   // x4+y -> E
    decomp(E, nullptr, Xb, nullptr, Sb, GA, cDM);                  // x5 -> Xb; ma -> Sb
    trendg(Sb);                                                    // t3

    // ---- final projections ----
    mg(Xb, p3padb, p3bpadf, TRD, nullptr, nullptr, O1, nullptr, (int)GBL, 128, cDM, cDM, 0, 0, 0,
       1, 0, cCIN, cCIN, 0);
    gemm_kernel<<<dim3(1, (int)(GBL / 128)), 256, 0, stream>>>(O1, p1W, p1b, O2, (int)GBL, cCIN,
                                                               cCIN);
    p2_kernel<<<dim3(BG, 32), 256, 0, stream>>>(O2, p2W, p2b,
                                                (float*)d_out + (long)b0 * cPRED * cCIN);
  }
}